// Round 1
// baseline (1437.519 us; speedup 1.0000x reference)
//
#include <hip/hip_runtime.h>
#include <math.h>

typedef unsigned short u16;
typedef unsigned int   u32;

#define NQv 32768
#define HWp 7680
#define NI  100

typedef short v8s __attribute__((ext_vector_type(8)));
typedef float v4f __attribute__((ext_vector_type(4)));

__device__ inline float bf2f(u16 u){ u32 x = ((u32)u) << 16; return __uint_as_float(x); }
__device__ inline u16 f2bf(float f){
  u32 x = __float_as_uint(f);
  u32 r = (x + 0x7fffu + ((x >> 16) & 1u)) >> 16;
  return (u16)r;
}
__device__ inline float sigf(float x){ return 1.0f / (1.0f + expf(-x)); }

// ---------------- small prep: invert K (3x3) and E (4x4), instance scores ----------------
__global__ void k_prep_small(const float* __restrict__ Km, const float* __restrict__ Em,
                             const float* __restrict__ logits,
                             float* __restrict__ mats, float* __restrict__ scores,
                             int* __restrict__ keep0)
{
  int tid = threadIdx.x;
  if (tid == 0) {
    double a[9];
    for (int i = 0; i < 9; i++) a[i] = (double)Km[i];
    double det = a[0]*(a[4]*a[8]-a[5]*a[7]) - a[1]*(a[3]*a[8]-a[5]*a[6]) + a[2]*(a[3]*a[7]-a[4]*a[6]);
    double id = 1.0 / det;
    double inv[9];
    inv[0]=(a[4]*a[8]-a[5]*a[7])*id; inv[1]=(a[2]*a[7]-a[1]*a[8])*id; inv[2]=(a[1]*a[5]-a[2]*a[4])*id;
    inv[3]=(a[5]*a[6]-a[3]*a[8])*id; inv[4]=(a[0]*a[8]-a[2]*a[6])*id; inv[5]=(a[2]*a[3]-a[0]*a[5])*id;
    inv[6]=(a[3]*a[7]-a[4]*a[6])*id; inv[7]=(a[1]*a[6]-a[0]*a[7])*id; inv[8]=(a[0]*a[4]-a[1]*a[3])*id;
    for (int i = 0; i < 9; i++) mats[i] = (float)inv[i];
    // 4x4 Gauss-Jordan with partial pivot (double)
    double m[4][8];
    for (int r = 0; r < 4; r++){
      for (int c = 0; c < 4; c++){ m[r][c] = (double)Em[r*4+c]; m[r][4+c] = (r==c) ? 1.0 : 0.0; }
    }
    for (int col = 0; col < 4; col++){
      int piv = col; double best = fabs(m[col][col]);
      for (int r = col+1; r < 4; r++){ double v = fabs(m[r][col]); if (v > best){ best = v; piv = r; } }
      if (piv != col){ for (int c = 0; c < 8; c++){ double t = m[col][c]; m[col][c] = m[piv][c]; m[piv][c] = t; } }
      double p = m[col][col];
      for (int c = 0; c < 8; c++) m[col][c] /= p;
      for (int r = 0; r < 4; r++) if (r != col){ double f = m[r][col]; for (int c = 0; c < 8; c++) m[r][c] -= f*m[col][c]; }
    }
    for (int r = 0; r < 3; r++) for (int c = 0; c < 4; c++) mats[9 + r*4 + c] = (float)m[r][4+c];
  }
  if (tid < NI) {
    float mx = -1e30f;
    for (int c = 0; c < 21; c++){ float t = sigf(logits[tid*21+c]) / 0.06f; mx = fmaxf(mx, t); }
    float s = 0.f;
    for (int c = 0; c < 21; c++){ float t = sigf(logits[tid*21+c]) / 0.06f; s += expf(t - mx); }
    float sc = 1.0f / s;
    scores[tid] = sc;
    keep0[tid] = (sc > 0.25f) ? 1 : 0;
  }
}

// ---------------- per-pixel argmax over instances (first-max semantics) ----------------
__global__ void k_mask_argmax(const float* __restrict__ pmL, const float* __restrict__ scores,
                              const int* __restrict__ keep0, int* __restrict__ mids)
{
  int p = blockIdx.x*256 + threadIdx.x;
  if (p >= HWp) return;
  float best = -2e30f; int bid = 0;
  for (int i = 0; i < NI; i++){
    float lg = pmL[i*HWp + p];
    float val = keep0[i] ? scores[i] * sigf(lg) : -1.0f;
    if (val > best){ best = val; bid = i; }
  }
  mids[p] = bid;
}

// ---------------- per-instance areas + keep flag ----------------
__global__ void k_inst_stats(const float* __restrict__ pmL, const int* __restrict__ mids,
                             const int* __restrict__ keep0, int* __restrict__ keep)
{
  int i = blockIdx.x, tid = threadIdx.x;
  int k0 = keep0[i];
  int ma = 0, pa = 0, it = 0;
  for (int p = tid; p < HWp; p += 256){
    float lg = pmL[i*HWp + p];
    int pb = (lg >= 0.0f) ? 1 : 0;        // sigmoid(lg) >= 0.5
    int mi = (mids[p] == i && k0) ? 1 : 0;
    ma += mi; pa += pb; it += (mi & pb);
  }
  __shared__ int sma[256], spa[256], sit[256];
  sma[tid] = ma; spa[tid] = pa; sit[tid] = it;
  __syncthreads();
  for (int off = 128; off; off >>= 1){
    if (tid < off){ sma[tid]+=sma[tid+off]; spa[tid]+=spa[tid+off]; sit[tid]+=sit[tid+off]; }
    __syncthreads();
  }
  if (tid == 0){
    keep[i] = (k0 && sit[0] > 0 && ((float)sma[0] >= 0.8f*(float)spa[0])) ? 1 : 0;
  }
}

__global__ void k_finalize(const int* __restrict__ keep, int* __restrict__ anyk,
                           float* __restrict__ usef, float* __restrict__ biasArr)
{
  int tid = threadIdx.x;
  __shared__ int s_any;
  if (tid == 0){
    int a = 0;
    for (int i = 0; i < NI; i++) a |= keep[i];
    s_any = a; anyk[0] = a; usef[0] = a ? 1.0f : 0.0f;
  }
  __syncthreads();
  if (tid < 128){
    float b;
    if (tid < NI) b = s_any ? (keep[tid] ? 0.0f : -1e9f) : 0.0f;
    else b = -1e9f;
    biasArr[tid] = b;
  }
}

// ---------------- back-projection + deterministic per-instance xyz sum ----------------
__global__ void k_backproject(const float* __restrict__ depth, const float* __restrict__ pmL,
                              const int* __restrict__ mids, const int* __restrict__ keep,
                              const float* __restrict__ mats, float* __restrict__ xyz)
{
  int i = blockIdx.x, tid = threadIdx.x;
  float sx = 0.f, sy = 0.f, sz = 0.f;
  if (keep[i]){
    float ik0=mats[0],ik1=mats[1],ik2=mats[2],ik3=mats[3],ik4=mats[4],ik5=mats[5],ik6=mats[6],ik7=mats[7],ik8=mats[8];
    const float* iE = mats + 9;
    for (int p = tid; p < HWp; p += 256){
      if (mids[p] == i && pmL[i*HWp + p] >= 0.0f){
        int r = p / 160, c = p % 160;
        float xg = (float)((double)c * (1279.0/159.0));
        float yg = (float)((double)r * (383.0/47.0));
        float d = depth[p];
        float g0 = xg*d, g1 = yg*d, g2 = d;
        float c0 = ik0*g0 + ik1*g1 + ik2*g2;
        float c1 = ik3*g0 + ik4*g1 + ik5*g2;
        float c2 = ik6*g0 + ik7*g1 + ik8*g2;
        sx += iE[0]*c0 + iE[1]*c1 + iE[2]*c2 + iE[3];
        sy += iE[4]*c0 + iE[5]*c1 + iE[6]*c2 + iE[7];
        sz += iE[8]*c0 + iE[9]*c1 + iE[10]*c2 + iE[11];
      }
    }
  }
  __shared__ float rx[256], ry[256], rz[256];
  rx[tid]=sx; ry[tid]=sy; rz[tid]=sz;
  __syncthreads();
  for (int off = 128; off; off >>= 1){
    if (tid < off){ rx[tid]+=rx[tid+off]; ry[tid]+=ry[tid+off]; rz[tid]+=rz[tid+off]; }
    __syncthreads();
  }
  if (tid == 0){ xyz[i*3+0]=rx[0]; xyz[i*3+1]=ry[0]; xyz[i*3+2]=rz[0]; }
}

// ---------------- kv_k = inst_queries + use * (xyz @ pos_embed^T) ----------------
__global__ void k_kvk(const float* __restrict__ iq, const float* __restrict__ pe,
                      const float* __restrict__ xyz, const float* __restrict__ usef,
                      float* __restrict__ kvk)
{
  int idx = blockIdx.x*256 + threadIdx.x;
  if (idx >= NI*128) return;
  int i = idx >> 7, c = idx & 127;
  float u = usef[0];
  float ip = pe[c*3+0]*xyz[i*3+0] + pe[c*3+1]*xyz[i*3+1] + pe[c*3+2]*xyz[i*3+2];
  kvk[idx] = iq[idx] + u * ip;
}

// ---------------- per-layer K/V head projections (K pre-scaled by 1/sqrt(32)) ----------------
__global__ void k_khvh(const float* __restrict__ kvk, const float* __restrict__ iq,
                       const float* __restrict__ Win, const float* __restrict__ bin,
                       float* __restrict__ khs, float* __restrict__ vhs)
{
  int k = blockIdx.x, li = blockIdx.y, c = threadIdx.x;
  if (c < 128){
    const float* w = Win + ((size_t)li*384 + 128 + c)*128;
    float acc = bin[li*384 + 128 + c];
    for (int j = 0; j < 128; j++) acc += kvk[k*128+j] * w[j];
    khs[(((size_t)li*4 + (c>>5))*NI + k)*32 + (c&31)] = acc * 0.17677669529663687f;
  } else {
    int c2 = c - 128;
    const float* w = Win + ((size_t)li*384 + 256 + c2)*128;
    float acc = bin[li*384 + 256 + c2];
    for (int j = 0; j < 128; j++) acc += iq[k*128+j] * w[j];
    vhs[(((size_t)li*4 + (c2>>5))*NI + k)*32 + (c2&31)] = acc;
  }
}

// ---------------- x = src + qpos (qpos recomputed on the fly); fp32 + bf16 out ----------------
__global__ void k_addpos(const float* __restrict__ src, const float* __restrict__ pe,
                         const float* __restrict__ vo, float* __restrict__ xf,
                         u16* __restrict__ xbf)
{
  int idx = blockIdx.x*256 + threadIdx.x;  // exactly NQ*128
  int q = idx >> 7, c = idx & 127;
  float px = ((float)(q >> 9)       + 0.5f)*0.8f + vo[0];
  float py = ((float)((q >> 3)&63)  + 0.5f)*0.8f + vo[1];
  float pz = ((float)(q & 7)        + 0.5f)*0.8f + vo[2];
  float qp = pe[c*3+0]*px + pe[c*3+1]*py + pe[c*3+2]*pz;
  float v = src[idx] + qp;
  xf[idx] = v;
  xbf[idx] = f2bf(v);
}

__global__ void k_f2bf(const float* __restrict__ in, u16* __restrict__ out, int n)
{ int i = blockIdx.x*256 + threadIdx.x; if (i < n) out[i] = f2bf(in[i]); }

// pack conv weights [li][o][i][t] -> [li][t][o][i] bf16
__global__ void k_packconv(const float* __restrict__ w, u16* __restrict__ wp, int n)
{
  int idx = blockIdx.x*256 + threadIdx.x;
  if (idx >= n) return;
  int i = idx & 127;
  int o = (idx >> 7) & 127;
  int lt = idx >> 14;
  int li = lt / 27, t = lt % 27;
  wp[idx] = f2bf(w[(((size_t)li*128 + o)*128 + i)*27 + t]);
}

// ---------------- generic bf16 MFMA GEMM: out = act(A[M,K] @ B[N,K]^T + bias (+res)) ----------------
__global__ __launch_bounds__(256) void k_gemm(
    const u16* __restrict__ A, const u16* __restrict__ B,
    const float* __restrict__ bias, const float* __restrict__ res,
    float* __restrict__ outF, u16* __restrict__ outB,
    int N, int K, int act)
{
  int lane = threadIdx.x & 63, wave = threadIdx.x >> 6;
  int m0 = blockIdx.x*64 + wave*16;
  int n0 = blockIdx.y*64;
  int r15 = lane & 15, kg = lane >> 4;
  const u16* Ap = A + (size_t)(m0 + r15)*K + kg*8;
  const u16* Bp = B + (size_t)(n0 + r15)*K + kg*8;
  v4f acc0 = {0,0,0,0}, acc1 = {0,0,0,0}, acc2 = {0,0,0,0}, acc3 = {0,0,0,0};
  for (int k0 = 0; k0 < K; k0 += 32){
    v8s a  = *(const v8s*)(Ap + k0);
    v8s b0 = *(const v8s*)(Bp + k0);
    v8s b1 = *(const v8s*)(Bp + (size_t)16*K + k0);
    v8s b2 = *(const v8s*)(Bp + (size_t)32*K + k0);
    v8s b3 = *(const v8s*)(Bp + (size_t)48*K + k0);
    acc0 = __builtin_amdgcn_mfma_f32_16x16x32_bf16(a, b0, acc0, 0, 0, 0);
    acc1 = __builtin_amdgcn_mfma_f32_16x16x32_bf16(a, b1, acc1, 0, 0, 0);
    acc2 = __builtin_amdgcn_mfma_f32_16x16x32_bf16(a, b2, acc2, 0, 0, 0);
    acc3 = __builtin_amdgcn_mfma_f32_16x16x32_bf16(a, b3, acc3, 0, 0, 0);
  }
  v4f accs[4] = {acc0, acc1, acc2, acc3};
  #pragma unroll
  for (int nn = 0; nn < 4; nn++){
    int col = n0 + nn*16 + r15;
    float bv = bias ? bias[col] : 0.0f;
    #pragma unroll
    for (int rr = 0; rr < 4; rr++){
      int row = m0 + kg*4 + rr;
      float v = accs[nn][rr] + bv;
      size_t oi = (size_t)row*N + col;
      if (res) v += res[oi];
      if (act == 1) v = 0.5f*v*(1.0f + erff(v*0.70710678118654752f));
      if (outF) outF[oi] = v;
      if (outB) outB[oi] = f2bf(v);
    }
  }
}

// ---------------- flash-style cross-attention: one wave = 64 queries x 1 head ----------------
__global__ __launch_bounds__(256) void k_attn(
    const float* __restrict__ QH, const float* __restrict__ KH, const float* __restrict__ VH,
    const float* __restrict__ biasArr, u16* __restrict__ O)
{
  __shared__ u16 skh[4*NI*32];
  __shared__ u16 svh[4*NI*32];
  __shared__ float sb[NI];
  int tid = threadIdx.x;
  for (int i = tid; i < 4*NI*32; i += 256){ skh[i] = f2bf(KH[i]); svh[i] = f2bf(VH[i]); }
  if (tid < NI) sb[tid] = biasArr[tid];
  __syncthreads();
  int lane = tid & 63, h = tid >> 6;
  int q = blockIdx.x*64 + lane;
  float qh[32];
  const float4* qp = (const float4*)(QH + (size_t)q*128 + h*32);
  #pragma unroll
  for (int j = 0; j < 8; j++){
    float4 t = qp[j];
    qh[4*j] = t.x; qh[4*j+1] = t.y; qh[4*j+2] = t.z; qh[4*j+3] = t.w;
  }
  float m = -1e30f, l = 0.0f;
  float o[32];
  #pragma unroll
  for (int d = 0; d < 32; d++) o[d] = 0.0f;
  for (int k = 0; k < NI; k++){
    const uint4* kr = (const uint4*)&skh[(h*NI + k)*32];
    float s = sb[k];
    #pragma unroll
    for (int j = 0; j < 4; j++){
      uint4 u = kr[j];
      s += bf2f((u16)(u.x & 0xffff))*qh[8*j+0] + bf2f((u16)(u.x >> 16))*qh[8*j+1];
      s += bf2f((u16)(u.y & 0xffff))*qh[8*j+2] + bf2f((u16)(u.y >> 16))*qh[8*j+3];
      s += bf2f((u16)(u.z & 0xffff))*qh[8*j+4] + bf2f((u16)(u.z >> 16))*qh[8*j+5];
      s += bf2f((u16)(u.w & 0xffff))*qh[8*j+6] + bf2f((u16)(u.w >> 16))*qh[8*j+7];
    }
    float nm = fmaxf(m, s);
    float corr = __expf(m - nm);
    float p = __expf(s - nm);
    l = l*corr + p;
    m = nm;
    const uint4* vr = (const uint4*)&svh[(h*NI + k)*32];
    #pragma unroll
    for (int j = 0; j < 4; j++){
      uint4 u = vr[j];
      o[8*j+0] = o[8*j+0]*corr + p*bf2f((u16)(u.x & 0xffff));
      o[8*j+1] = o[8*j+1]*corr + p*bf2f((u16)(u.x >> 16));
      o[8*j+2] = o[8*j+2]*corr + p*bf2f((u16)(u.y & 0xffff));
      o[8*j+3] = o[8*j+3]*corr + p*bf2f((u16)(u.y >> 16));
      o[8*j+4] = o[8*j+4]*corr + p*bf2f((u16)(u.z & 0xffff));
      o[8*j+5] = o[8*j+5]*corr + p*bf2f((u16)(u.z >> 16));
      o[8*j+6] = o[8*j+6]*corr + p*bf2f((u16)(u.w & 0xffff));
      o[8*j+7] = o[8*j+7]*corr + p*bf2f((u16)(u.w >> 16));
    }
  }
  float inv = 1.0f / l;
  u32* op = (u32*)(O + (size_t)q*128 + h*32);
  #pragma unroll
  for (int j = 0; j < 16; j++){
    u16 lo = f2bf(o[2*j]*inv), hi = f2bf(o[2*j+1]*inv);
    op[j] = (u32)lo | ((u32)hi << 16);
  }
}

// ---------------- LayerNorm over 128 dims; one wave per row ----------------
__global__ __launch_bounds__(256) void k_ln(const float* __restrict__ in,
    const float* __restrict__ g, const float* __restrict__ b,
    float* __restrict__ outF, u16* __restrict__ outB)
{
  int lane = threadIdx.x & 63, wave = threadIdx.x >> 6;
  size_t row = (size_t)blockIdx.x*4 + wave;
  const float* ip = in + row*128;
  float v0 = ip[lane], v1 = ip[lane+64];
  float sum = v0 + v1;
  #pragma unroll
  for (int off = 32; off > 0; off >>= 1) sum += __shfl_xor(sum, off, 64);
  float mean = sum * (1.0f/128.0f);
  float d0 = v0 - mean, d1 = v1 - mean;
  float vs = d0*d0 + d1*d1;
  #pragma unroll
  for (int off = 32; off > 0; off >>= 1) vs += __shfl_xor(vs, off, 64);
  float rs = rsqrtf(vs*(1.0f/128.0f) + 1e-5f);
  float o0 = d0*rs*g[lane]    + b[lane];
  float o1 = d1*rs*g[lane+64] + b[lane+64];
  if (outF){ outF[row*128+lane] = o0; outF[row*128+lane+64] = o1; }
  if (outB){ outB[row*128+lane] = f2bf(o0); outB[row*128+lane+64] = f2bf(o1); }
}

__global__ void k_fovsel(const float* __restrict__ resid, const float* __restrict__ qe,
                         const int* __restrict__ fov, u16* __restrict__ x3)
{
  int idx = blockIdx.x*256 + threadIdx.x;
  int q = idx >> 7;
  float v = fov[q] ? resid[idx] : qe[idx];
  x3[idx] = f2bf(v);
}

// ---------------- dilated 3x3x3 conv as 27-tap implicit MFMA GEMM, relu(conv+b+x) ----------------
__global__ __launch_bounds__(256) void k_conv(
    const u16* __restrict__ X, const u16* __restrict__ W,
    const float* __restrict__ bias, u16* __restrict__ Y, int dil)
{
  int lane = threadIdx.x & 63, wave = threadIdx.x >> 6;
  int m0 = blockIdx.x*64 + wave*16;
  int n0 = blockIdx.y*64;
  int r15 = lane & 15, kg = lane >> 4;
  int s = m0 + r15;
  int xs = s >> 9, ys = (s >> 3) & 63, zs = s & 7;
  v4f acc0 = {0,0,0,0}, acc1 = {0,0,0,0}, acc2 = {0,0,0,0}, acc3 = {0,0,0,0};
  for (int t = 0; t < 27; t++){
    int kx = t/9, ky = (t/3)%3, kz = t%3;
    int xx = xs + (kx-1)*dil, yy = ys + (ky-1)*dil, zz = zs + (kz-1)*dil;
    bool ok = ((unsigned)xx < 64u) & ((unsigned)yy < 64u) & ((unsigned)zz < 8u);
    int sp = ok ? ((xx*64 + yy)*8 + zz) : 0;
    const u16* Ap = X + (size_t)sp*128 + kg*8;
    const u16* Bp = W + ((size_t)t*128 + n0 + r15)*128 + kg*8;
    #pragma unroll
    for (int k0 = 0; k0 < 128; k0 += 32){
      v8s a = {0,0,0,0,0,0,0,0};
      if (ok) a = *(const v8s*)(Ap + k0);
      v8s b0 = *(const v8s*)(Bp + k0);
      v8s b1 = *(const v8s*)(Bp + 16*128 + k0);
      v8s b2 = *(const v8s*)(Bp + 32*128 + k0);
      v8s b3 = *(const v8s*)(Bp + 48*128 + k0);
      acc0 = __builtin_amdgcn_mfma_f32_16x16x32_bf16(a, b0, acc0, 0, 0, 0);
      acc1 = __builtin_amdgcn_mfma_f32_16x16x32_bf16(a, b1, acc1, 0, 0, 0);
      acc2 = __builtin_amdgcn_mfma_f32_16x16x32_bf16(a, b2, acc2, 0, 0, 0);
      acc3 = __builtin_amdgcn_mfma_f32_16x16x32_bf16(a, b3, acc3, 0, 0, 0);
    }
  }
  v4f accs[4] = {acc0, acc1, acc2, acc3};
  #pragma unroll
  for (int nn = 0; nn < 4; nn++){
    int col = n0 + nn*16 + r15;
    float bv = bias[col];
    #pragma unroll
    for (int rr = 0; rr < 4; rr++){
      int row = m0 + kg*4 + rr;
      float v = accs[nn][rr] + bv + bf2f(X[(size_t)row*128 + col]);
      v = fmaxf(v, 0.0f);
      Y[(size_t)row*128 + col] = f2bf(v);
    }
  }
}

// ---------------- 1x1x1 head conv -> d_out [20][32768] ----------------
__global__ __launch_bounds__(256) void k_outconv(const u16* __restrict__ X,
    const float* __restrict__ W, const float* __restrict__ B, float* __restrict__ out)
{
  __shared__ float sw[20*128];
  __shared__ float sbb[20];
  int tid = threadIdx.x;
  for (int i = tid; i < 20*128; i += 256) sw[i] = W[i];
  if (tid < 20) sbb[tid] = B[tid];
  __syncthreads();
  int s = blockIdx.x*256 + tid;
  u32 rv[64];
  const u32* xp = (const u32*)(X + (size_t)s*128);
  #pragma unroll
  for (int j = 0; j < 64; j++) rv[j] = xp[j];
  for (int ot = 0; ot < 20; ot++){
    float acc = sbb[ot];
    #pragma unroll
    for (int j = 0; j < 64; j++){
      u32 u = rv[j];
      acc += bf2f((u16)(u & 0xffff))*sw[ot*128 + 2*j] + bf2f((u16)(u >> 16))*sw[ot*128 + 2*j + 1];
    }
    out[(size_t)ot*NQv + s] = acc;
  }
}

extern "C" void kernel_launch(void* const* d_in, const int* in_sizes, int n_in,
                              void* d_out, int out_size, void* d_ws, size_t ws_size,
                              hipStream_t stream)
{
  const float* iq    = (const float*)d_in[0];
  const float* logits= (const float*)d_in[1];
  const float* pmL   = (const float*)d_in[2];
  const float* depth = (const float*)d_in[3];
  const float* Km    = (const float*)d_in[4];
  const float* Em    = (const float*)d_in[5];
  const float* vo    = (const float*)d_in[6];
  const float* qe    = (const float*)d_in[7];
  const float* pe    = (const float*)d_in[8];
  const float* ain_w = (const float*)d_in[9];
  const float* ain_b = (const float*)d_in[10];
  const float* aout_w= (const float*)d_in[11];
  const float* aout_b= (const float*)d_in[12];
  const float* ln1g  = (const float*)d_in[13];
  const float* ln1b  = (const float*)d_in[14];
  const float* w1    = (const float*)d_in[15];
  const float* b1    = (const float*)d_in[16];
  const float* w2    = (const float*)d_in[17];
  const float* b2    = (const float*)d_in[18];
  const float* ln2g  = (const float*)d_in[19];
  const float* ln2b  = (const float*)d_in[20];
  const float* pw    = (const float*)d_in[21];
  const float* pb    = (const float*)d_in[22];
  const float* ow    = (const float*)d_in[23];
  const float* ob    = (const float*)d_in[24];
  const int*   fov   = (const int*)d_in[25];
  float* out = (float*)d_out;

  char* ws = (char*)d_ws;
  size_t off = 0;
  auto alloc = [&](size_t bytes) -> char* {
    char* p = ws + off;
    off = (off + bytes + 255) & ~(size_t)255;
    return p;
  };
  float* mats    = (float*)alloc(32*4);
  float* scores  = (float*)alloc(128*4);
  int*   keep0   = (int*)  alloc(128*4);
  int*   keep    = (int*)  alloc(128*4);
  int*   anyk    = (int*)  alloc(64);
  float* usef    = (float*)alloc(64);
  float* biasArr = (float*)alloc(128*4);
  float* xyz     = (float*)alloc(512*4);
  int*   mids    = (int*)  alloc((size_t)HWp*4);
  float* kvkb    = (float*)alloc((size_t)NI*128*4);
  float* khs     = (float*)alloc((size_t)3*4*NI*32*4);
  float* vhs     = (float*)alloc((size_t)3*4*NI*32*4);
  u16* ain_bf  = (u16*)alloc((size_t)3*384*128*2);
  u16* aout_bf = (u16*)alloc((size_t)3*128*128*2);
  u16* w1_bf   = (u16*)alloc((size_t)3*512*128*2);
  u16* w2_bf   = (u16*)alloc((size_t)3*128*512*2);
  u16* wc_bf   = (u16*)alloc((size_t)3*27*128*128*2);
  float* XF = (float*)alloc((size_t)NQv*128*4);
  float* T1 = (float*)alloc((size_t)NQv*128*4);
  float* T2 = (float*)alloc((size_t)NQv*128*4);   // doubles as residual stream
  u16*  XB = (u16*) alloc((size_t)NQv*128*2);     // xbf / attn-out / ln1_bf
  u16*  HB = (u16*) alloc((size_t)NQv*512*2);     // ffn hidden; later x3a/x3b
  u16* x3a = HB;
  u16* x3b = HB + (size_t)NQv*128;
  (void)ws_size; (void)in_sizes; (void)n_in; (void)out_size; (void)anyk;

  // ---- small prep ----
  k_prep_small<<<1,128,0,stream>>>(Km, Em, logits, mats, scores, keep0);
  k_mask_argmax<<<30,256,0,stream>>>(pmL, scores, keep0, mids);
  k_inst_stats<<<NI,256,0,stream>>>(pmL, mids, keep0, keep);
  k_finalize<<<1,128,0,stream>>>(keep, anyk, usef, biasArr);
  k_backproject<<<NI,256,0,stream>>>(depth, pmL, mids, keep, mats, xyz);
  k_kvk<<<(NI*128+255)/256,256,0,stream>>>(iq, pe, xyz, usef, kvkb);
  { dim3 g(NI,3); k_khvh<<<g,256,0,stream>>>(kvkb, iq, ain_w, ain_b, khs, vhs); }

  // ---- weight converts / packs ----
  k_f2bf<<<(3*384*128+255)/256,256,0,stream>>>(ain_w, ain_bf, 3*384*128);
  k_f2bf<<<(3*128*128+255)/256,256,0,stream>>>(aout_w, aout_bf, 3*128*128);
  k_f2bf<<<(3*512*128+255)/256,256,0,stream>>>(w1, w1_bf, 3*512*128);
  k_f2bf<<<(3*128*512+255)/256,256,0,stream>>>(w2, w2_bf, 3*128*512);
  k_packconv<<<(3*27*128*128+255)/256,256,0,stream>>>(pw, wc_bf, 3*27*128*128);

  // ---- 3 transformer layers ----
  for (int li = 0; li < 3; li++){
    const float* src = (li == 0) ? qe : T2;
    k_addpos<<<16384,256,0,stream>>>(src, pe, vo, XF, XB);
    dim3 g1(512,2);
    k_gemm<<<g1,256,0,stream>>>(XB, ain_bf + (size_t)li*384*128, ain_b + li*384,
                                nullptr, T1, nullptr, 128, 128, 0);
    k_attn<<<512,256,0,stream>>>(T1, khs + (size_t)li*4*NI*32, vhs + (size_t)li*4*NI*32,
                                 biasArr, XB);
    k_gemm<<<g1,256,0,stream>>>(XB, aout_bf + (size_t)li*128*128, aout_b + li*128,
                                XF, T2, nullptr, 128, 128, 0);
    k_ln<<<8192,256,0,stream>>>(T2, ln1g + li*128, ln1b + li*128, T1, XB);
    dim3 g2(512,8);
    k_gemm<<<g2,256,0,stream>>>(XB, w1_bf + (size_t)li*512*128, b1 + li*512,
                                nullptr, nullptr, HB, 512, 128, 1);
    k_gemm<<<g1,256,0,stream>>>(HB, w2_bf + (size_t)li*128*512, b2 + li*128,
                                T1, T2, nullptr, 128, 512, 0);
    k_ln<<<8192,256,0,stream>>>(T2, ln2g + li*128, ln2b + li*128, T2, nullptr);
  }

  // ---- fov select + conv stack ----
  k_fovsel<<<16384,256,0,stream>>>(T2, qe, fov, x3a);
  dim3 gc(512,2);
  k_conv<<<gc,256,0,stream>>>(x3a, wc_bf + (size_t)0*27*128*128, pb + 0,   x3b, 1);
  k_conv<<<gc,256,0,stream>>>(x3b, wc_bf + (size_t)1*27*128*128, pb + 128, x3a, 2);
  k_conv<<<gc,256,0,stream>>>(x3a, wc_bf + (size_t)2*27*128*128, pb + 256, x3b, 3);
  k_outconv<<<128,256,0,stream>>>(x3b, ow, ob, out);
}

// Round 2
// 702.652 us; speedup vs baseline: 2.0458x; 2.0458x over previous
//
#include <hip/hip_runtime.h>
#include <math.h>

typedef unsigned short u16;
typedef unsigned int   u32;

#define NQv 32768
#define HWp 7680
#define NI  100

typedef short v8s __attribute__((ext_vector_type(8)));
typedef float v4f __attribute__((ext_vector_type(4)));

__device__ inline float bf2f(u16 u){ u32 x = ((u32)u) << 16; return __uint_as_float(x); }
__device__ inline u16 f2bf(float f){
  u32 x = __float_as_uint(f);
  u32 r = (x + 0x7fffu + ((x >> 16) & 1u)) >> 16;
  return (u16)r;
}
__device__ inline float sigf(float x){ return 1.0f / (1.0f + expf(-x)); }

typedef const __attribute__((address_space(1))) void* gas_t;
typedef __attribute__((address_space(3))) void* las_t;

// ---------------- small prep: invert K (3x3) and E (4x4), instance scores ----------------
__global__ void k_prep_small(const float* __restrict__ Km, const float* __restrict__ Em,
                             const float* __restrict__ logits,
                             float* __restrict__ mats, float* __restrict__ scores,
                             int* __restrict__ keep0)
{
  int tid = threadIdx.x;
  if (tid == 0) {
    double a[9];
    for (int i = 0; i < 9; i++) a[i] = (double)Km[i];
    double det = a[0]*(a[4]*a[8]-a[5]*a[7]) - a[1]*(a[3]*a[8]-a[5]*a[6]) + a[2]*(a[3]*a[7]-a[4]*a[6]);
    double id = 1.0 / det;
    double inv[9];
    inv[0]=(a[4]*a[8]-a[5]*a[7])*id; inv[1]=(a[2]*a[7]-a[1]*a[8])*id; inv[2]=(a[1]*a[5]-a[2]*a[4])*id;
    inv[3]=(a[5]*a[6]-a[3]*a[8])*id; inv[4]=(a[0]*a[8]-a[2]*a[6])*id; inv[5]=(a[2]*a[3]-a[0]*a[5])*id;
    inv[6]=(a[3]*a[7]-a[4]*a[6])*id; inv[7]=(a[1]*a[6]-a[0]*a[7])*id; inv[8]=(a[0]*a[4]-a[1]*a[3])*id;
    for (int i = 0; i < 9; i++) mats[i] = (float)inv[i];
    double m[4][8];
    for (int r = 0; r < 4; r++){
      for (int c = 0; c < 4; c++){ m[r][c] = (double)Em[r*4+c]; m[r][4+c] = (r==c) ? 1.0 : 0.0; }
    }
    for (int col = 0; col < 4; col++){
      int piv = col; double best = fabs(m[col][col]);
      for (int r = col+1; r < 4; r++){ double v = fabs(m[r][col]); if (v > best){ best = v; piv = r; } }
      if (piv != col){ for (int c = 0; c < 8; c++){ double t = m[col][c]; m[col][c] = m[piv][c]; m[piv][c] = t; } }
      double p = m[col][col];
      for (int c = 0; c < 8; c++) m[col][c] /= p;
      for (int r = 0; r < 4; r++) if (r != col){ double f = m[r][col]; for (int c = 0; c < 8; c++) m[r][c] -= f*m[col][c]; }
    }
    for (int r = 0; r < 3; r++) for (int c = 0; c < 4; c++) mats[9 + r*4 + c] = (float)m[r][4+c];
  }
  if (tid < NI) {
    float mx = -1e30f;
    for (int c = 0; c < 21; c++){ float t = sigf(logits[tid*21+c]) / 0.06f; mx = fmaxf(mx, t); }
    float s = 0.f;
    for (int c = 0; c < 21; c++){ float t = sigf(logits[tid*21+c]) / 0.06f; s += expf(t - mx); }
    float sc = 1.0f / s;
    scores[tid] = sc;
    keep0[tid] = (sc > 0.25f) ? 1 : 0;
  }
}

__global__ void k_mask_argmax(const float* __restrict__ pmL, const float* __restrict__ scores,
                              const int* __restrict__ keep0, int* __restrict__ mids)
{
  int p = blockIdx.x*256 + threadIdx.x;
  if (p >= HWp) return;
  float best = -2e30f; int bid = 0;
  for (int i = 0; i < NI; i++){
    float lg = pmL[i*HWp + p];
    float val = keep0[i] ? scores[i] * sigf(lg) : -1.0f;
    if (val > best){ best = val; bid = i; }
  }
  mids[p] = bid;
}

__global__ void k_inst_stats(const float* __restrict__ pmL, const int* __restrict__ mids,
                             const int* __restrict__ keep0, int* __restrict__ keep)
{
  int i = blockIdx.x, tid = threadIdx.x;
  int k0 = keep0[i];
  int ma = 0, pa = 0, it = 0;
  for (int p = tid; p < HWp; p += 256){
    float lg = pmL[i*HWp + p];
    int pb = (lg >= 0.0f) ? 1 : 0;
    int mi = (mids[p] == i && k0) ? 1 : 0;
    ma += mi; pa += pb; it += (mi & pb);
  }
  __shared__ int sma[256], spa[256], sit[256];
  sma[tid] = ma; spa[tid] = pa; sit[tid] = it;
  __syncthreads();
  for (int off = 128; off; off >>= 1){
    if (tid < off){ sma[tid]+=sma[tid+off]; spa[tid]+=spa[tid+off]; sit[tid]+=sit[tid+off]; }
    __syncthreads();
  }
  if (tid == 0){
    keep[i] = (k0 && sit[0] > 0 && ((float)sma[0] >= 0.8f*(float)spa[0])) ? 1 : 0;
  }
}

__global__ void k_finalize(const int* __restrict__ keep, int* __restrict__ anyk,
                           float* __restrict__ usef, float* __restrict__ biasArr)
{
  int tid = threadIdx.x;
  __shared__ int s_any;
  if (tid == 0){
    int a = 0;
    for (int i = 0; i < NI; i++) a |= keep[i];
    s_any = a; anyk[0] = a; usef[0] = a ? 1.0f : 0.0f;
  }
  __syncthreads();
  if (tid < 128){
    float b;
    if (tid < NI) b = s_any ? (keep[tid] ? 0.0f : -1e9f) : 0.0f;
    else b = -1e9f;
    biasArr[tid] = b;
  }
}

__global__ void k_backproject(const float* __restrict__ depth, const float* __restrict__ pmL,
                              const int* __restrict__ mids, const int* __restrict__ keep,
                              const float* __restrict__ mats, float* __restrict__ xyz)
{
  int i = blockIdx.x, tid = threadIdx.x;
  float sx = 0.f, sy = 0.f, sz = 0.f;
  if (keep[i]){
    float ik0=mats[0],ik1=mats[1],ik2=mats[2],ik3=mats[3],ik4=mats[4],ik5=mats[5],ik6=mats[6],ik7=mats[7],ik8=mats[8];
    const float* iE = mats + 9;
    for (int p = tid; p < HWp; p += 256){
      if (mids[p] == i && pmL[i*HWp + p] >= 0.0f){
        int r = p / 160, c = p % 160;
        float xg = (float)((double)c * (1279.0/159.0));
        float yg = (float)((double)r * (383.0/47.0));
        float d = depth[p];
        float g0 = xg*d, g1 = yg*d, g2 = d;
        float c0 = ik0*g0 + ik1*g1 + ik2*g2;
        float c1 = ik3*g0 + ik4*g1 + ik5*g2;
        float c2 = ik6*g0 + ik7*g1 + ik8*g2;
        sx += iE[0]*c0 + iE[1]*c1 + iE[2]*c2 + iE[3];
        sy += iE[4]*c0 + iE[5]*c1 + iE[6]*c2 + iE[7];
        sz += iE[8]*c0 + iE[9]*c1 + iE[10]*c2 + iE[11];
      }
    }
  }
  __shared__ float rx[256], ry[256], rz[256];
  rx[tid]=sx; ry[tid]=sy; rz[tid]=sz;
  __syncthreads();
  for (int off = 128; off; off >>= 1){
    if (tid < off){ rx[tid]+=rx[tid+off]; ry[tid]+=ry[tid+off]; rz[tid]+=rz[tid+off]; }
    __syncthreads();
  }
  if (tid == 0){ xyz[i*3+0]=rx[0]; xyz[i*3+1]=ry[0]; xyz[i*3+2]=rz[0]; }
}

__global__ void k_kvk(const float* __restrict__ iq, const float* __restrict__ pe,
                      const float* __restrict__ xyz, const float* __restrict__ usef,
                      float* __restrict__ kvk)
{
  int idx = blockIdx.x*256 + threadIdx.x;
  if (idx >= NI*128) return;
  int i = idx >> 7, c = idx & 127;
  float u = usef[0];
  float ip = pe[c*3+0]*xyz[i*3+0] + pe[c*3+1]*xyz[i*3+1] + pe[c*3+2]*xyz[i*3+2];
  kvk[idx] = iq[idx] + u * ip;
}

// ---------------- K/V head projections, LDS-staged coalesced ----------------
// grid (3, 4): li, c-chunk of 64 within 0..255 (first 128 = K-proj, rest V-proj)
__global__ __launch_bounds__(512) void k_khvh2(const float* __restrict__ kvk,
    const float* __restrict__ iq, const float* __restrict__ Win,
    const float* __restrict__ bin, float* __restrict__ khs, float* __restrict__ vhs)
{
  __shared__ u16 s_in[NI][130];
  __shared__ u16 s_w[64][130];
  int li = blockIdx.x, c0 = blockIdx.y*64;
  bool isK = (c0 < 128);
  const float* srcIn = isK ? kvk : iq;
  int tid = threadIdx.x;
  for (int i = tid; i < NI*128; i += 512) s_in[i>>7][i&127] = f2bf(srcIn[i]);
  const float* wbase = Win + ((size_t)li*384 + 128 + c0)*128;
  for (int i = tid; i < 64*128; i += 512) s_w[i>>7][i&127] = f2bf(wbase[i]);
  __syncthreads();
  for (int o = tid; o < NI*64; o += 512){
    int k = o >> 6, c = o & 63;
    float acc = 0.f;
    #pragma unroll 8
    for (int j = 0; j < 128; j++) acc += bf2f(s_in[k][j]) * bf2f(s_w[c][j]);
    int cc = c0 + c;
    float v = acc + bin[li*384 + 128 + cc];
    int ch = cc & 127;
    size_t oi = (((size_t)li*4 + (ch>>5))*NI + k)*32 + (ch&31);
    if (isK) khs[oi] = v * 0.17677669529663687f;
    else     vhs[oi] = v;
  }
}

__global__ void k_addpos(const float* __restrict__ src, const float* __restrict__ pe,
                         const float* __restrict__ vo, float* __restrict__ xf,
                         u16* __restrict__ xbf)
{
  int idx = blockIdx.x*256 + threadIdx.x;
  int q = idx >> 7, c = idx & 127;
  float px = ((float)(q >> 9)       + 0.5f)*0.8f + vo[0];
  float py = ((float)((q >> 3)&63)  + 0.5f)*0.8f + vo[1];
  float pz = ((float)(q & 7)        + 0.5f)*0.8f + vo[2];
  float qp = pe[c*3+0]*px + pe[c*3+1]*py + pe[c*3+2]*pz;
  float v = src[idx] + qp;
  xf[idx] = v;
  xbf[idx] = f2bf(v);
}

__global__ void k_f2bf(const float* __restrict__ in, u16* __restrict__ out, int n)
{ int i = blockIdx.x*256 + threadIdx.x; if (i < n) out[i] = f2bf(in[i]); }

__global__ void k_packconv(const float* __restrict__ w, u16* __restrict__ wp, int n)
{
  int idx = blockIdx.x*256 + threadIdx.x;
  if (idx >= n) return;
  int i = idx & 127;
  int o = (idx >> 7) & 127;
  int lt = idx >> 14;
  int li = lt / 27, t = lt % 27;
  wp[idx] = f2bf(w[(((size_t)li*128 + o)*128 + i)*27 + t]);
}

__global__ void k_zero(u16* p){ p[threadIdx.x] = 0; }

// ================= tiled MFMA infrastructure =================
// LDS tile = 128 rows x 128 k bf16 (16384 u16 = 32 KB), staged linearly via
// global_load_lds with the XOR swizzle applied on the GLOBAL SOURCE column,
// reads apply the same XOR (rule #21: both-sides-or-neither).

__device__ inline void stage128(const u16* __restrict__ G, u16* lds,
                                int rbase, int pitchK, int kofs)
{
  int lane = threadIdx.x & 63, w = threadIdx.x >> 6;
  #pragma unroll
  for (int s = 0; s < 4; s++){
    int ldsOff = s*8192 + w*1024 + lane*16;   // bytes
    int row = ldsOff >> 8;
    int cb  = ldsOff & 255;
    int scb = cb ^ ((row & 7) << 4);
    const u16* src = G + (size_t)(rbase + row)*pitchK + kofs + (scb >> 1);
    u16* dst = lds + (s*4096 + w*512);        // u16 units, wave-uniform
    __builtin_amdgcn_global_load_lds((gas_t)src, (las_t)dst, 16, 0, 0);
  }
}

__device__ inline void stageConvA(const u16* __restrict__ X, const u16* __restrict__ zp,
                                  u16* lds, int m0, int dx, int dy, int dz)
{
  int lane = threadIdx.x & 63, w = threadIdx.x >> 6;
  #pragma unroll
  for (int s = 0; s < 4; s++){
    int ldsOff = s*8192 + w*1024 + lane*16;
    int row = ldsOff >> 8;
    int cb  = ldsOff & 255;
    int scb = cb ^ ((row & 7) << 4);
    int sidx = m0 + row;
    int xs = (sidx >> 9) + dx, ys = ((sidx >> 3) & 63) + dy, zs = (sidx & 7) + dz;
    bool ok = ((unsigned)xs < 64u) & ((unsigned)ys < 64u) & ((unsigned)zs < 8u);
    const u16* src = ok ? (X + (size_t)((xs*64+ys)*8+zs)*128 + (scb>>1)) : (zp + (scb>>1));
    u16* dst = lds + (s*4096 + w*512);
    __builtin_amdgcn_global_load_lds((gas_t)src, (las_t)dst, 16, 0, 0);
  }
}

__device__ inline v8s fragld(const u16* base, int row, int cb){
  return *(const v8s*)(base + row*128 + (((cb) ^ ((row & 7) << 4)) >> 1));
}

// one 128-K tile of MFMA for an 8-wave (4m x 2n) 128x128 block tile
__device__ inline void compute128(const u16* As, const u16* Bs,
                                  int wm, int wn, int r15, int kg, v4f acc[2][4])
{
  #pragma unroll
  for (int k0 = 0; k0 < 4; k0++){
    int cb = k0*64 + kg*16;
    v8s a0 = fragld(As, wm*32 +      r15, cb);
    v8s a1 = fragld(As, wm*32 + 16 + r15, cb);
    v8s b0 = fragld(Bs, wn*64 +      r15, cb);
    v8s b1 = fragld(Bs, wn*64 + 16 + r15, cb);
    v8s b2 = fragld(Bs, wn*64 + 32 + r15, cb);
    v8s b3 = fragld(Bs, wn*64 + 48 + r15, cb);
    acc[0][0] = __builtin_amdgcn_mfma_f32_16x16x32_bf16(a0, b0, acc[0][0], 0, 0, 0);
    acc[0][1] = __builtin_amdgcn_mfma_f32_16x16x32_bf16(a0, b1, acc[0][1], 0, 0, 0);
    acc[0][2] = __builtin_amdgcn_mfma_f32_16x16x32_bf16(a0, b2, acc[0][2], 0, 0, 0);
    acc[0][3] = __builtin_amdgcn_mfma_f32_16x16x32_bf16(a0, b3, acc[0][3], 0, 0, 0);
    acc[1][0] = __builtin_amdgcn_mfma_f32_16x16x32_bf16(a1, b0, acc[1][0], 0, 0, 0);
    acc[1][1] = __builtin_amdgcn_mfma_f32_16x16x32_bf16(a1, b1, acc[1][1], 0, 0, 0);
    acc[1][2] = __builtin_amdgcn_mfma_f32_16x16x32_bf16(a1, b2, acc[1][2], 0, 0, 0);
    acc[1][3] = __builtin_amdgcn_mfma_f32_16x16x32_bf16(a1, b3, acc[1][3], 0, 0, 0);
  }
}

// ---------------- tiled GEMM: out = act(A[M,K] @ B[N,K]^T + bias (+res)) ----------------
// grid (M/128, N/128), 512 threads. KT = K/128 k-tiles, double-buffered when KT>1.
__global__ __launch_bounds__(512) void k_gemm2(
    const u16* __restrict__ A, const u16* __restrict__ B,
    const float* __restrict__ bias, const float* __restrict__ res,
    float* __restrict__ outF, u16* __restrict__ outB,
    int N, int K, int KT, int act)
{
  extern __shared__ u16 smem[];
  int tid = threadIdx.x, lane = tid & 63, w = tid >> 6;
  int wm = w & 3, wn = w >> 2, r15 = lane & 15, kg = lane >> 4;
  int m0 = blockIdx.x*128, n0 = blockIdx.y*128;
  v4f acc[2][4] = {};
  stage128(A, smem + 0,     m0, K, 0);
  stage128(B, smem + 16384, n0, K, 0);
  __syncthreads();
  for (int kt = 0; kt < KT; kt++){
    int b = kt & 1;
    if (kt + 1 < KT){
      int b2 = b ^ 1;
      stage128(A, smem + b2*32768,         m0, K, (kt+1)*128);
      stage128(B, smem + b2*32768 + 16384, n0, K, (kt+1)*128);
    }
    compute128(smem + b*32768, smem + b*32768 + 16384, wm, wn, r15, kg, acc);
    __syncthreads();
  }
  #pragma unroll
  for (int i = 0; i < 2; i++){
    #pragma unroll
    for (int j = 0; j < 4; j++){
      int col = n0 + wn*64 + j*16 + r15;
      float bv = bias ? bias[col] : 0.0f;
      #pragma unroll
      for (int rr = 0; rr < 4; rr++){
        int row = m0 + wm*32 + i*16 + kg*4 + rr;
        float v = acc[i][j][rr] + bv;
        size_t oi = (size_t)row*N + col;
        if (res) v += res[oi];
        if (act == 1) v = 0.5f*v*(1.0f + erff(v*0.70710678118654752f));
        if (outF) outF[oi] = v;
        if (outB) outB[oi] = f2bf(v);
      }
    }
  }
}

// ---------------- dilated 3x3x3 conv, 27-tap implicit GEMM, LDS double-buffered ----------------
__global__ __launch_bounds__(512) void k_conv2(
    const u16* __restrict__ X, const u16* __restrict__ W,
    const float* __restrict__ bias, const u16* __restrict__ zp,
    u16* __restrict__ Y, int dil)
{
  extern __shared__ u16 smem[];
  int tid = threadIdx.x, lane = tid & 63, w = tid >> 6;
  int wm = w & 3, wn = w >> 2, r15 = lane & 15, kg = lane >> 4;
  int m0 = blockIdx.x*128;
  v4f acc[2][4] = {};
  stageConvA(X, zp, smem + 0, m0, -dil, -dil, -dil);
  stage128(W, smem + 16384, 0, 128, 0);
  __syncthreads();
  for (int t = 0; t < 27; t++){
    int b = t & 1;
    if (t + 1 < 27){
      int tn = t + 1, b2 = b ^ 1;
      int dx = (tn/9) - 1, dy = ((tn/3)%3) - 1, dz = (tn%3) - 1;
      stageConvA(X, zp, smem + b2*32768, m0, dx*dil, dy*dil, dz*dil);
      stage128(W + (size_t)tn*16384, smem + b2*32768 + 16384, 0, 128, 0);
    }
    compute128(smem + b*32768, smem + b*32768 + 16384, wm, wn, r15, kg, acc);
    __syncthreads();
  }
  #pragma unroll
  for (int i = 0; i < 2; i++){
    #pragma unroll
    for (int j = 0; j < 4; j++){
      int col = wn*64 + j*16 + r15;
      float bv = bias[col];
      #pragma unroll
      for (int rr = 0; rr < 4; rr++){
        int row = m0 + wm*32 + i*16 + kg*4 + rr;
        float v = acc[i][j][rr] + bv + bf2f(X[(size_t)row*128 + col]);
        v = fmaxf(v, 0.0f);
        Y[(size_t)row*128 + col] = f2bf(v);
      }
    }
  }
}

// ---------------- flash-style cross-attention ----------------
__global__ __launch_bounds__(256) void k_attn(
    const float* __restrict__ QH, const float* __restrict__ KH, const float* __restrict__ VH,
    const float* __restrict__ biasArr, u16* __restrict__ O)
{
  __shared__ u16 skh[4*NI*32];
  __shared__ u16 svh[4*NI*32];
  __shared__ float sb[NI];
  int tid = threadIdx.x;
  for (int i = tid; i < 4*NI*32; i += 256){ skh[i] = f2bf(KH[i]); svh[i] = f2bf(VH[i]); }
  if (tid < NI) sb[tid] = biasArr[tid];
  __syncthreads();
  int lane = tid & 63, h = tid >> 6;
  int q = blockIdx.x*64 + lane;
  float qh[32];
  const float4* qp = (const float4*)(QH + (size_t)q*128 + h*32);
  #pragma unroll
  for (int j = 0; j < 8; j++){
    float4 t = qp[j];
    qh[4*j] = t.x; qh[4*j+1] = t.y; qh[4*j+2] = t.z; qh[4*j+3] = t.w;
  }
  float m = -1e30f, l = 0.0f;
  float o[32];
  #pragma unroll
  for (int d = 0; d < 32; d++) o[d] = 0.0f;
  for (int k = 0; k < NI; k++){
    const uint4* kr = (const uint4*)&skh[(h*NI + k)*32];
    float s = sb[k];
    #pragma unroll
    for (int j = 0; j < 4; j++){
      uint4 u = kr[j];
      s += bf2f((u16)(u.x & 0xffff))*qh[8*j+0] + bf2f((u16)(u.x >> 16))*qh[8*j+1];
      s += bf2f((u16)(u.y & 0xffff))*qh[8*j+2] + bf2f((u16)(u.y >> 16))*qh[8*j+3];
      s += bf2f((u16)(u.z & 0xffff))*qh[8*j+4] + bf2f((u16)(u.z >> 16))*qh[8*j+5];
      s += bf2f((u16)(u.w & 0xffff))*qh[8*j+6] + bf2f((u16)(u.w >> 16))*qh[8*j+7];
    }
    float nm = fmaxf(m, s);
    float corr = __expf(m - nm);
    float p = __expf(s - nm);
    l = l*corr + p;
    m = nm;
    const uint4* vr = (const uint4*)&svh[(h*NI + k)*32];
    #pragma unroll
    for (int j = 0; j < 4; j++){
      uint4 u = vr[j];
      o[8*j+0] = o[8*j+0]*corr + p*bf2f((u16)(u.x & 0xffff));
      o[8*j+1] = o[8*j+1]*corr + p*bf2f((u16)(u.x >> 16));
      o[8*j+2] = o[8*j+2]*corr + p*bf2f((u16)(u.y & 0xffff));
      o[8*j+3] = o[8*j+3]*corr + p*bf2f((u16)(u.y >> 16));
      o[8*j+4] = o[8*j+4]*corr + p*bf2f((u16)(u.z & 0xffff));
      o[8*j+5] = o[8*j+5]*corr + p*bf2f((u16)(u.z >> 16));
      o[8*j+6] = o[8*j+6]*corr + p*bf2f((u16)(u.w & 0xffff));
      o[8*j+7] = o[8*j+7]*corr + p*bf2f((u16)(u.w >> 16));
    }
  }
  float inv = 1.0f / l;
  u32* op = (u32*)(O + (size_t)q*128 + h*32);
  #pragma unroll
  for (int j = 0; j < 16; j++){
    u16 lo = f2bf(o[2*j]*inv), hi = f2bf(o[2*j+1]*inv);
    op[j] = (u32)lo | ((u32)hi << 16);
  }
}

// ---------------- LayerNorm ----------------
__global__ __launch_bounds__(256) void k_ln(const float* __restrict__ in,
    const float* __restrict__ g, const float* __restrict__ b,
    float* __restrict__ outF, u16* __restrict__ outB)
{
  int lane = threadIdx.x & 63, wave = threadIdx.x >> 6;
  size_t row = (size_t)blockIdx.x*4 + wave;
  const float* ip = in + row*128;
  float v0 = ip[lane], v1 = ip[lane+64];
  float sum = v0 + v1;
  #pragma unroll
  for (int off = 32; off > 0; off >>= 1) sum += __shfl_xor(sum, off, 64);
  float mean = sum * (1.0f/128.0f);
  float d0 = v0 - mean, d1 = v1 - mean;
  float vs = d0*d0 + d1*d1;
  #pragma unroll
  for (int off = 32; off > 0; off >>= 1) vs += __shfl_xor(vs, off, 64);
  float rs = rsqrtf(vs*(1.0f/128.0f) + 1e-5f);
  float o0 = d0*rs*g[lane]    + b[lane];
  float o1 = d1*rs*g[lane+64] + b[lane+64];
  if (outF){ outF[row*128+lane] = o0; outF[row*128+lane+64] = o1; }
  if (outB){ outB[row*128+lane] = f2bf(o0); outB[row*128+lane+64] = f2bf(o1); }
}

__global__ void k_fovsel(const float* __restrict__ resid, const float* __restrict__ qe,
                         const int* __restrict__ fov, u16* __restrict__ x3)
{
  int idx = blockIdx.x*256 + threadIdx.x;
  int q = idx >> 7;
  float v = fov[q] ? resid[idx] : qe[idx];
  x3[idx] = f2bf(v);
}

// ---------------- 1x1x1 head conv -> d_out [20][32768] ----------------
__global__ __launch_bounds__(256) void k_outconv(const u16* __restrict__ X,
    const float* __restrict__ W, const float* __restrict__ B, float* __restrict__ out)
{
  __shared__ float sw[20*128];
  __shared__ float sbb[20];
  int tid = threadIdx.x;
  for (int i = tid; i < 20*128; i += 256) sw[i] = W[i];
  if (tid < 20) sbb[tid] = B[tid];
  __syncthreads();
  int s = blockIdx.x*256 + tid;
  u32 rv[64];
  const u32* xp = (const u32*)(X + (size_t)s*128);
  #pragma unroll
  for (int j = 0; j < 64; j++) rv[j] = xp[j];
  for (int ot = 0; ot < 20; ot++){
    float acc = sbb[ot];
    #pragma unroll
    for (int j = 0; j < 64; j++){
      u32 u = rv[j];
      acc += bf2f((u16)(u & 0xffff))*sw[ot*128 + 2*j] + bf2f((u16)(u >> 16))*sw[ot*128 + 2*j + 1];
    }
    out[(size_t)ot*NQv + s] = acc;
  }
}

extern "C" void kernel_launch(void* const* d_in, const int* in_sizes, int n_in,
                              void* d_out, int out_size, void* d_ws, size_t ws_size,
                              hipStream_t stream)
{
  const float* iq    = (const float*)d_in[0];
  const float* logits= (const float*)d_in[1];
  const float* pmL   = (const float*)d_in[2];
  const float* depth = (const float*)d_in[3];
  const float* Km    = (const float*)d_in[4];
  const float* Em    = (const float*)d_in[5];
  const float* vo    = (const float*)d_in[6];
  const float* qe    = (const float*)d_in[7];
  const float* pe    = (const float*)d_in[8];
  const float* ain_w = (const float*)d_in[9];
  const float* ain_b = (const float*)d_in[10];
  const float* aout_w= (const float*)d_in[11];
  const float* aout_b= (const float*)d_in[12];
  const float* ln1g  = (const float*)d_in[13];
  const float* ln1b  = (const float*)d_in[14];
  const float* w1    = (const float*)d_in[15];
  const float* b1    = (const float*)d_in[16];
  const float* w2    = (const float*)d_in[17];
  const float* b2    = (const float*)d_in[18];
  const float* ln2g  = (const float*)d_in[19];
  const float* ln2b  = (const float*)d_in[20];
  const float* pw    = (const float*)d_in[21];
  const float* pb    = (const float*)d_in[22];
  const float* ow    = (const float*)d_in[23];
  const float* ob    = (const float*)d_in[24];
  const int*   fov   = (const int*)d_in[25];
  float* out = (float*)d_out;

  (void)hipFuncSetAttribute((const void*)k_gemm2, hipFuncAttributeMaxDynamicSharedMemorySize, 131072);
  (void)hipFuncSetAttribute((const void*)k_conv2, hipFuncAttributeMaxDynamicSharedMemorySize, 131072);

  char* ws = (char*)d_ws;
  size_t off = 0;
  auto alloc = [&](size_t bytes) -> char* {
    char* p = ws + off;
    off = (off + bytes + 255) & ~(size_t)255;
    return p;
  };
  float* mats    = (float*)alloc(32*4);
  float* scores  = (float*)alloc(128*4);
  int*   keep0   = (int*)  alloc(128*4);
  int*   keep    = (int*)  alloc(128*4);
  int*   anyk    = (int*)  alloc(64);
  float* usef    = (float*)alloc(64);
  float* biasArr = (float*)alloc(128*4);
  float* xyz     = (float*)alloc(512*4);
  u16*   zp      = (u16*)  alloc(256);
  int*   mids    = (int*)  alloc((size_t)HWp*4);
  float* kvkb    = (float*)alloc((size_t)NI*128*4);
  float* khs     = (float*)alloc((size_t)3*4*NI*32*4);
  float* vhs     = (float*)alloc((size_t)3*4*NI*32*4);
  u16* ain_bf  = (u16*)alloc((size_t)3*384*128*2);
  u16* aout_bf = (u16*)alloc((size_t)3*128*128*2);
  u16* w1_bf   = (u16*)alloc((size_t)3*512*128*2);
  u16* w2_bf   = (u16*)alloc((size_t)3*128*512*2);
  u16* wc_bf   = (u16*)alloc((size_t)3*27*128*128*2);
  float* XF = (float*)alloc((size_t)NQv*128*4);
  float* T1 = (float*)alloc((size_t)NQv*128*4);
  float* T2 = (float*)alloc((size_t)NQv*128*4);
  u16*  XB = (u16*) alloc((size_t)NQv*128*2);
  u16*  HB = (u16*) alloc((size_t)NQv*512*2);
  u16* x3a = HB;
  u16* x3b = HB + (size_t)NQv*128;
  (void)ws_size; (void)in_sizes; (void)n_in; (void)out_size; (void)anyk;

  // ---- small prep ----
  k_prep_small<<<1,128,0,stream>>>(Km, Em, logits, mats, scores, keep0);
  k_zero<<<1,128,0,stream>>>(zp);
  k_mask_argmax<<<30,256,0,stream>>>(pmL, scores, keep0, mids);
  k_inst_stats<<<NI,256,0,stream>>>(pmL, mids, keep0, keep);
  k_finalize<<<1,128,0,stream>>>(keep, anyk, usef, biasArr);
  k_backproject<<<NI,256,0,stream>>>(depth, pmL, mids, keep, mats, xyz);
  k_kvk<<<(NI*128+255)/256,256,0,stream>>>(iq, pe, xyz, usef, kvkb);
  { dim3 g(3,4); k_khvh2<<<g,512,0,stream>>>(kvkb, iq, ain_w, ain_b, khs, vhs); }

  // ---- weight converts / packs ----
  k_f2bf<<<(3*384*128+255)/256,256,0,stream>>>(ain_w, ain_bf, 3*384*128);
  k_f2bf<<<(3*128*128+255)/256,256,0,stream>>>(aout_w, aout_bf, 3*128*128);
  k_f2bf<<<(3*512*128+255)/256,256,0,stream>>>(w1, w1_bf, 3*512*128);
  k_f2bf<<<(3*128*512+255)/256,256,0,stream>>>(w2, w2_bf, 3*128*512);
  k_packconv<<<(3*27*128*128+255)/256,256,0,stream>>>(pw, wc_bf, 3*27*128*128);

  // ---- 3 transformer layers ----
  for (int li = 0; li < 3; li++){
    const float* src = (li == 0) ? qe : T2;
    k_addpos<<<16384,256,0,stream>>>(src, pe, vo, XF, XB);
    k_gemm2<<<dim3(256,1),512,65536,stream>>>(XB, ain_bf + (size_t)li*384*128, ain_b + li*384,
                                              nullptr, T1, nullptr, 128, 128, 1, 0);
    k_attn<<<512,256,0,stream>>>(T1, khs + (size_t)li*4*NI*32, vhs + (size_t)li*4*NI*32,
                                 biasArr, XB);
    k_gemm2<<<dim3(256,1),512,65536,stream>>>(XB, aout_bf + (size_t)li*128*128, aout_b + li*128,
                                              XF, T2, nullptr, 128, 128, 1, 0);
    k_ln<<<8192,256,0,stream>>>(T2, ln1g + li*128, ln1b + li*128, T1, XB);
    k_gemm2<<<dim3(256,4),512,65536,stream>>>(XB, w1_bf + (size_t)li*512*128, b1 + li*512,
                                              nullptr, nullptr, HB, 512, 128, 1, 1);
    k_gemm2<<<dim3(256,1),512,131072,stream>>>(HB, w2_bf + (size_t)li*128*512, b2 + li*128,
                                               T1, T2, nullptr, 128, 512, 4, 0);
    k_ln<<<8192,256,0,stream>>>(T2, ln2g + li*128, ln2b + li*128, T2, nullptr);
  }

  // ---- fov select + conv stack ----
  k_fovsel<<<16384,256,0,stream>>>(T2, qe, fov, x3a);
  k_conv2<<<256,512,131072,stream>>>(x3a, wc_bf + (size_t)0*27*16384, pb + 0,   zp, x3b, 1);
  k_conv2<<<256,512,131072,stream>>>(x3b, wc_bf + (size_t)1*27*16384, pb + 128, zp, x3a, 2);
  k_conv2<<<256,512,131072,stream>>>(x3a, wc_bf + (size_t)2*27*16384, pb + 256, zp, x3b, 3);
  k_outconv<<<128,256,0,stream>>>(x3b, ow, ob, out);
}

// Round 3
// 558.075 us; speedup vs baseline: 2.5759x; 1.2591x over previous
//
#include <hip/hip_runtime.h>
#include <math.h>

typedef unsigned short u16;
typedef unsigned int   u32;

#define NQv 32768
#define HWp 7680
#define NI  100

typedef short v8s __attribute__((ext_vector_type(8)));
typedef float v4f __attribute__((ext_vector_type(4)));

__device__ inline float bf2f(u16 u){ u32 x = ((u32)u) << 16; return __uint_as_float(x); }
__device__ inline u16 f2bf(float f){
  u32 x = __float_as_uint(f);
  u32 r = (x + 0x7fffu + ((x >> 16) & 1u)) >> 16;
  return (u16)r;
}
__device__ inline float sigf(float x){ return 1.0f / (1.0f + expf(-x)); }

typedef const __attribute__((address_space(1))) void* gas_t;
typedef __attribute__((address_space(3))) void* las_t;

// ---------------- small prep: invert K (3x3) and E (4x4), instance scores ----------------
__global__ void k_prep_small(const float* __restrict__ Km, const float* __restrict__ Em,
                             const float* __restrict__ logits,
                             float* __restrict__ mats, float* __restrict__ scores,
                             int* __restrict__ keep0)
{
  int tid = threadIdx.x;
  if (tid == 0) {
    double a[9];
    for (int i = 0; i < 9; i++) a[i] = (double)Km[i];
    double det = a[0]*(a[4]*a[8]-a[5]*a[7]) - a[1]*(a[3]*a[8]-a[5]*a[6]) + a[2]*(a[3]*a[7]-a[4]*a[6]);
    double id = 1.0 / det;
    double inv[9];
    inv[0]=(a[4]*a[8]-a[5]*a[7])*id; inv[1]=(a[2]*a[7]-a[1]*a[8])*id; inv[2]=(a[1]*a[5]-a[2]*a[4])*id;
    inv[3]=(a[5]*a[6]-a[3]*a[8])*id; inv[4]=(a[0]*a[8]-a[2]*a[6])*id; inv[5]=(a[2]*a[3]-a[0]*a[5])*id;
    inv[6]=(a[3]*a[7]-a[4]*a[6])*id; inv[7]=(a[1]*a[6]-a[0]*a[7])*id; inv[8]=(a[0]*a[4]-a[1]*a[3])*id;
    for (int i = 0; i < 9; i++) mats[i] = (float)inv[i];
    double m[4][8];
    for (int r = 0; r < 4; r++){
      for (int c = 0; c < 4; c++){ m[r][c] = (double)Em[r*4+c]; m[r][4+c] = (r==c) ? 1.0 : 0.0; }
    }
    for (int col = 0; col < 4; col++){
      int piv = col; double best = fabs(m[col][col]);
      for (int r = col+1; r < 4; r++){ double v = fabs(m[r][col]); if (v > best){ best = v; piv = r; } }
      if (piv != col){ for (int c = 0; c < 8; c++){ double t = m[col][c]; m[col][c] = m[piv][c]; m[piv][c] = t; } }
      double p = m[col][col];
      for (int c = 0; c < 8; c++) m[col][c] /= p;
      for (int r = 0; r < 4; r++) if (r != col){ double f = m[r][col]; for (int c = 0; c < 8; c++) m[r][c] -= f*m[col][c]; }
    }
    for (int r = 0; r < 3; r++) for (int c = 0; c < 4; c++) mats[9 + r*4 + c] = (float)m[r][4+c];
  }
  if (tid < NI) {
    float mx = -1e30f;
    for (int c = 0; c < 21; c++){ float t = sigf(logits[tid*21+c]) / 0.06f; mx = fmaxf(mx, t); }
    float s = 0.f;
    for (int c = 0; c < 21; c++){ float t = sigf(logits[tid*21+c]) / 0.06f; s += expf(t - mx); }
    float sc = 1.0f / s;
    scores[tid] = sc;
    keep0[tid] = (sc > 0.25f) ? 1 : 0;
  }
}

__global__ void k_mask_argmax(const float* __restrict__ pmL, const float* __restrict__ scores,
                              const int* __restrict__ keep0, int* __restrict__ mids)
{
  int p = blockIdx.x*256 + threadIdx.x;
  if (p >= HWp) return;
  float best = -2e30f; int bid = 0;
  for (int i = 0; i < NI; i++){
    float lg = pmL[i*HWp + p];
    float val = keep0[i] ? scores[i] * sigf(lg) : -1.0f;
    if (val > best){ best = val; bid = i; }
  }
  mids[p] = bid;
}

__global__ void k_inst_stats(const float* __restrict__ pmL, const int* __restrict__ mids,
                             const int* __restrict__ keep0, int* __restrict__ keep)
{
  int i = blockIdx.x, tid = threadIdx.x;
  int k0 = keep0[i];
  int ma = 0, pa = 0, it = 0;
  for (int p = tid; p < HWp; p += 256){
    float lg = pmL[i*HWp + p];
    int pb = (lg >= 0.0f) ? 1 : 0;
    int mi = (mids[p] == i && k0) ? 1 : 0;
    ma += mi; pa += pb; it += (mi & pb);
  }
  __shared__ int sma[256], spa[256], sit[256];
  sma[tid] = ma; spa[tid] = pa; sit[tid] = it;
  __syncthreads();
  for (int off = 128; off; off >>= 1){
    if (tid < off){ sma[tid]+=sma[tid+off]; spa[tid]+=spa[tid+off]; sit[tid]+=sit[tid+off]; }
    __syncthreads();
  }
  if (tid == 0){
    keep[i] = (k0 && sit[0] > 0 && ((float)sma[0] >= 0.8f*(float)spa[0])) ? 1 : 0;
  }
}

__global__ void k_finalize(const int* __restrict__ keep, int* __restrict__ anyk,
                           float* __restrict__ usef, float* __restrict__ biasArr)
{
  int tid = threadIdx.x;
  __shared__ int s_any;
  if (tid == 0){
    int a = 0;
    for (int i = 0; i < NI; i++) a |= keep[i];
    s_any = a; anyk[0] = a; usef[0] = a ? 1.0f : 0.0f;
  }
  __syncthreads();
  if (tid < 128){
    float b;
    if (tid < NI) b = s_any ? (keep[tid] ? 0.0f : -1e9f) : 0.0f;
    else b = -1e9f;
    biasArr[tid] = b;
  }
}

__global__ void k_backproject(const float* __restrict__ depth, const float* __restrict__ pmL,
                              const int* __restrict__ mids, const int* __restrict__ keep,
                              const float* __restrict__ mats, float* __restrict__ xyz)
{
  int i = blockIdx.x, tid = threadIdx.x;
  float sx = 0.f, sy = 0.f, sz = 0.f;
  if (keep[i]){
    float ik0=mats[0],ik1=mats[1],ik2=mats[2],ik3=mats[3],ik4=mats[4],ik5=mats[5],ik6=mats[6],ik7=mats[7],ik8=mats[8];
    const float* iE = mats + 9;
    for (int p = tid; p < HWp; p += 256){
      if (mids[p] == i && pmL[i*HWp + p] >= 0.0f){
        int r = p / 160, c = p % 160;
        float xg = (float)((double)c * (1279.0/159.0));
        float yg = (float)((double)r * (383.0/47.0));
        float d = depth[p];
        float g0 = xg*d, g1 = yg*d, g2 = d;
        float c0 = ik0*g0 + ik1*g1 + ik2*g2;
        float c1 = ik3*g0 + ik4*g1 + ik5*g2;
        float c2 = ik6*g0 + ik7*g1 + ik8*g2;
        sx += iE[0]*c0 + iE[1]*c1 + iE[2]*c2 + iE[3];
        sy += iE[4]*c0 + iE[5]*c1 + iE[6]*c2 + iE[7];
        sz += iE[8]*c0 + iE[9]*c1 + iE[10]*c2 + iE[11];
      }
    }
  }
  __shared__ float rx[256], ry[256], rz[256];
  rx[tid]=sx; ry[tid]=sy; rz[tid]=sz;
  __syncthreads();
  for (int off = 128; off; off >>= 1){
    if (tid < off){ rx[tid]+=rx[tid+off]; ry[tid]+=ry[tid+off]; rz[tid]+=rz[tid+off]; }
    __syncthreads();
  }
  if (tid == 0){ xyz[i*3+0]=rx[0]; xyz[i*3+1]=ry[0]; xyz[i*3+2]=rz[0]; }
}

__global__ void k_kvk(const float* __restrict__ iq, const float* __restrict__ pe,
                      const float* __restrict__ xyz, const float* __restrict__ usef,
                      float* __restrict__ kvk)
{
  int idx = blockIdx.x*256 + threadIdx.x;
  if (idx >= NI*128) return;
  int i = idx >> 7, c = idx & 127;
  float u = usef[0];
  float ip = pe[c*3+0]*xyz[i*3+0] + pe[c*3+1]*xyz[i*3+1] + pe[c*3+2]*xyz[i*3+2];
  kvk[idx] = iq[idx] + u * ip;
}

__global__ void k_zerobuf(u16* p, int n){ int i = blockIdx.x*256+threadIdx.x; if (i<n) p[i]=0; }

// ---------------- K/V head projections -> bf16 MFMA-ready layouts ----------------
// khs_bf: [li][h][128 keys (pad0)][32 dims], K pre-scaled by 1/sqrt(32)
// vt_bf : [li][h][32 dims][128 keys (pad0)]
__global__ __launch_bounds__(512) void k_khvh2(const float* __restrict__ kvk,
    const float* __restrict__ iq, const float* __restrict__ Win,
    const float* __restrict__ bin, u16* __restrict__ khs_bf, u16* __restrict__ vt_bf)
{
  __shared__ u16 s_in[NI][130];
  __shared__ u16 s_w[64][130];
  int li = blockIdx.x, c0 = blockIdx.y*64;
  bool isK = (c0 < 128);
  const float* srcIn = isK ? kvk : iq;
  int tid = threadIdx.x;
  for (int i = tid; i < NI*128; i += 512) s_in[i>>7][i&127] = f2bf(srcIn[i]);
  const float* wbase = Win + ((size_t)li*384 + 128 + c0)*128;
  for (int i = tid; i < 64*128; i += 512) s_w[i>>7][i&127] = f2bf(wbase[i]);
  __syncthreads();
  for (int o = tid; o < NI*64; o += 512){
    int k = o >> 6, c = o & 63;
    float acc = 0.f;
    #pragma unroll 8
    for (int j = 0; j < 128; j++) acc += bf2f(s_in[k][j]) * bf2f(s_w[c][j]);
    int cc = c0 + c;
    float v = acc + bin[li*384 + 128 + cc];
    int ch = cc & 127;
    if (isK) khs_bf[(((size_t)li*4 + (ch>>5))*128 + k)*32 + (ch&31)] = f2bf(v * 0.17677669529663687f);
    else     vt_bf [(((size_t)li*4 + (ch>>5))*32 + (ch&31))*128 + k] = f2bf(v);
  }
}

__global__ void k_addpos(const float* __restrict__ src, const float* __restrict__ pe,
                         const float* __restrict__ vo, float* __restrict__ xf,
                         u16* __restrict__ xbf)
{
  int idx = blockIdx.x*256 + threadIdx.x;
  int q = idx >> 7, c = idx & 127;
  float px = ((float)(q >> 9)       + 0.5f)*0.8f + vo[0];
  float py = ((float)((q >> 3)&63)  + 0.5f)*0.8f + vo[1];
  float pz = ((float)(q & 7)        + 0.5f)*0.8f + vo[2];
  float qp = pe[c*3+0]*px + pe[c*3+1]*py + pe[c*3+2]*pz;
  float v = src[idx] + qp;
  xf[idx] = v;
  xbf[idx] = f2bf(v);
}

__global__ void k_f2bf(const float* __restrict__ in, u16* __restrict__ out, int n)
{ int i = blockIdx.x*256 + threadIdx.x; if (i < n) out[i] = f2bf(in[i]); }

__global__ void k_packconv(const float* __restrict__ w, u16* __restrict__ wp, int n)
{
  int idx = blockIdx.x*256 + threadIdx.x;
  if (idx >= n) return;
  int i = idx & 127;
  int o = (idx >> 7) & 127;
  int lt = idx >> 14;
  int li = lt / 27, t = lt % 27;
  wp[idx] = f2bf(w[(((size_t)li*128 + o)*128 + i)*27 + t]);
}

__global__ void k_zero(u16* p){ p[threadIdx.x] = 0; }

// ================= tiled MFMA infrastructure =================
__device__ inline void stage128(const u16* __restrict__ G, u16* lds,
                                int rbase, int pitchK, int kofs)
{
  int lane = threadIdx.x & 63, w = threadIdx.x >> 6;
  #pragma unroll
  for (int s = 0; s < 4; s++){
    int ldsOff = s*8192 + w*1024 + lane*16;   // bytes
    int row = ldsOff >> 8;
    int cb  = ldsOff & 255;
    int scb = cb ^ ((row & 7) << 4);
    const u16* src = G + (size_t)(rbase + row)*pitchK + kofs + (scb >> 1);
    u16* dst = lds + (s*4096 + w*512);        // u16 units, wave-uniform
    __builtin_amdgcn_global_load_lds((gas_t)src, (las_t)dst, 16, 0, 0);
  }
}

__device__ inline void stageConvA(const u16* __restrict__ X, const u16* __restrict__ zp,
                                  u16* lds, int m0, int dx, int dy, int dz)
{
  int lane = threadIdx.x & 63, w = threadIdx.x >> 6;
  #pragma unroll
  for (int s = 0; s < 4; s++){
    int ldsOff = s*8192 + w*1024 + lane*16;
    int row = ldsOff >> 8;
    int cb  = ldsOff & 255;
    int scb = cb ^ ((row & 7) << 4);
    int sidx = m0 + row;
    int xs = (sidx >> 9) + dx, ys = ((sidx >> 3) & 63) + dy, zs = (sidx & 7) + dz;
    bool ok = ((unsigned)xs < 64u) & ((unsigned)ys < 64u) & ((unsigned)zs < 8u);
    const u16* src = ok ? (X + (size_t)((xs*64+ys)*8+zs)*128 + (scb>>1)) : (zp + (scb>>1));
    u16* dst = lds + (s*4096 + w*512);
    __builtin_amdgcn_global_load_lds((gas_t)src, (las_t)dst, 16, 0, 0);
  }
}

__device__ inline v8s fragld(const u16* base, int row, int cb){
  return *(const v8s*)(base + row*128 + (((cb) ^ ((row & 7) << 4)) >> 1));
}

__device__ inline void compute128(const u16* As, const u16* Bs,
                                  int wm, int wn, int r15, int kg, v4f acc[2][4])
{
  #pragma unroll
  for (int k0 = 0; k0 < 4; k0++){
    int cb = k0*64 + kg*16;
    v8s a0 = fragld(As, wm*32 +      r15, cb);
    v8s a1 = fragld(As, wm*32 + 16 + r15, cb);
    v8s b0 = fragld(Bs, wn*64 +      r15, cb);
    v8s b1 = fragld(Bs, wn*64 + 16 + r15, cb);
    v8s b2 = fragld(Bs, wn*64 + 32 + r15, cb);
    v8s b3 = fragld(Bs, wn*64 + 48 + r15, cb);
    acc[0][0] = __builtin_amdgcn_mfma_f32_16x16x32_bf16(a0, b0, acc[0][0], 0, 0, 0);
    acc[0][1] = __builtin_amdgcn_mfma_f32_16x16x32_bf16(a0, b1, acc[0][1], 0, 0, 0);
    acc[0][2] = __builtin_amdgcn_mfma_f32_16x16x32_bf16(a0, b2, acc[0][2], 0, 0, 0);
    acc[0][3] = __builtin_amdgcn_mfma_f32_16x16x32_bf16(a0, b3, acc[0][3], 0, 0, 0);
    acc[1][0] = __builtin_amdgcn_mfma_f32_16x16x32_bf16(a1, b0, acc[1][0], 0, 0, 0);
    acc[1][1] = __builtin_amdgcn_mfma_f32_16x16x32_bf16(a1, b1, acc[1][1], 0, 0, 0);
    acc[1][2] = __builtin_amdgcn_mfma_f32_16x16x32_bf16(a1, b2, acc[1][2], 0, 0, 0);
    acc[1][3] = __builtin_amdgcn_mfma_f32_16x16x32_bf16(a1, b3, acc[1][3], 0, 0, 0);
  }
}

// ---------------- tiled GEMM ----------------
__global__ __launch_bounds__(512) void k_gemm2(
    const u16* __restrict__ A, const u16* __restrict__ B,
    const float* __restrict__ bias, const float* __restrict__ res,
    float* __restrict__ outF, u16* __restrict__ outB,
    int N, int K, int KT, int act)
{
  extern __shared__ u16 smem[];
  int tid = threadIdx.x, lane = tid & 63, w = tid >> 6;
  int wm = w & 3, wn = w >> 2, r15 = lane & 15, kg = lane >> 4;
  int m0 = blockIdx.x*128, n0 = blockIdx.y*128;
  v4f acc[2][4] = {};
  stage128(A, smem + 0,     m0, K, 0);
  stage128(B, smem + 16384, n0, K, 0);
  __syncthreads();
  for (int kt = 0; kt < KT; kt++){
    int b = kt & 1;
    if (kt + 1 < KT){
      int b2 = b ^ 1;
      stage128(A, smem + b2*32768,         m0, K, (kt+1)*128);
      stage128(B, smem + b2*32768 + 16384, n0, K, (kt+1)*128);
    }
    compute128(smem + b*32768, smem + b*32768 + 16384, wm, wn, r15, kg, acc);
    __syncthreads();
  }
  #pragma unroll
  for (int i = 0; i < 2; i++){
    #pragma unroll
    for (int j = 0; j < 4; j++){
      int col = n0 + wn*64 + j*16 + r15;
      float bv = bias ? bias[col] : 0.0f;
      #pragma unroll
      for (int rr = 0; rr < 4; rr++){
        int row = m0 + wm*32 + i*16 + kg*4 + rr;
        float v = acc[i][j][rr] + bv;
        size_t oi = (size_t)row*N + col;
        if (res) v += res[oi];
        if (act == 1) v = 0.5f*v*(1.0f + erff(v*0.70710678118654752f));
        if (outF) outF[oi] = v;
        if (outB) outB[oi] = f2bf(v);
      }
    }
  }
}

// ---------------- dilated 3x3x3 conv ----------------
__global__ __launch_bounds__(512) void k_conv2(
    const u16* __restrict__ X, const u16* __restrict__ W,
    const float* __restrict__ bias, const u16* __restrict__ zp,
    u16* __restrict__ Y, int dil)
{
  extern __shared__ u16 smem[];
  int tid = threadIdx.x, lane = tid & 63, w = tid >> 6;
  int wm = w & 3, wn = w >> 2, r15 = lane & 15, kg = lane >> 4;
  int m0 = blockIdx.x*128;
  v4f acc[2][4] = {};
  stageConvA(X, zp, smem + 0, m0, -dil, -dil, -dil);
  stage128(W, smem + 16384, 0, 128, 0);
  __syncthreads();
  for (int t = 0; t < 27; t++){
    int b = t & 1;
    if (t + 1 < 27){
      int tn = t + 1, b2 = b ^ 1;
      int dx = (tn/9) - 1, dy = ((tn/3)%3) - 1, dz = (tn%3) - 1;
      stageConvA(X, zp, smem + b2*32768, m0, dx*dil, dy*dil, dz*dil);
      stage128(W + (size_t)tn*16384, smem + b2*32768 + 16384, 0, 128, 0);
    }
    compute128(smem + b*32768, smem + b*32768 + 16384, wm, wn, r15, kg, acc);
    __syncthreads();
  }
  #pragma unroll
  for (int i = 0; i < 2; i++){
    #pragma unroll
    for (int j = 0; j < 4; j++){
      int col = wn*64 + j*16 + r15;
      float bv = bias[col];
      #pragma unroll
      for (int rr = 0; rr < 4; rr++){
        int row = m0 + wm*32 + i*16 + kg*4 + rr;
        float v = acc[i][j][rr] + bv + bf2f(X[(size_t)row*128 + col]);
        v = fmaxf(v, 0.0f);
        Y[(size_t)row*128 + col] = f2bf(v);
      }
    }
  }
}

// ---------------- MFMA cross-attention: 1 wave = 1 head x 64 queries ----------------
// QB: bf16 [NQ][128] q-projection. KH: bf16 [4][128][32] (pre-scaled, zero-pad keys>=100,
// biasArr[k>=100] = -1e9). VT: bf16 [4][32][128]. O: bf16 [NQ][128].
__global__ __launch_bounds__(256) void k_attn2(
    const u16* __restrict__ QB, const u16* __restrict__ KH, const u16* __restrict__ VT,
    const float* __restrict__ biasArr, u16* __restrict__ O)
{
  __shared__ float sb[128];
  __shared__ u16 sp[4][32*128];   // per-wave P buffer, XOR-swizzled rows
  int tid = threadIdx.x, lane = tid & 63, w = tid >> 6;
  if (tid < 128) sb[tid] = biasArr[tid];
  __syncthreads();
  int c = lane & 15, r = lane >> 4;
  int q0 = blockIdx.x * 64;
  const u16* Kh = KH + (size_t)w*128*32;
  const u16* Vh = VT + (size_t)w*32*128;
  char* spw = (char*)&sp[w][0];

  v8s kf[8];
  #pragma unroll
  for (int kt = 0; kt < 8; kt++) kf[kt] = *(const v8s*)(Kh + (kt*16 + c)*32 + r*8);
  v8s vf[4][2];
  #pragma unroll
  for (int ks = 0; ks < 4; ks++)
    #pragma unroll
    for (int dt = 0; dt < 2; dt++)
      vf[ks][dt] = *(const v8s*)(Vh + (dt*16 + c)*128 + ks*32 + r*8);
  float bv[8][4];
  #pragma unroll
  for (int kt = 0; kt < 8; kt++){
    float4 t = *(const float4*)&sb[kt*16 + r*4];
    bv[kt][0] = t.x; bv[kt][1] = t.y; bv[kt][2] = t.z; bv[kt][3] = t.w;
  }

  #pragma unroll
  for (int half = 0; half < 2; half++){
    v4f s[2][8] = {};
    #pragma unroll
    for (int qt2 = 0; qt2 < 2; qt2++){
      int qt = half*2 + qt2;
      v8s qf = *(const v8s*)(QB + (size_t)(q0 + qt*16 + c)*128 + w*32 + r*8);
      #pragma unroll
      for (int kt = 0; kt < 8; kt++)
        s[qt2][kt] = __builtin_amdgcn_mfma_f32_16x16x32_bf16(kf[kt], qf, s[qt2][kt], 0, 0, 0);
    }
    #pragma unroll
    for (int qt2 = 0; qt2 < 2; qt2++){
      float mx = -1e30f;
      #pragma unroll
      for (int kt = 0; kt < 8; kt++)
        #pragma unroll
        for (int rg = 0; rg < 4; rg++){
          s[qt2][kt][rg] += bv[kt][rg];
          mx = fmaxf(mx, s[qt2][kt][rg]);
        }
      mx = fmaxf(mx, __shfl_xor(mx, 16, 64));
      mx = fmaxf(mx, __shfl_xor(mx, 32, 64));
      float sum = 0.f;
      #pragma unroll
      for (int kt = 0; kt < 8; kt++)
        #pragma unroll
        for (int rg = 0; rg < 4; rg++){
          float p = __expf(s[qt2][kt][rg] - mx);
          s[qt2][kt][rg] = p;
          sum += p;
        }
      sum += __shfl_xor(sum, 16, 64);
      sum += __shfl_xor(sum, 32, 64);
      float inv = 1.0f / sum;
      int row = qt2*16 + c;
      int rbyte = row*256;
      int rx = (row & 7) << 4;
      #pragma unroll
      for (int kt = 0; kt < 8; kt++){
        #pragma unroll
        for (int pr = 0; pr < 2; pr++){
          u32 pk = (u32)f2bf(s[qt2][kt][pr*2]*inv) | ((u32)f2bf(s[qt2][kt][pr*2+1]*inv) << 16);
          int colb = kt*32 + r*8 + pr*4;
          *(u32*)(spw + rbyte + (colb ^ rx)) = pk;
        }
      }
    }
    // PV: O[64x32] += P[64x128] @ V[128x32]
    v4f o[2][2] = {};
    #pragma unroll
    for (int ks = 0; ks < 4; ks++){
      #pragma unroll
      for (int qt2 = 0; qt2 < 2; qt2++){
        int row = qt2*16 + c;
        int colb = ks*64 + r*16;
        v8s aP = *(const v8s*)(spw + row*256 + (colb ^ ((row & 7) << 4)));
        o[qt2][0] = __builtin_amdgcn_mfma_f32_16x16x32_bf16(aP, vf[ks][0], o[qt2][0], 0, 0, 0);
        o[qt2][1] = __builtin_amdgcn_mfma_f32_16x16x32_bf16(aP, vf[ks][1], o[qt2][1], 0, 0, 0);
      }
    }
    #pragma unroll
    for (int qt2 = 0; qt2 < 2; qt2++){
      #pragma unroll
      for (int dt = 0; dt < 2; dt++){
        #pragma unroll
        for (int rg = 0; rg < 4; rg++){
          int qq = q0 + (half*2 + qt2)*16 + r*4 + rg;
          O[(size_t)qq*128 + w*32 + dt*16 + c] = f2bf(o[qt2][dt][rg]);
        }
      }
    }
  }
}

// ---------------- LayerNorm ----------------
__global__ __launch_bounds__(256) void k_ln(const float* __restrict__ in,
    const float* __restrict__ g, const float* __restrict__ b,
    float* __restrict__ outF, u16* __restrict__ outB)
{
  int lane = threadIdx.x & 63, wave = threadIdx.x >> 6;
  size_t row = (size_t)blockIdx.x*4 + wave;
  const float* ip = in + row*128;
  float v0 = ip[lane], v1 = ip[lane+64];
  float sum = v0 + v1;
  #pragma unroll
  for (int off = 32; off > 0; off >>= 1) sum += __shfl_xor(sum, off, 64);
  float mean = sum * (1.0f/128.0f);
  float d0 = v0 - mean, d1 = v1 - mean;
  float vs = d0*d0 + d1*d1;
  #pragma unroll
  for (int off = 32; off > 0; off >>= 1) vs += __shfl_xor(vs, off, 64);
  float rs = rsqrtf(vs*(1.0f/128.0f) + 1e-5f);
  float o0 = d0*rs*g[lane]    + b[lane];
  float o1 = d1*rs*g[lane+64] + b[lane+64];
  if (outF){ outF[row*128+lane] = o0; outF[row*128+lane+64] = o1; }
  if (outB){ outB[row*128+lane] = f2bf(o0); outB[row*128+lane+64] = f2bf(o1); }
}

__global__ void k_fovsel(const float* __restrict__ resid, const float* __restrict__ qe,
                         const int* __restrict__ fov, u16* __restrict__ x3)
{
  int idx = blockIdx.x*256 + threadIdx.x;
  int q = idx >> 7;
  float v = fov[q] ? resid[idx] : qe[idx];
  x3[idx] = f2bf(v);
}

// ---------------- 1x1x1 head conv -> d_out [20][32768] ----------------
__global__ __launch_bounds__(256) void k_outconv(const u16* __restrict__ X,
    const float* __restrict__ W, const float* __restrict__ B, float* __restrict__ out)
{
  __shared__ float sw[20*128];
  __shared__ float sbb[20];
  int tid = threadIdx.x;
  for (int i = tid; i < 20*128; i += 256) sw[i] = W[i];
  if (tid < 20) sbb[tid] = B[tid];
  __syncthreads();
  int s = blockIdx.x*256 + tid;
  u32 rv[64];
  const u32* xp = (const u32*)(X + (size_t)s*128);
  #pragma unroll
  for (int j = 0; j < 64; j++) rv[j] = xp[j];
  for (int ot = 0; ot < 20; ot++){
    float acc = sbb[ot];
    #pragma unroll
    for (int j = 0; j < 64; j++){
      u32 u = rv[j];
      acc += bf2f((u16)(u & 0xffff))*sw[ot*128 + 2*j] + bf2f((u16)(u >> 16))*sw[ot*128 + 2*j + 1];
    }
    out[(size_t)ot*NQv + s] = acc;
  }
}

extern "C" void kernel_launch(void* const* d_in, const int* in_sizes, int n_in,
                              void* d_out, int out_size, void* d_ws, size_t ws_size,
                              hipStream_t stream)
{
  const float* iq    = (const float*)d_in[0];
  const float* logits= (const float*)d_in[1];
  const float* pmL   = (const float*)d_in[2];
  const float* depth = (const float*)d_in[3];
  const float* Km    = (const float*)d_in[4];
  const float* Em    = (const float*)d_in[5];
  const float* vo    = (const float*)d_in[6];
  const float* qe    = (const float*)d_in[7];
  const float* pe    = (const float*)d_in[8];
  const float* ain_w = (const float*)d_in[9];
  const float* ain_b = (const float*)d_in[10];
  const float* aout_w= (const float*)d_in[11];
  const float* aout_b= (const float*)d_in[12];
  const float* ln1g  = (const float*)d_in[13];
  const float* ln1b  = (const float*)d_in[14];
  const float* w1    = (const float*)d_in[15];
  const float* b1    = (const float*)d_in[16];
  const float* w2    = (const float*)d_in[17];
  const float* b2    = (const float*)d_in[18];
  const float* ln2g  = (const float*)d_in[19];
  const float* ln2b  = (const float*)d_in[20];
  const float* pw    = (const float*)d_in[21];
  const float* pb    = (const float*)d_in[22];
  const float* ow    = (const float*)d_in[23];
  const float* ob    = (const float*)d_in[24];
  const int*   fov   = (const int*)d_in[25];
  float* out = (float*)d_out;

  (void)hipFuncSetAttribute((const void*)k_gemm2, hipFuncAttributeMaxDynamicSharedMemorySize, 131072);
  (void)hipFuncSetAttribute((const void*)k_conv2, hipFuncAttributeMaxDynamicSharedMemorySize, 131072);

  char* ws = (char*)d_ws;
  size_t off = 0;
  auto alloc = [&](size_t bytes) -> char* {
    char* p = ws + off;
    off = (off + bytes + 255) & ~(size_t)255;
    return p;
  };
  float* mats    = (float*)alloc(32*4);
  float* scores  = (float*)alloc(128*4);
  int*   keep0   = (int*)  alloc(128*4);
  int*   keep    = (int*)  alloc(128*4);
  int*   anyk    = (int*)  alloc(64);
  float* usef    = (float*)alloc(64);
  float* biasArr = (float*)alloc(128*4);
  float* xyz     = (float*)alloc(512*4);
  u16*   zp      = (u16*)  alloc(256);
  int*   mids    = (int*)  alloc((size_t)HWp*4);
  float* kvkb    = (float*)alloc((size_t)NI*128*4);
  u16* khs_bf  = (u16*)alloc((size_t)3*4*128*32*2);
  u16* vt_bf   = (u16*)alloc((size_t)3*4*32*128*2);
  u16* ain_bf  = (u16*)alloc((size_t)3*384*128*2);
  u16* aout_bf = (u16*)alloc((size_t)3*128*128*2);
  u16* w1_bf   = (u16*)alloc((size_t)3*512*128*2);
  u16* w2_bf   = (u16*)alloc((size_t)3*128*512*2);
  u16* wc_bf   = (u16*)alloc((size_t)3*27*128*128*2);
  float* XF = (float*)alloc((size_t)NQv*128*4);
  float* T1 = (float*)alloc((size_t)NQv*128*4);
  float* T2 = (float*)alloc((size_t)NQv*128*4);
  u16*  XB = (u16*) alloc((size_t)NQv*128*2);
  u16*  HB = (u16*) alloc((size_t)NQv*512*2);
  u16* QB  = HB;                       // q-projection bf16 (HB free until FFN1)
  u16* x3a = HB;
  u16* x3b = HB + (size_t)NQv*128;
  (void)ws_size; (void)in_sizes; (void)n_in; (void)out_size; (void)anyk;

  // ---- small prep ----
  k_prep_small<<<1,128,0,stream>>>(Km, Em, logits, mats, scores, keep0);
  k_zero<<<1,128,0,stream>>>(zp);
  k_mask_argmax<<<30,256,0,stream>>>(pmL, scores, keep0, mids);
  k_inst_stats<<<NI,256,0,stream>>>(pmL, mids, keep0, keep);
  k_finalize<<<1,128,0,stream>>>(keep, anyk, usef, biasArr);
  k_backproject<<<NI,256,0,stream>>>(depth, pmL, mids, keep, mats, xyz);
  k_kvk<<<(NI*128+255)/256,256,0,stream>>>(iq, pe, xyz, usef, kvkb);
  k_zerobuf<<<(2*3*4*128*32+255)/256,256,0,stream>>>(khs_bf, 2*3*4*128*32);
  { dim3 g(3,4); k_khvh2<<<g,512,0,stream>>>(kvkb, iq, ain_w, ain_b, khs_bf, vt_bf); }

  // ---- weight converts / packs ----
  k_f2bf<<<(3*384*128+255)/256,256,0,stream>>>(ain_w, ain_bf, 3*384*128);
  k_f2bf<<<(3*128*128+255)/256,256,0,stream>>>(aout_w, aout_bf, 3*128*128);
  k_f2bf<<<(3*512*128+255)/256,256,0,stream>>>(w1, w1_bf, 3*512*128);
  k_f2bf<<<(3*128*512+255)/256,256,0,stream>>>(w2, w2_bf, 3*128*512);
  k_packconv<<<(3*27*128*128+255)/256,256,0,stream>>>(pw, wc_bf, 3*27*128*128);

  // ---- 3 transformer layers ----
  for (int li = 0; li < 3; li++){
    const float* src = (li == 0) ? qe : T2;
    k_addpos<<<16384,256,0,stream>>>(src, pe, vo, XF, XB);
    k_gemm2<<<dim3(256,1),512,65536,stream>>>(XB, ain_bf + (size_t)li*384*128, ain_b + li*384,
                                              nullptr, nullptr, QB, 128, 128, 1, 0);
    k_attn2<<<512,256,0,stream>>>(QB, khs_bf + (size_t)li*4*128*32,
                                  vt_bf + (size_t)li*4*32*128, biasArr, XB);
    k_gemm2<<<dim3(256,1),512,65536,stream>>>(XB, aout_bf + (size_t)li*128*128, aout_b + li*128,
                                              XF, T2, nullptr, 128, 128, 1, 0);
    k_ln<<<8192,256,0,stream>>>(T2, ln1g + li*128, ln1b + li*128, T1, XB);
    k_gemm2<<<dim3(256,4),512,65536,stream>>>(XB, w1_bf + (size_t)li*512*128, b1 + li*512,
                                              nullptr, nullptr, HB, 512, 128, 1, 1);
    k_gemm2<<<dim3(256,1),512,131072,stream>>>(HB, w2_bf + (size_t)li*128*512, b2 + li*128,
                                               T1, T2, nullptr, 128, 512, 4, 0);
    k_ln<<<8192,256,0,stream>>>(T2, ln2g + li*128, ln2b + li*128, T2, nullptr);
  }

  // ---- fov select + conv stack ----
  k_fovsel<<<16384,256,0,stream>>>(T2, qe, fov, x3a);
  k_conv2<<<256,512,131072,stream>>>(x3a, wc_bf + (size_t)0*27*16384, pb + 0,   zp, x3b, 1);
  k_conv2<<<256,512,131072,stream>>>(x3b, wc_bf + (size_t)1*27*16384, pb + 128, zp, x3a, 2);
  k_conv2<<<256,512,131072,stream>>>(x3a, wc_bf + (size_t)2*27*16384, pb + 256, zp, x3b, 3);
  k_outconv<<<128,256,0,stream>>>(x3b, ow, ob, out);
}

// Round 4
// 518.220 us; speedup vs baseline: 2.7740x; 1.0769x over previous
//
#include <hip/hip_runtime.h>
#include <math.h>

typedef unsigned short u16;
typedef unsigned int   u32;

#define NQv 32768
#define HWp 7680
#define NI  100

typedef short v8s __attribute__((ext_vector_type(8)));
typedef float v4f __attribute__((ext_vector_type(4)));

__device__ inline float bf2f(u16 u){ u32 x = ((u32)u) << 16; return __uint_as_float(x); }
__device__ inline u16 f2bf(float f){
  u32 x = __float_as_uint(f);
  u32 r = (x + 0x7fffu + ((x >> 16) & 1u)) >> 16;
  return (u16)r;
}
__device__ inline float sigf(float x){ return 1.0f / (1.0f + expf(-x)); }

typedef const __attribute__((address_space(1))) void* gas_t;
typedef __attribute__((address_space(3))) void* las_t;

// ---------------- small prep: invert K (3x3) and E (4x4), instance scores ----------------
__global__ void k_prep_small(const float* __restrict__ Km, const float* __restrict__ Em,
                             const float* __restrict__ logits,
                             float* __restrict__ mats, float* __restrict__ scores,
                             int* __restrict__ keep0)
{
  int tid = threadIdx.x;
  if (tid == 0) {
    double a[9];
    for (int i = 0; i < 9; i++) a[i] = (double)Km[i];
    double det = a[0]*(a[4]*a[8]-a[5]*a[7]) - a[1]*(a[3]*a[8]-a[5]*a[6]) + a[2]*(a[3]*a[7]-a[4]*a[6]);
    double id = 1.0 / det;
    double inv[9];
    inv[0]=(a[4]*a[8]-a[5]*a[7])*id; inv[1]=(a[2]*a[7]-a[1]*a[8])*id; inv[2]=(a[1]*a[5]-a[2]*a[4])*id;
    inv[3]=(a[5]*a[6]-a[3]*a[8])*id; inv[4]=(a[0]*a[8]-a[2]*a[6])*id; inv[5]=(a[2]*a[3]-a[0]*a[5])*id;
    inv[6]=(a[3]*a[7]-a[4]*a[6])*id; inv[7]=(a[1]*a[6]-a[0]*a[7])*id; inv[8]=(a[0]*a[4]-a[1]*a[3])*id;
    for (int i = 0; i < 9; i++) mats[i] = (float)inv[i];
    double m[4][8];
    for (int r = 0; r < 4; r++){
      for (int c = 0; c < 4; c++){ m[r][c] = (double)Em[r*4+c]; m[r][4+c] = (r==c) ? 1.0 : 0.0; }
    }
    for (int col = 0; col < 4; col++){
      int piv = col; double best = fabs(m[col][col]);
      for (int r = col+1; r < 4; r++){ double v = fabs(m[r][col]); if (v > best){ best = v; piv = r; } }
      if (piv != col){ for (int c = 0; c < 8; c++){ double t = m[col][c]; m[col][c] = m[piv][c]; m[piv][c] = t; } }
      double p = m[col][col];
      for (int c = 0; c < 8; c++) m[col][c] /= p;
      for (int r = 0; r < 4; r++) if (r != col){ double f = m[r][col]; for (int c = 0; c < 8; c++) m[r][c] -= f*m[col][c]; }
    }
    for (int r = 0; r < 3; r++) for (int c = 0; c < 4; c++) mats[9 + r*4 + c] = (float)m[r][4+c];
  }
  if (tid < NI) {
    float mx = -1e30f;
    for (int c = 0; c < 21; c++){ float t = sigf(logits[tid*21+c]) / 0.06f; mx = fmaxf(mx, t); }
    float s = 0.f;
    for (int c = 0; c < 21; c++){ float t = sigf(logits[tid*21+c]) / 0.06f; s += expf(t - mx); }
    float sc = 1.0f / s;
    scores[tid] = sc;
    keep0[tid] = (sc > 0.25f) ? 1 : 0;
  }
}

// ---- one launch: 4 weight f32->bf16 converts + 3 zero-fills ----
__global__ void k_prep_multi(
    const float* __restrict__ s0, u16* __restrict__ d0, int n0,
    const float* __restrict__ s1, u16* __restrict__ d1, int n1,
    const float* __restrict__ s2, u16* __restrict__ d2, int n2,
    const float* __restrict__ s3, u16* __restrict__ d3, int n3,
    u16* __restrict__ z0, int zn0, u16* __restrict__ z1, int zn1,
    u16* __restrict__ z2, int zn2)
{
  int i = blockIdx.x*256 + threadIdx.x;
  if (i < n0){ d0[i] = f2bf(s0[i]); return; } i -= n0;
  if (i < n1){ d1[i] = f2bf(s1[i]); return; } i -= n1;
  if (i < n2){ d2[i] = f2bf(s2[i]); return; } i -= n2;
  if (i < n3){ d3[i] = f2bf(s3[i]); return; } i -= n3;
  if (i < zn0){ z0[i] = 0; return; } i -= zn0;
  if (i < zn1){ z1[i] = 0; return; } i -= zn1;
  if (i < zn2){ z2[i] = 0; return; }
}

// ---------------- per-pixel argmax, instance axis split across 4 waves ----------------
__global__ __launch_bounds__(256) void k_mask_argmax2(
    const float* __restrict__ pmL, const float* __restrict__ scores,
    const int* __restrict__ keep0, int* __restrict__ mids)
{
  __shared__ float sv[4][64];
  __shared__ int   si[4][64];
  int tid = threadIdx.x, lane = tid & 63, w = tid >> 6;
  int p = blockIdx.x*64 + lane;
  float best = -2e30f; int bid = 0;
  #pragma unroll 5
  for (int jj = 0; jj < 25; jj++){
    int i = w*25 + jj;
    float lg = pmL[i*HWp + p];
    float val = keep0[i] ? scores[i] * sigf(lg) : -1.0f;
    if (val > best){ best = val; bid = i; }   // ascending i -> first-max
  }
  sv[w][lane] = best; si[w][lane] = bid;
  __syncthreads();
  if (w == 0){
    float b0 = sv[0][lane]; int i0 = si[0][lane];
    #pragma unroll
    for (int g = 1; g < 4; g++){
      float bg = sv[g][lane]; int ig = si[g][lane];
      if (bg > b0 || (bg == b0 && ig < i0)){ b0 = bg; i0 = ig; }
    }
    mids[p] = i0;
  }
}

__global__ void k_inst_stats(const float* __restrict__ pmL, const int* __restrict__ mids,
                             const int* __restrict__ keep0, int* __restrict__ keep)
{
  int i = blockIdx.x, tid = threadIdx.x;
  int k0 = keep0[i];
  int ma = 0, pa = 0, it = 0;
  for (int p = tid; p < HWp; p += 256){
    float lg = pmL[i*HWp + p];
    int pb = (lg >= 0.0f) ? 1 : 0;
    int mi = (mids[p] == i && k0) ? 1 : 0;
    ma += mi; pa += pb; it += (mi & pb);
  }
  __shared__ int sma[256], spa[256], sit[256];
  sma[tid] = ma; spa[tid] = pa; sit[tid] = it;
  __syncthreads();
  for (int off = 128; off; off >>= 1){
    if (tid < off){ sma[tid]+=sma[tid+off]; spa[tid]+=spa[tid+off]; sit[tid]+=sit[tid+off]; }
    __syncthreads();
  }
  if (tid == 0){
    keep[i] = (k0 && sit[0] > 0 && ((float)sma[0] >= 0.8f*(float)spa[0])) ? 1 : 0;
  }
}

__global__ void k_finalize(const int* __restrict__ keep, int* __restrict__ anyk,
                           float* __restrict__ usef, float* __restrict__ biasArr)
{
  int tid = threadIdx.x;
  __shared__ int s_any;
  if (tid == 0){
    int a = 0;
    for (int i = 0; i < NI; i++) a |= keep[i];
    s_any = a; anyk[0] = a; usef[0] = a ? 1.0f : 0.0f;
  }
  __syncthreads();
  if (tid < 128){
    float b;
    if (tid < NI) b = s_any ? (keep[tid] ? 0.0f : -1e9f) : 0.0f;
    else b = -1e9f;
    biasArr[tid] = b;
  }
}

__global__ void k_backproject(const float* __restrict__ depth, const float* __restrict__ pmL,
                              const int* __restrict__ mids, const int* __restrict__ keep,
                              const float* __restrict__ mats, float* __restrict__ xyz)
{
  int i = blockIdx.x, tid = threadIdx.x;
  float sx = 0.f, sy = 0.f, sz = 0.f;
  if (keep[i]){
    float ik0=mats[0],ik1=mats[1],ik2=mats[2],ik3=mats[3],ik4=mats[4],ik5=mats[5],ik6=mats[6],ik7=mats[7],ik8=mats[8];
    const float* iE = mats + 9;
    for (int p = tid; p < HWp; p += 256){
      if (mids[p] == i && pmL[i*HWp + p] >= 0.0f){
        int r = p / 160, c = p % 160;
        float xg = (float)((double)c * (1279.0/159.0));
        float yg = (float)((double)r * (383.0/47.0));
        float d = depth[p];
        float g0 = xg*d, g1 = yg*d, g2 = d;
        float c0 = ik0*g0 + ik1*g1 + ik2*g2;
        float c1 = ik3*g0 + ik4*g1 + ik5*g2;
        float c2 = ik6*g0 + ik7*g1 + ik8*g2;
        sx += iE[0]*c0 + iE[1]*c1 + iE[2]*c2 + iE[3];
        sy += iE[4]*c0 + iE[5]*c1 + iE[6]*c2 + iE[7];
        sz += iE[8]*c0 + iE[9]*c1 + iE[10]*c2 + iE[11];
      }
    }
  }
  __shared__ float rx[256], ry[256], rz[256];
  rx[tid]=sx; ry[tid]=sy; rz[tid]=sz;
  __syncthreads();
  for (int off = 128; off; off >>= 1){
    if (tid < off){ rx[tid]+=rx[tid+off]; ry[tid]+=ry[tid+off]; rz[tid]+=rz[tid+off]; }
    __syncthreads();
  }
  if (tid == 0){ xyz[i*3+0]=rx[0]; xyz[i*3+1]=ry[0]; xyz[i*3+2]=rz[0]; }
}

__global__ void k_kvk(const float* __restrict__ iq, const float* __restrict__ pe,
                      const float* __restrict__ xyz, const float* __restrict__ usef,
                      float* __restrict__ kvk)
{
  int idx = blockIdx.x*256 + threadIdx.x;
  if (idx >= NI*128) return;
  int i = idx >> 7, c = idx & 127;
  float u = usef[0];
  float ip = pe[c*3+0]*xyz[i*3+0] + pe[c*3+1]*xyz[i*3+1] + pe[c*3+2]*xyz[i*3+2];
  kvk[idx] = iq[idx] + u * ip;
}

// ---------------- K/V head projections -> bf16 MFMA-ready layouts ----------------
__global__ __launch_bounds__(512) void k_khvh2(const float* __restrict__ kvk,
    const float* __restrict__ iq, const float* __restrict__ Win,
    const float* __restrict__ bin, u16* __restrict__ khs_bf, u16* __restrict__ vt_bf)
{
  __shared__ u16 s_in[NI][130];
  __shared__ u16 s_w[64][130];
  int li = blockIdx.x, c0 = blockIdx.y*64;
  bool isK = (c0 < 128);
  const float* srcIn = isK ? kvk : iq;
  int tid = threadIdx.x;
  for (int i = tid; i < NI*128; i += 512) s_in[i>>7][i&127] = f2bf(srcIn[i]);
  const float* wbase = Win + ((size_t)li*384 + 128 + c0)*128;
  for (int i = tid; i < 64*128; i += 512) s_w[i>>7][i&127] = f2bf(wbase[i]);
  __syncthreads();
  for (int o = tid; o < NI*64; o += 512){
    int k = o >> 6, c = o & 63;
    float acc = 0.f;
    #pragma unroll 8
    for (int j = 0; j < 128; j++) acc += bf2f(s_in[k][j]) * bf2f(s_w[c][j]);
    int cc = c0 + c;
    float v = acc + bin[li*384 + 128 + cc];
    int ch = cc & 127;
    if (isK) khs_bf[(((size_t)li*4 + (ch>>5))*128 + k)*32 + (ch&31)] = f2bf(v * 0.17677669529663687f);
    else     vt_bf [(((size_t)li*4 + (ch>>5))*32 + (ch&31))*128 + k] = f2bf(v);
  }
}

// x = src + qpos, bf16 out only
__global__ void k_addpos(const float* __restrict__ src, const float* __restrict__ pe,
                         const float* __restrict__ vo, u16* __restrict__ xbf)
{
  int idx = blockIdx.x*256 + threadIdx.x;
  int q = idx >> 7, c = idx & 127;
  float px = ((float)(q >> 9)       + 0.5f)*0.8f + vo[0];
  float py = ((float)((q >> 3)&63)  + 0.5f)*0.8f + vo[1];
  float pz = ((float)(q & 7)        + 0.5f)*0.8f + vo[2];
  float qp = pe[c*3+0]*px + pe[c*3+1]*py + pe[c*3+2]*pz;
  xbf[idx] = f2bf(src[idx] + qp);
}

// conv weights [li][o][i][t] -> [li][t][o][i] bf16, block per (o, li)
__global__ __launch_bounds__(256) void k_packconv2(const float* __restrict__ w, u16* __restrict__ wp)
{
  __shared__ u16 s[3456];
  int o = blockIdx.x, li = blockIdx.y;
  const float* src = w + ((size_t)li*128 + o)*3456;     // [i][t] contiguous
  for (int t = threadIdx.x; t < 3456; t += 256) s[t] = f2bf(src[t]);
  __syncthreads();
  for (int e = threadIdx.x; e < 3456; e += 256){
    int t = e >> 7, i = e & 127;
    wp[(((size_t)li*27 + t)*128 + o)*128 + i] = s[i*27 + t];
  }
}

// ================= tiled MFMA infrastructure =================
__device__ inline void stage128(const u16* __restrict__ G, u16* lds,
                                int rbase, int pitchK, int kofs)
{
  int lane = threadIdx.x & 63, w = threadIdx.x >> 6;
  #pragma unroll
  for (int s = 0; s < 4; s++){
    int ldsOff = s*8192 + w*1024 + lane*16;   // bytes
    int row = ldsOff >> 8;
    int cb  = ldsOff & 255;
    int scb = cb ^ ((row & 7) << 4);
    const u16* src = G + (size_t)(rbase + row)*pitchK + kofs + (scb >> 1);
    u16* dst = lds + (s*4096 + w*512);
    __builtin_amdgcn_global_load_lds((gas_t)src, (las_t)dst, 16, 0, 0);
  }
}

__device__ inline void stageConvA(const u16* __restrict__ X, const u16* __restrict__ zp,
                                  u16* lds, int m0, int dx, int dy, int dz)
{
  int lane = threadIdx.x & 63, w = threadIdx.x >> 6;
  #pragma unroll
  for (int s = 0; s < 4; s++){
    int ldsOff = s*8192 + w*1024 + lane*16;
    int row = ldsOff >> 8;
    int cb  = ldsOff & 255;
    int scb = cb ^ ((row & 7) << 4);
    int sidx = m0 + row;
    int xs = (sidx >> 9) + dx, ys = ((sidx >> 3) & 63) + dy, zs = (sidx & 7) + dz;
    bool ok = ((unsigned)xs < 64u) & ((unsigned)ys < 64u) & ((unsigned)zs < 8u);
    const u16* src = ok ? (X + (size_t)((xs*64+ys)*8+zs)*128 + (scb>>1)) : (zp + (scb>>1));
    u16* dst = lds + (s*4096 + w*512);
    __builtin_amdgcn_global_load_lds((gas_t)src, (las_t)dst, 16, 0, 0);
  }
}

__device__ inline v8s fragld(const u16* base, int row, int cb){
  return *(const v8s*)(base + row*128 + (((cb) ^ ((row & 7) << 4)) >> 1));
}

__device__ inline void compute128(const u16* As, const u16* Bs,
                                  int wm, int wn, int r15, int kg, v4f acc[2][4])
{
  #pragma unroll
  for (int k0 = 0; k0 < 4; k0++){
    int cb = k0*64 + kg*16;
    v8s a0 = fragld(As, wm*32 +      r15, cb);
    v8s a1 = fragld(As, wm*32 + 16 + r15, cb);
    v8s b0 = fragld(Bs, wn*64 +      r15, cb);
    v8s b1 = fragld(Bs, wn*64 + 16 + r15, cb);
    v8s b2 = fragld(Bs, wn*64 + 32 + r15, cb);
    v8s b3 = fragld(Bs, wn*64 + 48 + r15, cb);
    acc[0][0] = __builtin_amdgcn_mfma_f32_16x16x32_bf16(a0, b0, acc[0][0], 0, 0, 0);
    acc[0][1] = __builtin_amdgcn_mfma_f32_16x16x32_bf16(a0, b1, acc[0][1], 0, 0, 0);
    acc[0][2] = __builtin_amdgcn_mfma_f32_16x16x32_bf16(a0, b2, acc[0][2], 0, 0, 0);
    acc[0][3] = __builtin_amdgcn_mfma_f32_16x16x32_bf16(a0, b3, acc[0][3], 0, 0, 0);
    acc[1][0] = __builtin_amdgcn_mfma_f32_16x16x32_bf16(a1, b0, acc[1][0], 0, 0, 0);
    acc[1][1] = __builtin_amdgcn_mfma_f32_16x16x32_bf16(a1, b1, acc[1][1], 0, 0, 0);
    acc[1][2] = __builtin_amdgcn_mfma_f32_16x16x32_bf16(a1, b2, acc[1][2], 0, 0, 0);
    acc[1][3] = __builtin_amdgcn_mfma_f32_16x16x32_bf16(a1, b3, acc[1][3], 0, 0, 0);
  }
}

// ---------------- tiled GEMM (no LN) ----------------
__global__ __launch_bounds__(512) void k_gemm2(
    const u16* __restrict__ A, const u16* __restrict__ B,
    const float* __restrict__ bias, const float* __restrict__ res,
    float* __restrict__ outF, u16* __restrict__ outB,
    int N, int K, int KT, int act)
{
  extern __shared__ u16 smem[];
  int tid = threadIdx.x, lane = tid & 63, w = tid >> 6;
  int wm = w & 3, wn = w >> 2, r15 = lane & 15, kg = lane >> 4;
  int m0 = blockIdx.x*128, n0 = blockIdx.y*128;
  v4f acc[2][4] = {};
  stage128(A, smem + 0,     m0, K, 0);
  stage128(B, smem + 16384, n0, K, 0);
  __syncthreads();
  for (int kt = 0; kt < KT; kt++){
    int b = kt & 1;
    if (kt + 1 < KT){
      int b2 = b ^ 1;
      stage128(A, smem + b2*32768,         m0, K, (kt+1)*128);
      stage128(B, smem + b2*32768 + 16384, n0, K, (kt+1)*128);
    }
    compute128(smem + b*32768, smem + b*32768 + 16384, wm, wn, r15, kg, acc);
    __syncthreads();
  }
  #pragma unroll
  for (int i = 0; i < 2; i++){
    #pragma unroll
    for (int j = 0; j < 4; j++){
      int col = n0 + wn*64 + j*16 + r15;
      float bv = bias ? bias[col] : 0.0f;
      #pragma unroll
      for (int rr = 0; rr < 4; rr++){
        int row = m0 + wm*32 + i*16 + kg*4 + rr;
        float v = acc[i][j][rr] + bv;
        size_t oi = (size_t)row*N + col;
        if (res) v += res[oi];
        if (act == 1) v = 0.5f*v*(1.0f + erff(v*0.70710678118654752f));
        if (outF) outF[oi] = v;
        if (outB) outB[oi] = f2bf(v);
      }
    }
  }
}

// ---------------- GEMM (N=128) + residual + LayerNorm fused ----------------
// mode 0: res = resSrc[oi]        (FFN2: res = LN1 f32)
// mode 1: res = resSrc[oi] + qpos (out-proj: resSrc = layer input stream)
// if fov != null: outB[oi] = fov[q] ? LN(x) : qe[oi]  (layer-2 FFN2)
__global__ __launch_bounds__(512) void k_gemmln(
    const u16* __restrict__ A, const u16* __restrict__ B,
    const float* __restrict__ bias, const float* __restrict__ resSrc,
    const float* __restrict__ pe, const float* __restrict__ vo,
    const float* __restrict__ g, const float* __restrict__ b,
    float* __restrict__ outF, u16* __restrict__ outB,
    const int* __restrict__ fov, const float* __restrict__ qe,
    int K, int KT, int mode)
{
  extern __shared__ u16 smem[];
  int tid = threadIdx.x, lane = tid & 63, w = tid >> 6;
  int wm = w & 3, wn = w >> 2, r15 = lane & 15, kg = lane >> 4;
  int m0 = blockIdx.x*128;
  v4f acc[2][4] = {};
  stage128(A, smem + 0,     m0, K, 0);
  stage128(B, smem + 16384, 0,  K, 0);
  __syncthreads();
  for (int kt = 0; kt < KT; kt++){
    int bb = kt & 1;
    if (kt + 1 < KT){
      int b2 = bb ^ 1;
      stage128(A, smem + b2*32768,         m0, K, (kt+1)*128);
      stage128(B, smem + b2*32768 + 16384, 0,  K, (kt+1)*128);
    }
    compute128(smem + bb*32768, smem + bb*32768 + 16384, wm, wn, r15, kg, acc);
    __syncthreads();
  }
  // ---- write x = acc + bias + res into LDS (aliases staging; safe after sync) ----
  float* lnbuf = (float*)smem;   // [128][132]
  float vo0 = 0.f, vo1 = 0.f, vo2 = 0.f;
  if (mode == 1){ vo0 = vo[0]; vo1 = vo[1]; vo2 = vo[2]; }
  #pragma unroll
  for (int i = 0; i < 2; i++){
    #pragma unroll
    for (int j = 0; j < 4; j++){
      int col = wn*64 + j*16 + r15;
      float bv = bias[col];
      float p0 = 0, p1 = 0, p2 = 0;
      if (mode == 1){ p0 = pe[col*3+0]; p1 = pe[col*3+1]; p2 = pe[col*3+2]; }
      #pragma unroll
      for (int rr = 0; rr < 4; rr++){
        int row = wm*32 + i*16 + kg*4 + rr;
        int q = m0 + row;
        size_t oi = (size_t)q*128 + col;
        float x = acc[i][j][rr] + bv;
        if (mode == 1){
          float px = ((float)(q >> 9)      + 0.5f)*0.8f + vo0;
          float py = ((float)((q >> 3)&63) + 0.5f)*0.8f + vo1;
          float pz = ((float)(q & 7)       + 0.5f)*0.8f + vo2;
          x += resSrc[oi] + p0*px + p1*py + p2*pz;
        } else {
          x += resSrc[oi];
        }
        lnbuf[row*132 + col] = x;
      }
    }
  }
  __syncthreads();
  // ---- LN: row = w*16 + (lane>>2), 4 lanes per row, interleaved cols ----
  int r = w*16 + (lane >> 2), j4 = lane & 3;
  const float* rowp = lnbuf + r*132;
  float s = 0.f;
  #pragma unroll
  for (int k = 0; k < 32; k++) s += rowp[j4 + 4*k];
  s += __shfl_xor(s, 1, 64); s += __shfl_xor(s, 2, 64);
  float mean = s * (1.0f/128.0f);
  float vv = 0.f;
  #pragma unroll
  for (int k = 0; k < 32; k++){ float d = rowp[j4 + 4*k] - mean; vv += d*d; }
  vv += __shfl_xor(vv, 1, 64); vv += __shfl_xor(vv, 2, 64);
  float rs = rsqrtf(vv*(1.0f/128.0f) + 1e-5f);
  int gq = m0 + r;
  #pragma unroll
  for (int k = 0; k < 32; k++){
    int c = j4 + 4*k;
    float o = (rowp[c] - mean)*rs*g[c] + b[c];
    size_t oi = (size_t)gq*128 + c;
    if (fov){
      outB[oi] = f2bf(fov[gq] ? o : qe[oi]);
    } else {
      if (outF) outF[oi] = o;
      if (outB) outB[oi] = f2bf(o);
    }
  }
}

// ---------------- dilated 3x3x3 conv ----------------
__global__ __launch_bounds__(512) void k_conv2(
    const u16* __restrict__ X, const u16* __restrict__ W,
    const float* __restrict__ bias, const u16* __restrict__ zp,
    u16* __restrict__ Y, int dil)
{
  extern __shared__ u16 smem[];
  int tid = threadIdx.x, lane = tid & 63, w = tid >> 6;
  int wm = w & 3, wn = w >> 2, r15 = lane & 15, kg = lane >> 4;
  int m0 = blockIdx.x*128;
  v4f acc[2][4] = {};
  stageConvA(X, zp, smem + 0, m0, -dil, -dil, -dil);
  stage128(W, smem + 16384, 0, 128, 0);
  __syncthreads();
  for (int t = 0; t < 27; t++){
    int b = t & 1;
    if (t + 1 < 27){
      int tn = t + 1, b2 = b ^ 1;
      int dx = (tn/9) - 1, dy = ((tn/3)%3) - 1, dz = (tn%3) - 1;
      stageConvA(X, zp, smem + b2*32768, m0, dx*dil, dy*dil, dz*dil);
      stage128(W + (size_t)tn*16384, smem + b2*32768 + 16384, 0, 128, 0);
    }
    compute128(smem + b*32768, smem + b*32768 + 16384, wm, wn, r15, kg, acc);
    __syncthreads();
  }
  #pragma unroll
  for (int i = 0; i < 2; i++){
    #pragma unroll
    for (int j = 0; j < 4; j++){
      int col = wn*64 + j*16 + r15;
      float bv = bias[col];
      #pragma unroll
      for (int rr = 0; rr < 4; rr++){
        int row = m0 + wm*32 + i*16 + kg*4 + rr;
        float v = acc[i][j][rr] + bv + bf2f(X[(size_t)row*128 + col]);
        v = fmaxf(v, 0.0f);
        Y[(size_t)row*128 + col] = f2bf(v);
      }
    }
  }
}

// ---------------- MFMA cross-attention ----------------
__global__ __launch_bounds__(256) void k_attn2(
    const u16* __restrict__ QB, const u16* __restrict__ KH, const u16* __restrict__ VT,
    const float* __restrict__ biasArr, u16* __restrict__ O)
{
  __shared__ float sb[128];
  __shared__ u16 sp[4][32*128];
  int tid = threadIdx.x, lane = tid & 63, w = tid >> 6;
  if (tid < 128) sb[tid] = biasArr[tid];
  __syncthreads();
  int c = lane & 15, r = lane >> 4;
  int q0 = blockIdx.x * 64;
  const u16* Kh = KH + (size_t)w*128*32;
  const u16* Vh = VT + (size_t)w*32*128;
  char* spw = (char*)&sp[w][0];

  v8s kf[8];
  #pragma unroll
  for (int kt = 0; kt < 8; kt++) kf[kt] = *(const v8s*)(Kh + (kt*16 + c)*32 + r*8);
  v8s vf[4][2];
  #pragma unroll
  for (int ks = 0; ks < 4; ks++)
    #pragma unroll
    for (int dt = 0; dt < 2; dt++)
      vf[ks][dt] = *(const v8s*)(Vh + (dt*16 + c)*128 + ks*32 + r*8);
  float bv[8][4];
  #pragma unroll
  for (int kt = 0; kt < 8; kt++){
    float4 t = *(const float4*)&sb[kt*16 + r*4];
    bv[kt][0] = t.x; bv[kt][1] = t.y; bv[kt][2] = t.z; bv[kt][3] = t.w;
  }

  #pragma unroll
  for (int half = 0; half < 2; half++){
    v4f s[2][8] = {};
    #pragma unroll
    for (int qt2 = 0; qt2 < 2; qt2++){
      int qt = half*2 + qt2;
      v8s qf = *(const v8s*)(QB + (size_t)(q0 + qt*16 + c)*128 + w*32 + r*8);
      #pragma unroll
      for (int kt = 0; kt < 8; kt++)
        s[qt2][kt] = __builtin_amdgcn_mfma_f32_16x16x32_bf16(kf[kt], qf, s[qt2][kt], 0, 0, 0);
    }
    #pragma unroll
    for (int qt2 = 0; qt2 < 2; qt2++){
      float mx = -1e30f;
      #pragma unroll
      for (int kt = 0; kt < 8; kt++)
        #pragma unroll
        for (int rg = 0; rg < 4; rg++){
          s[qt2][kt][rg] += bv[kt][rg];
          mx = fmaxf(mx, s[qt2][kt][rg]);
        }
      mx = fmaxf(mx, __shfl_xor(mx, 16, 64));
      mx = fmaxf(mx, __shfl_xor(mx, 32, 64));
      float sum = 0.f;
      #pragma unroll
      for (int kt = 0; kt < 8; kt++)
        #pragma unroll
        for (int rg = 0; rg < 4; rg++){
          float p = __expf(s[qt2][kt][rg] - mx);
          s[qt2][kt][rg] = p;
          sum += p;
        }
      sum += __shfl_xor(sum, 16, 64);
      sum += __shfl_xor(sum, 32, 64);
      float inv = 1.0f / sum;
      int row = qt2*16 + c;
      int rbyte = row*256;
      int rx = (row & 7) << 4;
      #pragma unroll
      for (int kt = 0; kt < 8; kt++){
        #pragma unroll
        for (int pr = 0; pr < 2; pr++){
          u32 pk = (u32)f2bf(s[qt2][kt][pr*2]*inv) | ((u32)f2bf(s[qt2][kt][pr*2+1]*inv) << 16);
          int colb = kt*32 + r*8 + pr*4;
          *(u32*)(spw + rbyte + (colb ^ rx)) = pk;
        }
      }
    }
    v4f o[2][2] = {};
    #pragma unroll
    for (int ks = 0; ks < 4; ks++){
      #pragma unroll
      for (int qt2 = 0; qt2 < 2; qt2++){
        int row = qt2*16 + c;
        int colb = ks*64 + r*16;
        v8s aP = *(const v8s*)(spw + row*256 + (colb ^ ((row & 7) << 4)));
        o[qt2][0] = __builtin_amdgcn_mfma_f32_16x16x32_bf16(aP, vf[ks][0], o[qt2][0], 0, 0, 0);
        o[qt2][1] = __builtin_amdgcn_mfma_f32_16x16x32_bf16(aP, vf[ks][1], o[qt2][1], 0, 0, 0);
      }
    }
    #pragma unroll
    for (int qt2 = 0; qt2 < 2; qt2++){
      #pragma unroll
      for (int dt = 0; dt < 2; dt++){
        #pragma unroll
        for (int rg = 0; rg < 4; rg++){
          int qq = q0 + (half*2 + qt2)*16 + r*4 + rg;
          O[(size_t)qq*128 + w*32 + dt*16 + c] = f2bf(o[qt2][dt][rg]);
        }
      }
    }
  }
}

// ---------------- 1x1x1 head conv -> d_out [20][32768] ----------------
__global__ __launch_bounds__(256) void k_outconv(const u16* __restrict__ X,
    const float* __restrict__ W, const float* __restrict__ B, float* __restrict__ out)
{
  __shared__ float sw[20*128];
  __shared__ float sbb[20];
  int tid = threadIdx.x;
  for (int i = tid; i < 20*128; i += 256) sw[i] = W[i];
  if (tid < 20) sbb[tid] = B[tid];
  __syncthreads();
  int s = blockIdx.x*256 + tid;
  u32 rv[64];
  const u32* xp = (const u32*)(X + (size_t)s*128);
  #pragma unroll
  for (int j = 0; j < 64; j++) rv[j] = xp[j];
  for (int ot = 0; ot < 20; ot++){
    float acc = sbb[ot];
    #pragma unroll
    for (int j = 0; j < 64; j++){
      u32 u = rv[j];
      acc += bf2f((u16)(u & 0xffff))*sw[ot*128 + 2*j] + bf2f((u16)(u >> 16))*sw[ot*128 + 2*j + 1];
    }
    out[(size_t)ot*NQv + s] = acc;
  }
}

extern "C" void kernel_launch(void* const* d_in, const int* in_sizes, int n_in,
                              void* d_out, int out_size, void* d_ws, size_t ws_size,
                              hipStream_t stream)
{
  const float* iq    = (const float*)d_in[0];
  const float* logits= (const float*)d_in[1];
  const float* pmL   = (const float*)d_in[2];
  const float* depth = (const float*)d_in[3];
  const float* Km    = (const float*)d_in[4];
  const float* Em    = (const float*)d_in[5];
  const float* vo    = (const float*)d_in[6];
  const float* qe    = (const float*)d_in[7];
  const float* pe    = (const float*)d_in[8];
  const float* ain_w = (const float*)d_in[9];
  const float* ain_b = (const float*)d_in[10];
  const float* aout_w= (const float*)d_in[11];
  const float* aout_b= (const float*)d_in[12];
  const float* ln1g  = (const float*)d_in[13];
  const float* ln1b  = (const float*)d_in[14];
  const float* w1    = (const float*)d_in[15];
  const float* b1    = (const float*)d_in[16];
  const float* w2    = (const float*)d_in[17];
  const float* b2    = (const float*)d_in[18];
  const float* ln2g  = (const float*)d_in[19];
  const float* ln2b  = (const float*)d_in[20];
  const float* pw    = (const float*)d_in[21];
  const float* pb    = (const float*)d_in[22];
  const float* ow    = (const float*)d_in[23];
  const float* ob    = (const float*)d_in[24];
  const int*   fov   = (const int*)d_in[25];
  float* out = (float*)d_out;

  (void)hipFuncSetAttribute((const void*)k_gemm2,  hipFuncAttributeMaxDynamicSharedMemorySize, 131072);
  (void)hipFuncSetAttribute((const void*)k_gemmln, hipFuncAttributeMaxDynamicSharedMemorySize, 131072);
  (void)hipFuncSetAttribute((const void*)k_conv2,  hipFuncAttributeMaxDynamicSharedMemorySize, 131072);

  char* ws = (char*)d_ws;
  size_t off = 0;
  auto alloc = [&](size_t bytes) -> char* {
    char* p = ws + off;
    off = (off + bytes + 255) & ~(size_t)255;
    return p;
  };
  float* mats    = (float*)alloc(32*4);
  float* scores  = (float*)alloc(128*4);
  int*   keep0   = (int*)  alloc(128*4);
  int*   keep    = (int*)  alloc(128*4);
  int*   anyk    = (int*)  alloc(64);
  float* usef    = (float*)alloc(64);
  float* biasArr = (float*)alloc(128*4);
  float* xyz     = (float*)alloc(512*4);
  u16*   zp      = (u16*)  alloc(256);
  int*   mids    = (int*)  alloc((size_t)HWp*4);
  float* kvkb    = (float*)alloc((size_t)NI*128*4);
  u16* khs_bf  = (u16*)alloc((size_t)3*4*128*32*2);
  u16* vt_bf   = (u16*)alloc((size_t)3*4*32*128*2);
  u16* ain_bf  = (u16*)alloc((size_t)3*384*128*2);
  u16* aout_bf = (u16*)alloc((size_t)3*128*128*2);
  u16* w1_bf   = (u16*)alloc((size_t)3*512*128*2);
  u16* w2_bf   = (u16*)alloc((size_t)3*128*512*2);
  u16* wc_bf   = (u16*)alloc((size_t)3*27*128*128*2);
  float* T1 = (float*)alloc((size_t)NQv*128*4);
  float* T2 = (float*)alloc((size_t)NQv*128*4);
  u16*  XB = (u16*) alloc((size_t)NQv*128*2);
  u16*  HB = (u16*) alloc((size_t)NQv*512*2);
  u16* QB  = HB;           // q-projection (HB free until FFN1)
  u16* x3a = XB;           // conv ping (XB dead after FFN1 of layer 2)
  u16* x3b = HB;           // conv pong (HB dead after FFN2)
  (void)ws_size; (void)in_sizes; (void)n_in; (void)out_size; (void)anyk;

  // ---- prep ----
  k_prep_small<<<1,128,0,stream>>>(Km, Em, logits, mats, scores, keep0);
  {
    int n0 = 3*384*128, n1 = 3*128*128, n2 = 3*512*128, n3 = 3*128*512;
    int zn0 = 3*4*128*32, zn1 = 3*4*32*128, zn2 = 128;
    int total = n0+n1+n2+n3+zn0+zn1+zn2;
    k_prep_multi<<<(total+255)/256,256,0,stream>>>(
        ain_w, ain_bf, n0, aout_w, aout_bf, n1, w1, w1_bf, n2, w2, w2_bf, n3,
        khs_bf, zn0, vt_bf, zn1, zp, zn2);
  }
  k_packconv2<<<dim3(128,3),256,0,stream>>>(pw, wc_bf);
  k_mask_argmax2<<<120,256,0,stream>>>(pmL, scores, keep0, mids);
  k_inst_stats<<<NI,256,0,stream>>>(pmL, mids, keep0, keep);
  k_finalize<<<1,128,0,stream>>>(keep, anyk, usef, biasArr);
  k_backproject<<<NI,256,0,stream>>>(depth, pmL, mids, keep, mats, xyz);
  k_kvk<<<(NI*128+255)/256,256,0,stream>>>(iq, pe, xyz, usef, kvkb);
  { dim3 g(3,4); k_khvh2<<<g,512,0,stream>>>(kvkb, iq, ain_w, ain_b, khs_bf, vt_bf); }

  // ---- 3 transformer layers ----
  for (int li = 0; li < 3; li++){
    const float* src = (li == 0) ? qe : T2;
    k_addpos<<<16384,256,0,stream>>>(src, pe, vo, XB);
    k_gemm2<<<dim3(256,1),512,65536,stream>>>(XB, ain_bf + (size_t)li*384*128, ain_b + li*384,
                                              nullptr, nullptr, QB, 128, 128, 1, 0);
    k_attn2<<<512,256,0,stream>>>(QB, khs_bf + (size_t)li*4*128*32,
                                  vt_bf + (size_t)li*4*32*128, biasArr, XB);
    // out-proj + residual(src+qpos) + LN1 -> T1 (f32) + XB (bf16)
    k_gemmln<<<256,512,69632,stream>>>(XB, aout_bf + (size_t)li*128*128, aout_b + li*128,
                                       src, pe, vo, ln1g + li*128, ln1b + li*128,
                                       T1, XB, nullptr, nullptr, 128, 1, 1);
    k_gemm2<<<dim3(256,4),512,65536,stream>>>(XB, w1_bf + (size_t)li*512*128, b1 + li*512,
                                              nullptr, nullptr, HB, 512, 128, 1, 1);
    // FFN2 + residual(T1) + LN2 -> li<2: T2 f32; li==2: x3a bf16 with fov select
    if (li < 2){
      k_gemmln<<<256,512,131072,stream>>>(HB, w2_bf + (size_t)li*128*512, b2 + li*128,
                                          T1, nullptr, nullptr, ln2g + li*128, ln2b + li*128,
                                          T2, nullptr, nullptr, nullptr, 512, 4, 0);
    } else {
      k_gemmln<<<256,512,131072,stream>>>(HB, w2_bf + (size_t)li*128*512, b2 + li*128,
                                          T1, nullptr, nullptr, ln2g + li*128, ln2b + li*128,
                                          nullptr, x3a, fov, qe, 512, 4, 0);
    }
  }

  // ---- conv stack ----
  k_conv2<<<256,512,131072,stream>>>(x3a, wc_bf + (size_t)0*27*16384, pb + 0,   zp, x3b, 1);
  k_conv2<<<256,512,131072,stream>>>(x3b, wc_bf + (size_t)1*27*16384, pb + 128, zp, x3a, 2);
  k_conv2<<<256,512,131072,stream>>>(x3a, wc_bf + (size_t)2*27*16384, pb + 256, zp, x3b, 3);
  k_outconv<<<128,256,0,stream>>>(x3b, ow, ob, out);
}

// Round 5
// 492.315 us; speedup vs baseline: 2.9199x; 1.0526x over previous
//
#include <hip/hip_runtime.h>
#include <math.h>

typedef unsigned short u16;
typedef unsigned int   u32;

#define NQv 32768
#define HWp 7680
#define NI  100

typedef short v8s __attribute__((ext_vector_type(8)));
typedef float v4f __attribute__((ext_vector_type(4)));

__device__ inline float bf2f(u16 u){ u32 x = ((u32)u) << 16; return __uint_as_float(x); }
__device__ inline u16 f2bf(float f){
  u32 x = __float_as_uint(f);
  u32 r = (x + 0x7fffu + ((x >> 16) & 1u)) >> 16;
  return (u16)r;
}
__device__ inline float sigf(float x){ return 1.0f / (1.0f + expf(-x)); }

typedef const __attribute__((address_space(1))) void* gas_t;
typedef __attribute__((address_space(3))) void* las_t;

// ---------------- small prep: invert K (3x3) and E (4x4), instance scores ----------------
__global__ void k_prep_small(const float* __restrict__ Km, const float* __restrict__ Em,
                             const float* __restrict__ logits,
                             float* __restrict__ mats, float* __restrict__ scores,
                             int* __restrict__ keep0)
{
  int tid = threadIdx.x;
  if (tid == 0) {
    double a[9];
    for (int i = 0; i < 9; i++) a[i] = (double)Km[i];
    double det = a[0]*(a[4]*a[8]-a[5]*a[7]) - a[1]*(a[3]*a[8]-a[5]*a[6]) + a[2]*(a[3]*a[7]-a[4]*a[6]);
    double id = 1.0 / det;
    double inv[9];
    inv[0]=(a[4]*a[8]-a[5]*a[7])*id; inv[1]=(a[2]*a[7]-a[1]*a[8])*id; inv[2]=(a[1]*a[5]-a[2]*a[4])*id;
    inv[3]=(a[5]*a[6]-a[3]*a[8])*id; inv[4]=(a[0]*a[8]-a[2]*a[6])*id; inv[5]=(a[2]*a[3]-a[0]*a[5])*id;
    inv[6]=(a[3]*a[7]-a[4]*a[6])*id; inv[7]=(a[1]*a[6]-a[0]*a[7])*id; inv[8]=(a[0]*a[4]-a[1]*a[3])*id;
    for (int i = 0; i < 9; i++) mats[i] = (float)inv[i];
    double m[4][8];
    for (int r = 0; r < 4; r++){
      for (int c = 0; c < 4; c++){ m[r][c] = (double)Em[r*4+c]; m[r][4+c] = (r==c) ? 1.0 : 0.0; }
    }
    for (int col = 0; col < 4; col++){
      int piv = col; double best = fabs(m[col][col]);
      for (int r = col+1; r < 4; r++){ double v = fabs(m[r][col]); if (v > best){ best = v; piv = r; } }
      if (piv != col){ for (int c = 0; c < 8; c++){ double t = m[col][c]; m[col][c] = m[piv][c]; m[piv][c] = t; } }
      double p = m[col][col];
      for (int c = 0; c < 8; c++) m[col][c] /= p;
      for (int r = 0; r < 4; r++) if (r != col){ double f = m[r][col]; for (int c = 0; c < 8; c++) m[r][c] -= f*m[col][c]; }
    }
    for (int r = 0; r < 3; r++) for (int c = 0; c < 4; c++) mats[9 + r*4 + c] = (float)m[r][4+c];
  }
  if (tid < NI) {
    float mx = -1e30f;
    for (int c = 0; c < 21; c++){ float t = sigf(logits[tid*21+c]) / 0.06f; mx = fmaxf(mx, t); }
    float s = 0.f;
    for (int c = 0; c < 21; c++){ float t = sigf(logits[tid*21+c]) / 0.06f; s += expf(t - mx); }
    float sc = 1.0f / s;
    scores[tid] = sc;
    keep0[tid] = (sc > 0.25f) ? 1 : 0;
  }
}

// ---- one launch: 4 weight f32->bf16 converts + 2 zero-fills + zero page + pe transpose ----
__global__ void k_prep_multi(
    const float* __restrict__ s0, u16* __restrict__ d0, int n0,
    const float* __restrict__ s1, u16* __restrict__ d1, int n1,
    const float* __restrict__ s2, u16* __restrict__ d2, int n2,
    const float* __restrict__ s3, u16* __restrict__ d3, int n3,
    u16* __restrict__ z0, int zn0, u16* __restrict__ z1, int zn1,
    u16* __restrict__ z2, int zn2,
    const float* __restrict__ pe, float* __restrict__ peT)
{
  int i = blockIdx.x*256 + threadIdx.x;
  if (i < n0){ d0[i] = f2bf(s0[i]); return; } i -= n0;
  if (i < n1){ d1[i] = f2bf(s1[i]); return; } i -= n1;
  if (i < n2){ d2[i] = f2bf(s2[i]); return; } i -= n2;
  if (i < n3){ d3[i] = f2bf(s3[i]); return; } i -= n3;
  if (i < zn0){ z0[i] = 0; return; } i -= zn0;
  if (i < zn1){ z1[i] = 0; return; } i -= zn1;
  if (i < zn2){ z2[i] = 0; return; } i -= zn2;
  if (i < 384){ int d = i >> 7, c = i & 127; peT[i] = pe[c*3 + d]; }
}

// ---------------- per-pixel argmax, instance axis split across 4 waves ----------------
__global__ __launch_bounds__(256) void k_mask_argmax2(
    const float* __restrict__ pmL, const float* __restrict__ scores,
    const int* __restrict__ keep0, int* __restrict__ mids)
{
  __shared__ float sv[4][64];
  __shared__ int   si[4][64];
  int tid = threadIdx.x, lane = tid & 63, w = tid >> 6;
  int p = blockIdx.x*64 + lane;
  float best = -2e30f; int bid = 0;
  #pragma unroll 5
  for (int jj = 0; jj < 25; jj++){
    int i = w*25 + jj;
    float lg = pmL[i*HWp + p];
    float val = keep0[i] ? scores[i] * sigf(lg) : -1.0f;
    if (val > best){ best = val; bid = i; }
  }
  sv[w][lane] = best; si[w][lane] = bid;
  __syncthreads();
  if (w == 0){
    float b0 = sv[0][lane]; int i0 = si[0][lane];
    #pragma unroll
    for (int g = 1; g < 4; g++){
      float bg = sv[g][lane]; int ig = si[g][lane];
      if (bg > b0 || (bg == b0 && ig < i0)){ b0 = bg; i0 = ig; }
    }
    mids[p] = i0;
  }
}

// ---------------- merged per-instance stats + keep + back-projection ----------------
__global__ __launch_bounds__(256) void k_instbp(
    const float* __restrict__ pmL, const int* __restrict__ mids,
    const int* __restrict__ keep0, const float* __restrict__ depth,
    const float* __restrict__ mats, int* __restrict__ keep, float* __restrict__ xyz)
{
  int i = blockIdx.x, tid = threadIdx.x;
  int k0 = keep0[i];
  int ma = 0, pa = 0, it = 0;
  for (int p = tid; p < HWp; p += 256){
    float lg = pmL[i*HWp + p];
    int pb = (lg >= 0.0f) ? 1 : 0;
    int mi = (mids[p] == i && k0) ? 1 : 0;
    ma += mi; pa += pb; it += (mi & pb);
  }
  __shared__ int sma[256], spa[256], sit[256];
  __shared__ int s_keep;
  sma[tid] = ma; spa[tid] = pa; sit[tid] = it;
  __syncthreads();
  for (int off = 128; off; off >>= 1){
    if (tid < off){ sma[tid]+=sma[tid+off]; spa[tid]+=spa[tid+off]; sit[tid]+=sit[tid+off]; }
    __syncthreads();
  }
  if (tid == 0){
    int kk = (k0 && sit[0] > 0 && ((float)sma[0] >= 0.8f*(float)spa[0])) ? 1 : 0;
    keep[i] = kk; s_keep = kk;
  }
  __syncthreads();
  float sx = 0.f, sy = 0.f, sz = 0.f;
  if (s_keep){
    float ik0=mats[0],ik1=mats[1],ik2=mats[2],ik3=mats[3],ik4=mats[4],ik5=mats[5],ik6=mats[6],ik7=mats[7],ik8=mats[8];
    const float* iE = mats + 9;
    for (int p = tid; p < HWp; p += 256){
      if (mids[p] == i && pmL[i*HWp + p] >= 0.0f){
        int r = p / 160, c = p % 160;
        float xg = (float)((double)c * (1279.0/159.0));
        float yg = (float)((double)r * (383.0/47.0));
        float d = depth[p];
        float g0 = xg*d, g1 = yg*d, g2 = d;
        float c0 = ik0*g0 + ik1*g1 + ik2*g2;
        float c1 = ik3*g0 + ik4*g1 + ik5*g2;
        float c2 = ik6*g0 + ik7*g1 + ik8*g2;
        sx += iE[0]*c0 + iE[1]*c1 + iE[2]*c2 + iE[3];
        sy += iE[4]*c0 + iE[5]*c1 + iE[6]*c2 + iE[7];
        sz += iE[8]*c0 + iE[9]*c1 + iE[10]*c2 + iE[11];
      }
    }
  }
  __shared__ float rx[256], ry[256], rz[256];
  rx[tid]=sx; ry[tid]=sy; rz[tid]=sz;
  __syncthreads();
  for (int off = 128; off; off >>= 1){
    if (tid < off){ rx[tid]+=rx[tid+off]; ry[tid]+=ry[tid+off]; rz[tid]+=rz[tid+off]; }
    __syncthreads();
  }
  if (tid == 0){ xyz[i*3+0]=rx[0]; xyz[i*3+1]=ry[0]; xyz[i*3+2]=rz[0]; }
}

// ---------------- kv_k = inst_queries + use * (xyz @ pos_embed^T); use from keep scan ----
__global__ void k_kvk(const float* __restrict__ iq, const float* __restrict__ pe,
                      const float* __restrict__ xyz, const int* __restrict__ keep,
                      float* __restrict__ kvk)
{
  int tid = threadIdx.x;
  unsigned long long b = __ballot(tid < 100 && keep[tid] != 0);
  __shared__ int s_w[4];
  if ((tid & 63) == 0) s_w[tid >> 6] = (b != 0ULL);
  __syncthreads();
  float u = (s_w[0] | s_w[1]) ? 1.0f : 0.0f;
  int idx = blockIdx.x*256 + tid;
  if (idx >= NI*128) return;
  int i = idx >> 7, c = idx & 127;
  float ip = pe[c*3+0]*xyz[i*3+0] + pe[c*3+1]*xyz[i*3+1] + pe[c*3+2]*xyz[i*3+2];
  kvk[idx] = iq[idx] + u * ip;
}

// ---------------- K/V head projections -> bf16 MFMA-ready layouts (+ biasArr by block 0,0) ----
__global__ __launch_bounds__(512) void k_khvh2(const float* __restrict__ kvk,
    const float* __restrict__ iq, const float* __restrict__ Win,
    const float* __restrict__ bin, const int* __restrict__ keep,
    float* __restrict__ biasArr, u16* __restrict__ khs_bf, u16* __restrict__ vt_bf)
{
  __shared__ u16 s_in[NI][130];
  __shared__ u16 s_w[64][130];
  __shared__ int s_any[8];
  int li = blockIdx.x, c0 = blockIdx.y*64;
  bool isK = (c0 < 128);
  const float* srcIn = isK ? kvk : iq;
  int tid = threadIdx.x;
  unsigned long long bm = __ballot(tid < 100 && keep[tid] != 0);
  if ((tid & 63) == 0) s_any[tid >> 6] = (bm != 0ULL);
  for (int i = tid; i < NI*128; i += 512) s_in[i>>7][i&127] = f2bf(srcIn[i]);
  const float* wbase = Win + ((size_t)li*384 + 128 + c0)*128;
  for (int i = tid; i < 64*128; i += 512) s_w[i>>7][i&127] = f2bf(wbase[i]);
  __syncthreads();
  if (li == 0 && c0 == 0 && tid < 128){
    int any = s_any[0] | s_any[1];
    float bb;
    if (tid < NI) bb = any ? (keep[tid] ? 0.0f : -1e9f) : 0.0f;
    else bb = -1e9f;
    biasArr[tid] = bb;
  }
  for (int o = tid; o < NI*64; o += 512){
    int k = o >> 6, c = o & 63;
    float acc = 0.f;
    #pragma unroll 8
    for (int j = 0; j < 128; j++) acc += bf2f(s_in[k][j]) * bf2f(s_w[c][j]);
    int cc = c0 + c;
    float v = acc + bin[li*384 + 128 + cc];
    int ch = cc & 127;
    if (isK) khs_bf[(((size_t)li*4 + (ch>>5))*128 + k)*32 + (ch&31)] = f2bf(v * 0.17677669529663687f);
    else     vt_bf [(((size_t)li*4 + (ch>>5))*32 + (ch&31))*128 + k] = f2bf(v);
  }
}

// conv weights [li][o][i][t] -> [li][t][o][i] bf16, block per (o, li)
__global__ __launch_bounds__(256) void k_packconv2(const float* __restrict__ w, u16* __restrict__ wp)
{
  __shared__ u16 s[3456];
  int o = blockIdx.x, li = blockIdx.y;
  const float* src = w + ((size_t)li*128 + o)*3456;
  for (int t = threadIdx.x; t < 3456; t += 256) s[t] = f2bf(src[t]);
  __syncthreads();
  for (int e = threadIdx.x; e < 3456; e += 256){
    int t = e >> 7, i = e & 127;
    wp[(((size_t)li*27 + t)*128 + o)*128 + i] = s[i*27 + t];
  }
}

// ================= tiled MFMA infrastructure =================
__device__ inline void stage128(const u16* __restrict__ G, u16* lds,
                                int rbase, int pitchK, int kofs)
{
  int lane = threadIdx.x & 63, w = threadIdx.x >> 6;
  #pragma unroll
  for (int s = 0; s < 4; s++){
    int ldsOff = s*8192 + w*1024 + lane*16;   // bytes
    int row = ldsOff >> 8;
    int cb  = ldsOff & 255;
    int scb = cb ^ ((row & 7) << 4);
    const u16* src = G + (size_t)(rbase + row)*pitchK + kofs + (scb >> 1);
    u16* dst = lds + (s*4096 + w*512);
    __builtin_amdgcn_global_load_lds((gas_t)src, (las_t)dst, 16, 0, 0);
  }
}

__device__ inline void stageConvA(const u16* __restrict__ X, const u16* __restrict__ zp,
                                  u16* lds, int m0, int dx, int dy, int dz)
{
  int lane = threadIdx.x & 63, w = threadIdx.x >> 6;
  #pragma unroll
  for (int s = 0; s < 4; s++){
    int ldsOff = s*8192 + w*1024 + lane*16;
    int row = ldsOff >> 8;
    int cb  = ldsOff & 255;
    int scb = cb ^ ((row & 7) << 4);
    int sidx = m0 + row;
    int xs = (sidx >> 9) + dx, ys = ((sidx >> 3) & 63) + dy, zs = (sidx & 7) + dz;
    bool ok = ((unsigned)xs < 64u) & ((unsigned)ys < 64u) & ((unsigned)zs < 8u);
    const u16* src = ok ? (X + (size_t)((xs*64+ys)*8+zs)*128 + (scb>>1)) : (zp + (scb>>1));
    u16* dst = lds + (s*4096 + w*512);
    __builtin_amdgcn_global_load_lds((gas_t)src, (las_t)dst, 16, 0, 0);
  }
}

__device__ inline v8s fragld(const u16* base, int row, int cb){
  return *(const v8s*)(base + row*128 + (((cb) ^ ((row & 7) << 4)) >> 1));
}

__device__ inline void compute128(const u16* As, const u16* Bs,
                                  int wm, int wn, int r15, int kg, v4f acc[2][4])
{
  #pragma unroll
  for (int k0 = 0; k0 < 4; k0++){
    int cb = k0*64 + kg*16;
    v8s a0 = fragld(As, wm*32 +      r15, cb);
    v8s a1 = fragld(As, wm*32 + 16 + r15, cb);
    v8s b0 = fragld(Bs, wn*64 +      r15, cb);
    v8s b1 = fragld(Bs, wn*64 + 16 + r15, cb);
    v8s b2 = fragld(Bs, wn*64 + 32 + r15, cb);
    v8s b3 = fragld(Bs, wn*64 + 48 + r15, cb);
    acc[0][0] = __builtin_amdgcn_mfma_f32_16x16x32_bf16(a0, b0, acc[0][0], 0, 0, 0);
    acc[0][1] = __builtin_amdgcn_mfma_f32_16x16x32_bf16(a0, b1, acc[0][1], 0, 0, 0);
    acc[0][2] = __builtin_amdgcn_mfma_f32_16x16x32_bf16(a0, b2, acc[0][2], 0, 0, 0);
    acc[0][3] = __builtin_amdgcn_mfma_f32_16x16x32_bf16(a0, b3, acc[0][3], 0, 0, 0);
    acc[1][0] = __builtin_amdgcn_mfma_f32_16x16x32_bf16(a1, b0, acc[1][0], 0, 0, 0);
    acc[1][1] = __builtin_amdgcn_mfma_f32_16x16x32_bf16(a1, b1, acc[1][1], 0, 0, 0);
    acc[1][2] = __builtin_amdgcn_mfma_f32_16x16x32_bf16(a1, b2, acc[1][2], 0, 0, 0);
    acc[1][3] = __builtin_amdgcn_mfma_f32_16x16x32_bf16(a1, b3, acc[1][3], 0, 0, 0);
  }
}

// ---------------- tiled GEMM ----------------
__global__ __launch_bounds__(512) void k_gemm2(
    const u16* __restrict__ A, const u16* __restrict__ B,
    const float* __restrict__ bias, const float* __restrict__ res,
    float* __restrict__ outF, u16* __restrict__ outB,
    int N, int K, int KT, int act)
{
  extern __shared__ u16 smem[];
  int tid = threadIdx.x, lane = tid & 63, w = tid >> 6;
  int wm = w & 3, wn = w >> 2, r15 = lane & 15, kg = lane >> 4;
  int m0 = blockIdx.x*128, n0 = blockIdx.y*128;
  v4f acc[2][4] = {};
  stage128(A, smem + 0,     m0, K, 0);
  stage128(B, smem + 16384, n0, K, 0);
  __syncthreads();
  for (int kt = 0; kt < KT; kt++){
    int b = kt & 1;
    if (kt + 1 < KT){
      int b2 = b ^ 1;
      stage128(A, smem + b2*32768,         m0, K, (kt+1)*128);
      stage128(B, smem + b2*32768 + 16384, n0, K, (kt+1)*128);
    }
    compute128(smem + b*32768, smem + b*32768 + 16384, wm, wn, r15, kg, acc);
    __syncthreads();
  }
  #pragma unroll
  for (int i = 0; i < 2; i++){
    #pragma unroll
    for (int j = 0; j < 4; j++){
      int col = n0 + wn*64 + j*16 + r15;
      float bv = bias ? bias[col] : 0.0f;
      #pragma unroll
      for (int rr = 0; rr < 4; rr++){
        int row = m0 + wm*32 + i*16 + kg*4 + rr;
        float v = acc[i][j][rr] + bv;
        size_t oi = (size_t)row*N + col;
        if (res) v += res[oi];
        if (act == 1) v = 0.5f*v*(1.0f + erff(v*0.70710678118654752f));
        if (outF) outF[oi] = v;
        if (outB) outB[oi] = f2bf(v);
      }
    }
  }
}

// ---------------- fused addpos + Q-projection: A reg-staged with qpos on the fly ----------------
__global__ __launch_bounds__(512) void k_qproj(
    const float* __restrict__ src, const float* __restrict__ peT,
    const float* __restrict__ vo, const u16* __restrict__ B,
    const float* __restrict__ bias, u16* __restrict__ QB)
{
  extern __shared__ u16 smem[];
  u16* sA = smem;
  u16* sB = smem + 16384;
  int tid = threadIdx.x, lane = tid & 63, w = tid >> 6;
  int wm = w & 3, wn = w >> 2, r15 = lane & 15, kg = lane >> 4;
  int m0 = blockIdx.x*128;
  stage128(B, sB, 0, 128, 0);
  // A tile: thread owns row r = tid>>2, cols (tid&3)*32..+31
  int r = tid >> 2, c0 = (tid & 3)*32;
  int q = m0 + r;
  float px = ((float)(q >> 9)       + 0.5f)*0.8f + vo[0];
  float py = ((float)((q >> 3)&63)  + 0.5f)*0.8f + vo[1];
  float pz = ((float)(q & 7)        + 0.5f)*0.8f + vo[2];
  const float4* sp  = (const float4*)(src + (size_t)q*128 + c0);
  const float4* pex = (const float4*)(peT +   0 + c0);
  const float4* pey = (const float4*)(peT + 128 + c0);
  const float4* pez = (const float4*)(peT + 256 + c0);
  char* arow = (char*)sA + r*256;
  int rx = (r & 7) << 4;
  #pragma unroll
  for (int j = 0; j < 8; j++){
    float4 v = sp[j];
    float4 ax = pex[j], ay = pey[j], az = pez[j];
    float o0 = v.x + ax.x*px + ay.x*py + az.x*pz;
    float o1 = v.y + ax.y*px + ay.y*py + az.y*pz;
    float o2 = v.z + ax.z*px + ay.z*py + az.z*pz;
    float o3 = v.w + ax.w*px + ay.w*py + az.w*pz;
    int cbyte = (c0 + j*4)*2;
    *(u32*)(arow + ((cbyte    ) ^ rx)) = (u32)f2bf(o0) | ((u32)f2bf(o1) << 16);
    *(u32*)(arow + ((cbyte + 4) ^ rx)) = (u32)f2bf(o2) | ((u32)f2bf(o3) << 16);
  }
  __syncthreads();
  v4f acc[2][4] = {};
  compute128(sA, sB, wm, wn, r15, kg, acc);
  #pragma unroll
  for (int i = 0; i < 2; i++){
    #pragma unroll
    for (int j = 0; j < 4; j++){
      int col = wn*64 + j*16 + r15;
      float bv = bias[col];
      #pragma unroll
      for (int rr = 0; rr < 4; rr++){
        int row = m0 + wm*32 + i*16 + kg*4 + rr;
        QB[(size_t)row*128 + col] = f2bf(acc[i][j][rr] + bv);
      }
    }
  }
}

// ---------------- GEMM (N=128) + residual + LayerNorm fused ----------------
__global__ __launch_bounds__(512) void k_gemmln(
    const u16* __restrict__ A, const u16* __restrict__ B,
    const float* __restrict__ bias, const float* __restrict__ resSrc,
    const float* __restrict__ peT, const float* __restrict__ vo,
    const float* __restrict__ g, const float* __restrict__ b,
    float* __restrict__ outF, u16* __restrict__ outB,
    const int* __restrict__ fov, const float* __restrict__ qe,
    int K, int KT, int mode)
{
  extern __shared__ u16 smem[];
  int tid = threadIdx.x, lane = tid & 63, w = tid >> 6;
  int wm = w & 3, wn = w >> 2, r15 = lane & 15, kg = lane >> 4;
  int m0 = blockIdx.x*128;
  v4f acc[2][4] = {};
  stage128(A, smem + 0,     m0, K, 0);
  stage128(B, smem + 16384, 0,  K, 0);
  __syncthreads();
  for (int kt = 0; kt < KT; kt++){
    int bb = kt & 1;
    if (kt + 1 < KT){
      int b2 = bb ^ 1;
      stage128(A, smem + b2*32768,         m0, K, (kt+1)*128);
      stage128(B, smem + b2*32768 + 16384, 0,  K, (kt+1)*128);
    }
    compute128(smem + bb*32768, smem + bb*32768 + 16384, wm, wn, r15, kg, acc);
    __syncthreads();
  }
  float* lnbuf = (float*)smem;   // [128][132]
  float vo0 = 0.f, vo1 = 0.f, vo2 = 0.f;
  if (mode == 1){ vo0 = vo[0]; vo1 = vo[1]; vo2 = vo[2]; }
  #pragma unroll
  for (int i = 0; i < 2; i++){
    #pragma unroll
    for (int j = 0; j < 4; j++){
      int col = wn*64 + j*16 + r15;
      float bv = bias[col];
      float p0 = 0, p1 = 0, p2 = 0;
      if (mode == 1){ p0 = peT[col]; p1 = peT[128+col]; p2 = peT[256+col]; }
      #pragma unroll
      for (int rr = 0; rr < 4; rr++){
        int row = wm*32 + i*16 + kg*4 + rr;
        int q = m0 + row;
        size_t oi = (size_t)q*128 + col;
        float x = acc[i][j][rr] + bv;
        if (mode == 1){
          float px = ((float)(q >> 9)      + 0.5f)*0.8f + vo0;
          float py = ((float)((q >> 3)&63) + 0.5f)*0.8f + vo1;
          float pz = ((float)(q & 7)       + 0.5f)*0.8f + vo2;
          x += resSrc[oi] + p0*px + p1*py + p2*pz;
        } else {
          x += resSrc[oi];
        }
        lnbuf[row*132 + col] = x;
      }
    }
  }
  __syncthreads();
  int r = w*16 + (lane >> 2), j4 = lane & 3;
  const float* rowp = lnbuf + r*132;
  float s = 0.f;
  #pragma unroll
  for (int k = 0; k < 32; k++) s += rowp[j4 + 4*k];
  s += __shfl_xor(s, 1, 64); s += __shfl_xor(s, 2, 64);
  float mean = s * (1.0f/128.0f);
  float vv = 0.f;
  #pragma unroll
  for (int k = 0; k < 32; k++){ float d = rowp[j4 + 4*k] - mean; vv += d*d; }
  vv += __shfl_xor(vv, 1, 64); vv += __shfl_xor(vv, 2, 64);
  float rs = rsqrtf(vv*(1.0f/128.0f) + 1e-5f);
  int gq = m0 + r;
  #pragma unroll
  for (int k = 0; k < 32; k++){
    int c = j4 + 4*k;
    float o = (rowp[c] - mean)*rs*g[c] + b[c];
    size_t oi = (size_t)gq*128 + c;
    if (fov){
      outB[oi] = f2bf(fov[gq] ? o : qe[oi]);
    } else {
      if (outF) outF[oi] = o;
      if (outB) outB[oi] = f2bf(o);
    }
  }
}

// ---------------- dilated 3x3x3 conv: z-reuse A staging + counted-vmcnt 2-barrier phases ----
__global__ __launch_bounds__(512) void k_conv3(
    const u16* __restrict__ X, const u16* __restrict__ W,
    const float* __restrict__ bias, const u16* __restrict__ zp,
    u16* __restrict__ Y, int dil)
{
  extern __shared__ u16 smem[];
  u16* bufA0 = smem;
  u16* bufA1 = smem + 16384;
  u16* bufW0 = smem + 32768;
  u16* bufW1 = smem + 49152;
  int tid = threadIdx.x, lane = tid & 63, w = tid >> 6;
  int wm = w & 3, wn = w >> 2, r15 = lane & 15, kg = lane >> 4;
  int m0 = blockIdx.x*128;
  v4f acc[2][4] = {};
  const v8s vzero = {0,0,0,0,0,0,0,0};
  // prologue: A(group 0), W(tap 0)
  stageConvA(X, zp, bufA0, m0, -dil, -dil, 0);
  stage128(W, bufW0, 0, 128, 0);
  for (int g = 0; g < 9; g++){
    const u16* As = (g & 1) ? bufA1 : bufA0;
    #pragma unroll
    for (int dzi = 0; dzi < 3; dzi++){
      int t = g*3 + dzi;
      const u16* Ws = (t & 1) ? bufW1 : bufW0;
      // issue next stages (targets = buffers last read 2 phases ago, barrier-protected)
      if (t + 1 < 27)
        stage128(W + (size_t)(t+1)*16384, ((t+1)&1) ? bufW1 : bufW0, 0, 128, 0);
      if (dzi == 0 && g < 8){
        int gn = g + 1;
        stageConvA(X, zp, (gn & 1) ? bufA1 : bufA0, m0, (gn/3 - 1)*dil, (gn%3 - 1)*dil, 0);
      }
      // counted wait: allow exactly this iteration's issues to stay in flight
      if (dzi == 0){
        if (g < 8) asm volatile("s_waitcnt vmcnt(8)" ::: "memory");
        else       asm volatile("s_waitcnt vmcnt(4)" ::: "memory");
      } else {
        if (t < 26) asm volatile("s_waitcnt vmcnt(4)" ::: "memory");
        else        asm volatile("s_waitcnt vmcnt(0)" ::: "memory");
      }
      __builtin_amdgcn_s_barrier();
      asm volatile("" ::: "memory");
      // compute tap t: A rows z-shifted by (dzi-1)*dil, zero outside z range
      int zofs = (dzi - 1)*dil;
      bool okz = (unsigned)((r15 & 7) + zofs) < 8u;
      int ra0 = wm*32 + r15 + zofs;
      int rc0 = min(max(ra0, 0), 127);
      int rc1 = min(max(ra0 + 16, 0), 127);
      #pragma unroll
      for (int k0 = 0; k0 < 4; k0++){
        int cb = k0*64 + kg*16;
        v8s a0 = fragld(As, rc0, cb);
        v8s a1 = fragld(As, rc1, cb);
        if (!okz){ a0 = vzero; a1 = vzero; }
        v8s b0 = fragld(Ws, wn*64 +      r15, cb);
        v8s b1 = fragld(Ws, wn*64 + 16 + r15, cb);
        v8s b2 = fragld(Ws, wn*64 + 32 + r15, cb);
        v8s b3 = fragld(Ws, wn*64 + 48 + r15, cb);
        acc[0][0] = __builtin_amdgcn_mfma_f32_16x16x32_bf16(a0, b0, acc[0][0], 0, 0, 0);
        acc[0][1] = __builtin_amdgcn_mfma_f32_16x16x32_bf16(a0, b1, acc[0][1], 0, 0, 0);
        acc[0][2] = __builtin_amdgcn_mfma_f32_16x16x32_bf16(a0, b2, acc[0][2], 0, 0, 0);
        acc[0][3] = __builtin_amdgcn_mfma_f32_16x16x32_bf16(a0, b3, acc[0][3], 0, 0, 0);
        acc[1][0] = __builtin_amdgcn_mfma_f32_16x16x32_bf16(a1, b0, acc[1][0], 0, 0, 0);
        acc[1][1] = __builtin_amdgcn_mfma_f32_16x16x32_bf16(a1, b1, acc[1][1], 0, 0, 0);
        acc[1][2] = __builtin_amdgcn_mfma_f32_16x16x32_bf16(a1, b2, acc[1][2], 0, 0, 0);
        acc[1][3] = __builtin_amdgcn_mfma_f32_16x16x32_bf16(a1, b3, acc[1][3], 0, 0, 0);
      }
      asm volatile("" ::: "memory");
      __builtin_amdgcn_s_barrier();
      asm volatile("" ::: "memory");
    }
  }
  #pragma unroll
  for (int i = 0; i < 2; i++){
    #pragma unroll
    for (int j = 0; j < 4; j++){
      int col = wn*64 + j*16 + r15;
      float bv = bias[col];
      #pragma unroll
      for (int rr = 0; rr < 4; rr++){
        int row = m0 + wm*32 + i*16 + kg*4 + rr;
        float v = acc[i][j][rr] + bv + bf2f(X[(size_t)row*128 + col]);
        v = fmaxf(v, 0.0f);
        Y[(size_t)row*128 + col] = f2bf(v);
      }
    }
  }
}

// ---------------- MFMA cross-attention ----------------
__global__ __launch_bounds__(256) void k_attn2(
    const u16* __restrict__ QB, const u16* __restrict__ KH, const u16* __restrict__ VT,
    const float* __restrict__ biasArr, u16* __restrict__ O)
{
  __shared__ float sb[128];
  __shared__ u16 sp[4][32*128];
  int tid = threadIdx.x, lane = tid & 63, w = tid >> 6;
  if (tid < 128) sb[tid] = biasArr[tid];
  __syncthreads();
  int c = lane & 15, r = lane >> 4;
  int q0 = blockIdx.x * 64;
  const u16* Kh = KH + (size_t)w*128*32;
  const u16* Vh = VT + (size_t)w*32*128;
  char* spw = (char*)&sp[w][0];

  v8s kf[8];
  #pragma unroll
  for (int kt = 0; kt < 8; kt++) kf[kt] = *(const v8s*)(Kh + (kt*16 + c)*32 + r*8);
  v8s vf[4][2];
  #pragma unroll
  for (int ks = 0; ks < 4; ks++)
    #pragma unroll
    for (int dt = 0; dt < 2; dt++)
      vf[ks][dt] = *(const v8s*)(Vh + (dt*16 + c)*128 + ks*32 + r*8);
  float bv[8][4];
  #pragma unroll
  for (int kt = 0; kt < 8; kt++){
    float4 t = *(const float4*)&sb[kt*16 + r*4];
    bv[kt][0] = t.x; bv[kt][1] = t.y; bv[kt][2] = t.z; bv[kt][3] = t.w;
  }

  #pragma unroll
  for (int half = 0; half < 2; half++){
    v4f s[2][8] = {};
    #pragma unroll
    for (int qt2 = 0; qt2 < 2; qt2++){
      int qt = half*2 + qt2;
      v8s qf = *(const v8s*)(QB + (size_t)(q0 + qt*16 + c)*128 + w*32 + r*8);
      #pragma unroll
      for (int kt = 0; kt < 8; kt++)
        s[qt2][kt] = __builtin_amdgcn_mfma_f32_16x16x32_bf16(kf[kt], qf, s[qt2][kt], 0, 0, 0);
    }
    #pragma unroll
    for (int qt2 = 0; qt2 < 2; qt2++){
      float mx = -1e30f;
      #pragma unroll
      for (int kt = 0; kt < 8; kt++)
        #pragma unroll
        for (int rg = 0; rg < 4; rg++){
          s[qt2][kt][rg] += bv[kt][rg];
          mx = fmaxf(mx, s[qt2][kt][rg]);
        }
      mx = fmaxf(mx, __shfl_xor(mx, 16, 64));
      mx = fmaxf(mx, __shfl_xor(mx, 32, 64));
      float sum = 0.f;
      #pragma unroll
      for (int kt = 0; kt < 8; kt++)
        #pragma unroll
        for (int rg = 0; rg < 4; rg++){
          float p = __expf(s[qt2][kt][rg] - mx);
          s[qt2][kt][rg] = p;
          sum += p;
        }
      sum += __shfl_xor(sum, 16, 64);
      sum += __shfl_xor(sum, 32, 64);
      float inv = 1.0f / sum;
      int row = qt2*16 + c;
      int rbyte = row*256;
      int rxx = (row & 7) << 4;
      #pragma unroll
      for (int kt = 0; kt < 8; kt++){
        #pragma unroll
        for (int pr = 0; pr < 2; pr++){
          u32 pk = (u32)f2bf(s[qt2][kt][pr*2]*inv) | ((u32)f2bf(s[qt2][kt][pr*2+1]*inv) << 16);
          int colb = kt*32 + r*8 + pr*4;
          *(u32*)(spw + rbyte + (colb ^ rxx)) = pk;
        }
      }
    }
    v4f o[2][2] = {};
    #pragma unroll
    for (int ks = 0; ks < 4; ks++){
      #pragma unroll
      for (int qt2 = 0; qt2 < 2; qt2++){
        int row = qt2*16 + c;
        int colb = ks*64 + r*16;
        v8s aP = *(const v8s*)(spw + row*256 + (colb ^ ((row & 7) << 4)));
        o[qt2][0] = __builtin_amdgcn_mfma_f32_16x16x32_bf16(aP, vf[ks][0], o[qt2][0], 0, 0, 0);
        o[qt2][1] = __builtin_amdgcn_mfma_f32_16x16x32_bf16(aP, vf[ks][1], o[qt2][1], 0, 0, 0);
      }
    }
    #pragma unroll
    for (int qt2 = 0; qt2 < 2; qt2++){
      #pragma unroll
      for (int dt = 0; dt < 2; dt++){
        #pragma unroll
        for (int rg = 0; rg < 4; rg++){
          int qq = q0 + (half*2 + qt2)*16 + r*4 + rg;
          O[(size_t)qq*128 + w*32 + dt*16 + c] = f2bf(o[qt2][dt][rg]);
        }
      }
    }
  }
}

// ---------------- 1x1x1 head conv -> d_out [20][32768] ----------------
__global__ __launch_bounds__(256) void k_outconv(const u16* __restrict__ X,
    const float* __restrict__ W, const float* __restrict__ B, float* __restrict__ out)
{
  __shared__ float sw[20*128];
  __shared__ float sbb[20];
  int tid = threadIdx.x;
  for (int i = tid; i < 20*128; i += 256) sw[i] = W[i];
  if (tid < 20) sbb[tid] = B[tid];
  __syncthreads();
  int s = blockIdx.x*256 + tid;
  u32 rv[64];
  const u32* xp = (const u32*)(X + (size_t)s*128);
  #pragma unroll
  for (int j = 0; j < 64; j++) rv[j] = xp[j];
  for (int ot = 0; ot < 20; ot++){
    float acc = sbb[ot];
    #pragma unroll
    for (int j = 0; j < 64; j++){
      u32 u = rv[j];
      acc += bf2f((u16)(u & 0xffff))*sw[ot*128 + 2*j] + bf2f((u16)(u >> 16))*sw[ot*128 + 2*j + 1];
    }
    out[(size_t)ot*NQv + s] = acc;
  }
}

extern "C" void kernel_launch(void* const* d_in, const int* in_sizes, int n_in,
                              void* d_out, int out_size, void* d_ws, size_t ws_size,
                              hipStream_t stream)
{
  const float* iq    = (const float*)d_in[0];
  const float* logits= (const float*)d_in[1];
  const float* pmL   = (const float*)d_in[2];
  const float* depth = (const float*)d_in[3];
  const float* Km    = (const float*)d_in[4];
  const float* Em    = (const float*)d_in[5];
  const float* vo    = (const float*)d_in[6];
  const float* qe    = (const float*)d_in[7];
  const float* pe    = (const float*)d_in[8];
  const float* ain_w = (const float*)d_in[9];
  const float* ain_b = (const float*)d_in[10];
  const float* aout_w= (const float*)d_in[11];
  const float* aout_b= (const float*)d_in[12];
  const float* ln1g  = (const float*)d_in[13];
  const float* ln1b  = (const float*)d_in[14];
  const float* w1    = (const float*)d_in[15];
  const float* b1    = (const float*)d_in[16];
  const float* w2    = (const float*)d_in[17];
  const float* b2    = (const float*)d_in[18];
  const float* ln2g  = (const float*)d_in[19];
  const float* ln2b  = (const float*)d_in[20];
  const float* pw    = (const float*)d_in[21];
  const float* pb    = (const float*)d_in[22];
  const float* ow    = (const float*)d_in[23];
  const float* ob    = (const float*)d_in[24];
  const int*   fov   = (const int*)d_in[25];
  float* out = (float*)d_out;

  (void)hipFuncSetAttribute((const void*)k_gemm2,  hipFuncAttributeMaxDynamicSharedMemorySize, 131072);
  (void)hipFuncSetAttribute((const void*)k_gemmln, hipFuncAttributeMaxDynamicSharedMemorySize, 131072);
  (void)hipFuncSetAttribute((const void*)k_conv3,  hipFuncAttributeMaxDynamicSharedMemorySize, 131072);
  (void)hipFuncSetAttribute((const void*)k_qproj,  hipFuncAttributeMaxDynamicSharedMemorySize, 65536);

  char* ws = (char*)d_ws;
  size_t off = 0;
  auto alloc = [&](size_t bytes) -> char* {
    char* p = ws + off;
    off = (off + bytes + 255) & ~(size_t)255;
    return p;
  };
  float* mats    = (float*)alloc(32*4);
  float* scores  = (float*)alloc(128*4);
  int*   keep0   = (int*)  alloc(128*4);
  int*   keep    = (int*)  alloc(128*4);
  float* biasArr = (float*)alloc(128*4);
  float* xyz     = (float*)alloc(512*4);
  u16*   zp      = (u16*)  alloc(256);
  float* peT     = (float*)alloc(384*4);
  int*   mids    = (int*)  alloc((size_t)HWp*4);
  float* kvkb    = (float*)alloc((size_t)NI*128*4);
  u16* khs_bf  = (u16*)alloc((size_t)3*4*128*32*2);
  u16* vt_bf   = (u16*)alloc((size_t)3*4*32*128*2);
  u16* ain_bf  = (u16*)alloc((size_t)3*384*128*2);
  u16* aout_bf = (u16*)alloc((size_t)3*128*128*2);
  u16* w1_bf   = (u16*)alloc((size_t)3*512*128*2);
  u16* w2_bf   = (u16*)alloc((size_t)3*128*512*2);
  u16* wc_bf   = (u16*)alloc((size_t)3*27*128*128*2);
  float* T1 = (float*)alloc((size_t)NQv*128*4);
  float* T2 = (float*)alloc((size_t)NQv*128*4);
  u16*  XB = (u16*) alloc((size_t)NQv*128*2);
  u16*  HB = (u16*) alloc((size_t)NQv*512*2);
  u16* QB  = HB;           // q-projection (HB free until FFN1)
  u16* x3a = XB;           // conv ping
  u16* x3b = HB;           // conv pong
  (void)ws_size; (void)in_sizes; (void)n_in; (void)out_size;

  // ---- prep ----
  k_prep_small<<<1,128,0,stream>>>(Km, Em, logits, mats, scores, keep0);
  {
    int n0 = 3*384*128, n1 = 3*128*128, n2 = 3*512*128, n3 = 3*128*512;
    int zn0 = 3*4*128*32, zn1 = 3*4*32*128, zn2 = 128;
    int total = n0+n1+n2+n3+zn0+zn1+zn2+384;
    k_prep_multi<<<(total+255)/256,256,0,stream>>>(
        ain_w, ain_bf, n0, aout_w, aout_bf, n1, w1, w1_bf, n2, w2, w2_bf, n3,
        khs_bf, zn0, vt_bf, zn1, zp, zn2, pe, peT);
  }
  k_packconv2<<<dim3(128,3),256,0,stream>>>(pw, wc_bf);
  k_mask_argmax2<<<120,256,0,stream>>>(pmL, scores, keep0, mids);
  k_instbp<<<NI,256,0,stream>>>(pmL, mids, keep0, depth, mats, keep, xyz);
  k_kvk<<<(NI*128+255)/256,256,0,stream>>>(iq, pe, xyz, keep, kvkb);
  { dim3 g(3,4); k_khvh2<<<g,512,0,stream>>>(kvkb, iq, ain_w, ain_b, keep, biasArr, khs_bf, vt_bf); }

  // ---- 3 transformer layers ----
  for (int li = 0; li < 3; li++){
    const float* src = (li == 0) ? qe : T2;
    k_qproj<<<256,512,65536,stream>>>(src, peT, vo, ain_bf + (size_t)li*384*128,
                                      ain_b + li*384, QB);
    k_attn2<<<512,256,0,stream>>>(QB, khs_bf + (size_t)li*4*128*32,
                                  vt_bf + (size_t)li*4*32*128, biasArr, XB);
    // out-proj + residual(src+qpos) + LN1 -> T1 (f32) + XB (bf16)
    k_gemmln<<<256,512,69632,stream>>>(XB, aout_bf + (size_t)li*128*128, aout_b + li*128,
                                       src, peT, vo, ln1g + li*128, ln1b + li*128,
                                       T1, XB, nullptr, nullptr, 128, 1, 1);
    k_gemm2<<<dim3(256,4),512,65536,stream>>>(XB, w1_bf + (size_t)li*512*128, b1 + li*512,
                                              nullptr, nullptr, HB, 512, 128, 1, 1);
    if (li < 2){
      k_gemmln<<<256,512,131072,stream>>>(HB, w2_bf + (size_t)li*128*512, b2 + li*128,
                                          T1, nullptr, nullptr, ln2g + li*128, ln2b + li*128,
                                          T2, nullptr, nullptr, nullptr, 512, 4, 0);
    } else {
      k_gemmln<<<256,512,131072,stream>>>(HB, w2_bf + (size_t)li*128*512, b2 + li*128,
                                          T1, nullptr, nullptr, ln2g + li*128, ln2b + li*128,
                                          nullptr, x3a, fov, qe, 512, 4, 0);
    }
  }

  // ---- conv stack ----
  k_conv3<<<256,512,131072,stream>>>(x3a, wc_bf + (size_t)0*27*16384, pb + 0,   zp, x3b, 1);
  k_conv3<<<256,512,131072,stream>>>(x3b, wc_bf + (size_t)1*27*16384, pb + 128, zp, x3a, 2);
  k_conv3<<<256,512,131072,stream>>>(x3a, wc_bf + (size_t)2*27*16384, pb + 256, zp, x3b, 3);
  k_outconv<<<128,256,0,stream>>>(x3b, ow, ob, out);
}

// Round 7
// 486.070 us; speedup vs baseline: 2.9574x; 1.0128x over previous
//
#include <hip/hip_runtime.h>
#include <math.h>

typedef unsigned short u16;
typedef unsigned int   u32;

#define NQv 32768
#define HWp 7680
#define NI  100

typedef short v8s __attribute__((ext_vector_type(8)));
typedef float v4f __attribute__((ext_vector_type(4)));

__device__ inline float bf2f(u16 u){ u32 x = ((u32)u) << 16; return __uint_as_float(x); }
__device__ inline u16 f2bf(float f){
  u32 x = __float_as_uint(f);
  u32 r = (x + 0x7fffu + ((x >> 16) & 1u)) >> 16;
  return (u16)r;
}
__device__ inline float sigf(float x){ return 1.0f / (1.0f + expf(-x)); }

typedef const __attribute__((address_space(1))) void* gas_t;
typedef __attribute__((address_space(3))) void* las_t;

// ---------------- small prep: invert K (3x3) and E (4x4), instance scores ----------------
__global__ void k_prep_small(const float* __restrict__ Km, const float* __restrict__ Em,
                             const float* __restrict__ logits,
                             float* __restrict__ mats, float* __restrict__ scores,
                             int* __restrict__ keep0)
{
  int tid = threadIdx.x;
  if (tid == 0) {
    double a[9];
    for (int i = 0; i < 9; i++) a[i] = (double)Km[i];
    double det = a[0]*(a[4]*a[8]-a[5]*a[7]) - a[1]*(a[3]*a[8]-a[5]*a[6]) + a[2]*(a[3]*a[7]-a[4]*a[6]);
    double id = 1.0 / det;
    double inv[9];
    inv[0]=(a[4]*a[8]-a[5]*a[7])*id; inv[1]=(a[2]*a[7]-a[1]*a[8])*id; inv[2]=(a[1]*a[5]-a[2]*a[4])*id;
    inv[3]=(a[5]*a[6]-a[3]*a[8])*id; inv[4]=(a[0]*a[8]-a[2]*a[6])*id; inv[5]=(a[2]*a[3]-a[0]*a[5])*id;
    inv[6]=(a[3]*a[7]-a[4]*a[6])*id; inv[7]=(a[1]*a[6]-a[0]*a[7])*id; inv[8]=(a[0]*a[4]-a[1]*a[3])*id;
    for (int i = 0; i < 9; i++) mats[i] = (float)inv[i];
    double m[4][8];
    for (int r = 0; r < 4; r++){
      for (int c = 0; c < 4; c++){ m[r][c] = (double)Em[r*4+c]; m[r][4+c] = (r==c) ? 1.0 : 0.0; }
    }
    for (int col = 0; col < 4; col++){
      int piv = col; double best = fabs(m[col][col]);
      for (int r = col+1; r < 4; r++){ double v = fabs(m[r][col]); if (v > best){ best = v; piv = r; } }
      if (piv != col){ for (int c = 0; c < 8; c++){ double t = m[col][c]; m[col][c] = m[piv][c]; m[piv][c] = t; } }
      double p = m[col][col];
      for (int c = 0; c < 8; c++) m[col][c] /= p;
      for (int r = 0; r < 4; r++) if (r != col){ double f = m[r][col]; for (int c = 0; c < 8; c++) m[r][c] -= f*m[col][c]; }
    }
    for (int r = 0; r < 3; r++) for (int c = 0; c < 4; c++) mats[9 + r*4 + c] = (float)m[r][4+c];
  }
  if (tid < NI) {
    float mx = -1e30f;
    for (int c = 0; c < 21; c++){ float t = sigf(logits[tid*21+c]) / 0.06f; mx = fmaxf(mx, t); }
    float s = 0.f;
    for (int c = 0; c < 21; c++){ float t = sigf(logits[tid*21+c]) / 0.06f; s += expf(t - mx); }
    float sc = 1.0f / s;
    scores[tid] = sc;
    keep0[tid] = (sc > 0.25f) ? 1 : 0;
  }
}

// ---- one launch: 4 weight f32->bf16 converts + 2 zero-fills + zero page + pe transpose ----
__global__ void k_prep_multi(
    const float* __restrict__ s0, u16* __restrict__ d0, int n0,
    const float* __restrict__ s1, u16* __restrict__ d1, int n1,
    const float* __restrict__ s2, u16* __restrict__ d2, int n2,
    const float* __restrict__ s3, u16* __restrict__ d3, int n3,
    u16* __restrict__ z0, int zn0, u16* __restrict__ z1, int zn1,
    u16* __restrict__ z2, int zn2,
    const float* __restrict__ pe, float* __restrict__ peT)
{
  int i = blockIdx.x*256 + threadIdx.x;
  if (i < n0){ d0[i] = f2bf(s0[i]); return; } i -= n0;
  if (i < n1){ d1[i] = f2bf(s1[i]); return; } i -= n1;
  if (i < n2){ d2[i] = f2bf(s2[i]); return; } i -= n2;
  if (i < n3){ d3[i] = f2bf(s3[i]); return; } i -= n3;
  if (i < zn0){ z0[i] = 0; return; } i -= zn0;
  if (i < zn1){ z1[i] = 0; return; } i -= zn1;
  if (i < zn2){ z2[i] = 0; return; } i -= zn2;
  if (i < 384){ int d = i >> 7, c = i & 127; peT[i] = pe[c*3 + d]; }
}

// ---------------- per-pixel argmax, instance axis split across 4 waves ----------------
__global__ __launch_bounds__(256) void k_mask_argmax2(
    const float* __restrict__ pmL, const float* __restrict__ scores,
    const int* __restrict__ keep0, int* __restrict__ mids)
{
  __shared__ float sv[4][64];
  __shared__ int   si[4][64];
  int tid = threadIdx.x, lane = tid & 63, w = tid >> 6;
  int p = blockIdx.x*64 + lane;
  float best = -2e30f; int bid = 0;
  #pragma unroll 5
  for (int jj = 0; jj < 25; jj++){
    int i = w*25 + jj;
    float lg = pmL[i*HWp + p];
    float val = keep0[i] ? scores[i] * sigf(lg) : -1.0f;
    if (val > best){ best = val; bid = i; }
  }
  sv[w][lane] = best; si[w][lane] = bid;
  __syncthreads();
  if (w == 0){
    float b0 = sv[0][lane]; int i0 = si[0][lane];
    #pragma unroll
    for (int g = 1; g < 4; g++){
      float bg = sv[g][lane]; int ig = si[g][lane];
      if (bg > b0 || (bg == b0 && ig < i0)){ b0 = bg; i0 = ig; }
    }
    mids[p] = i0;
  }
}

// ---------------- merged per-instance stats + keep + back-projection ----------------
__global__ __launch_bounds__(256) void k_instbp(
    const float* __restrict__ pmL, const int* __restrict__ mids,
    const int* __restrict__ keep0, const float* __restrict__ depth,
    const float* __restrict__ mats, int* __restrict__ keep, float* __restrict__ xyz)
{
  int i = blockIdx.x, tid = threadIdx.x;
  int k0 = keep0[i];
  int ma = 0, pa = 0, it = 0;
  for (int p = tid; p < HWp; p += 256){
    float lg = pmL[i*HWp + p];
    int pb = (lg >= 0.0f) ? 1 : 0;
    int mi = (mids[p] == i && k0) ? 1 : 0;
    ma += mi; pa += pb; it += (mi & pb);
  }
  __shared__ int sma[256], spa[256], sit[256];
  __shared__ int s_keep;
  sma[tid] = ma; spa[tid] = pa; sit[tid] = it;
  __syncthreads();
  for (int off = 128; off; off >>= 1){
    if (tid < off){ sma[tid]+=sma[tid+off]; spa[tid]+=spa[tid+off]; sit[tid]+=sit[tid+off]; }
    __syncthreads();
  }
  if (tid == 0){
    int kk = (k0 && sit[0] > 0 && ((float)sma[0] >= 0.8f*(float)spa[0])) ? 1 : 0;
    keep[i] = kk; s_keep = kk;
  }
  __syncthreads();
  float sx = 0.f, sy = 0.f, sz = 0.f;
  if (s_keep){
    float ik0=mats[0],ik1=mats[1],ik2=mats[2],ik3=mats[3],ik4=mats[4],ik5=mats[5],ik6=mats[6],ik7=mats[7],ik8=mats[8];
    const float* iE = mats + 9;
    for (int p = tid; p < HWp; p += 256){
      if (mids[p] == i && pmL[i*HWp + p] >= 0.0f){
        int r = p / 160, c = p % 160;
        float xg = (float)((double)c * (1279.0/159.0));
        float yg = (float)((double)r * (383.0/47.0));
        float d = depth[p];
        float g0 = xg*d, g1 = yg*d, g2 = d;
        float c0 = ik0*g0 + ik1*g1 + ik2*g2;
        float c1 = ik3*g0 + ik4*g1 + ik5*g2;
        float c2 = ik6*g0 + ik7*g1 + ik8*g2;
        sx += iE[0]*c0 + iE[1]*c1 + iE[2]*c2 + iE[3];
        sy += iE[4]*c0 + iE[5]*c1 + iE[6]*c2 + iE[7];
        sz += iE[8]*c0 + iE[9]*c1 + iE[10]*c2 + iE[11];
      }
    }
  }
  __shared__ float rx[256], ry[256], rz[256];
  rx[tid]=sx; ry[tid]=sy; rz[tid]=sz;
  __syncthreads();
  for (int off = 128; off; off >>= 1){
    if (tid < off){ rx[tid]+=rx[tid+off]; ry[tid]+=ry[tid+off]; rz[tid]+=rz[tid+off]; }
    __syncthreads();
  }
  if (tid == 0){ xyz[i*3+0]=rx[0]; xyz[i*3+1]=ry[0]; xyz[i*3+2]=rz[0]; }
}

// ---------------- kv_k = inst_queries + use * (xyz @ pos_embed^T); use from keep scan ----
__global__ void k_kvk(const float* __restrict__ iq, const float* __restrict__ pe,
                      const float* __restrict__ xyz, const int* __restrict__ keep,
                      float* __restrict__ kvk)
{
  int tid = threadIdx.x;
  unsigned long long b = __ballot(tid < 100 && keep[tid] != 0);
  __shared__ int s_w[4];
  if ((tid & 63) == 0) s_w[tid >> 6] = (b != 0ULL);
  __syncthreads();
  float u = (s_w[0] | s_w[1]) ? 1.0f : 0.0f;
  int idx = blockIdx.x*256 + tid;
  if (idx >= NI*128) return;
  int i = idx >> 7, c = idx & 127;
  float ip = pe[c*3+0]*xyz[i*3+0] + pe[c*3+1]*xyz[i*3+1] + pe[c*3+2]*xyz[i*3+2];
  kvk[idx] = iq[idx] + u * ip;
}

// ---------------- K/V head projections -> bf16 MFMA-ready layouts (+ biasArr by block 0,0) ----
__global__ __launch_bounds__(512) void k_khvh2(const float* __restrict__ kvk,
    const float* __restrict__ iq, const float* __restrict__ Win,
    const float* __restrict__ bin, const int* __restrict__ keep,
    float* __restrict__ biasArr, u16* __restrict__ khs_bf, u16* __restrict__ vt_bf)
{
  __shared__ u16 s_in[NI][130];
  __shared__ u16 s_w[64][130];
  __shared__ int s_any[8];
  int li = blockIdx.x, c0 = blockIdx.y*64;
  bool isK = (c0 < 128);
  const float* srcIn = isK ? kvk : iq;
  int tid = threadIdx.x;
  unsigned long long bm = __ballot(tid < 100 && keep[tid] != 0);
  if ((tid & 63) == 0) s_any[tid >> 6] = (bm != 0ULL);
  for (int i = tid; i < NI*128; i += 512) s_in[i>>7][i&127] = f2bf(srcIn[i]);
  const float* wbase = Win + ((size_t)li*384 + 128 + c0)*128;
  for (int i = tid; i < 64*128; i += 512) s_w[i>>7][i&127] = f2bf(wbase[i]);
  __syncthreads();
  if (li == 0 && c0 == 0 && tid < 128){
    int any = s_any[0] | s_any[1];
    float bb;
    if (tid < NI) bb = any ? (keep[tid] ? 0.0f : -1e9f) : 0.0f;
    else bb = -1e9f;
    biasArr[tid] = bb;
  }
  for (int o = tid; o < NI*64; o += 512){
    int k = o >> 6, c = o & 63;
    float acc = 0.f;
    #pragma unroll 8
    for (int j = 0; j < 128; j++) acc += bf2f(s_in[k][j]) * bf2f(s_w[c][j]);
    int cc = c0 + c;
    float v = acc + bin[li*384 + 128 + cc];
    int ch = cc & 127;
    if (isK) khs_bf[(((size_t)li*4 + (ch>>5))*128 + k)*32 + (ch&31)] = f2bf(v * 0.17677669529663687f);
    else     vt_bf [(((size_t)li*4 + (ch>>5))*32 + (ch&31))*128 + k] = f2bf(v);
  }
}

// conv weights [li][o][i][t] -> [li][t][o][i] bf16, block per (o, li)
__global__ __launch_bounds__(256) void k_packconv2(const float* __restrict__ w, u16* __restrict__ wp)
{
  __shared__ u16 s[3456];
  int o = blockIdx.x, li = blockIdx.y;
  const float* src = w + ((size_t)li*128 + o)*3456;
  for (int t = threadIdx.x; t < 3456; t += 256) s[t] = f2bf(src[t]);
  __syncthreads();
  for (int e = threadIdx.x; e < 3456; e += 256){
    int t = e >> 7, i = e & 127;
    wp[(((size_t)li*27 + t)*128 + o)*128 + i] = s[i*27 + t];
  }
}

// ================= tiled MFMA infrastructure =================
// 512 threads: 4 issues x 512 x 16 B = 32 KB (full tile)
__device__ inline void stage128(const u16* __restrict__ G, u16* lds,
                                int rbase, int pitchK, int kofs)
{
  int lane = threadIdx.x & 63, w = threadIdx.x >> 6;
  #pragma unroll
  for (int s = 0; s < 4; s++){
    int ldsOff = s*8192 + w*1024 + lane*16;   // bytes
    int row = ldsOff >> 8;
    int cb  = ldsOff & 255;
    int scb = cb ^ ((row & 7) << 4);
    const u16* src = G + (size_t)(rbase + row)*pitchK + kofs + (scb >> 1);
    u16* dst = lds + (s*4096 + w*512);
    __builtin_amdgcn_global_load_lds((gas_t)src, (las_t)dst, 16, 0, 0);
  }
}

// conv A stage: (dx,dy) shift only, z handled at read time. 4 issues = full 32 KB.
__device__ inline void stageConvA4(const u16* __restrict__ X, const u16* __restrict__ zp,
                                   u16* lds, int m0, int dx, int dy)
{
  int lane = threadIdx.x & 63, w = threadIdx.x >> 6;
  #pragma unroll
  for (int s = 0; s < 4; s++){
    int ldsOff = s*8192 + w*1024 + lane*16;
    int row = ldsOff >> 8;
    int cb  = ldsOff & 255;
    int scb = cb ^ ((row & 7) << 4);
    int sidx = m0 + row;
    int xs = (sidx >> 9) + dx, ys = ((sidx >> 3) & 63) + dy, zs = sidx & 7;
    bool ok = ((unsigned)xs < 64u) & ((unsigned)ys < 64u);
    const u16* src = ok ? (X + (size_t)((xs*64+ys)*8+zs)*128 + (scb>>1)) : (zp + (scb>>1));
    u16* dst = lds + (s*4096 + w*512);
    __builtin_amdgcn_global_load_lds((gas_t)src, (las_t)dst, 16, 0, 0);
  }
}

__device__ inline v8s fragld(const u16* base, int row, int cb){
  return *(const v8s*)(base + row*128 + (((cb) ^ ((row & 7) << 4)) >> 1));
}

__device__ inline void compute128(const u16* As, const u16* Bs,
                                  int wm, int wn, int r15, int kg, v4f acc[2][4])
{
  #pragma unroll
  for (int k0 = 0; k0 < 4; k0++){
    int cb = k0*64 + kg*16;
    v8s a0 = fragld(As, wm*32 +      r15, cb);
    v8s a1 = fragld(As, wm*32 + 16 + r15, cb);
    v8s b0 = fragld(Bs, wn*64 +      r15, cb);
    v8s b1 = fragld(Bs, wn*64 + 16 + r15, cb);
    v8s b2 = fragld(Bs, wn*64 + 32 + r15, cb);
    v8s b3 = fragld(Bs, wn*64 + 48 + r15, cb);
    acc[0][0] = __builtin_amdgcn_mfma_f32_16x16x32_bf16(a0, b0, acc[0][0], 0, 0, 0);
    acc[0][1] = __builtin_amdgcn_mfma_f32_16x16x32_bf16(a0, b1, acc[0][1], 0, 0, 0);
    acc[0][2] = __builtin_amdgcn_mfma_f32_16x16x32_bf16(a0, b2, acc[0][2], 0, 0, 0);
    acc[0][3] = __builtin_amdgcn_mfma_f32_16x16x32_bf16(a0, b3, acc[0][3], 0, 0, 0);
    acc[1][0] = __builtin_amdgcn_mfma_f32_16x16x32_bf16(a1, b0, acc[1][0], 0, 0, 0);
    acc[1][1] = __builtin_amdgcn_mfma_f32_16x16x32_bf16(a1, b1, acc[1][1], 0, 0, 0);
    acc[1][2] = __builtin_amdgcn_mfma_f32_16x16x32_bf16(a1, b2, acc[1][2], 0, 0, 0);
    acc[1][3] = __builtin_amdgcn_mfma_f32_16x16x32_bf16(a1, b3, acc[1][3], 0, 0, 0);
  }
}

// ---------------- tiled GEMM ----------------
__global__ __launch_bounds__(512) void k_gemm2(
    const u16* __restrict__ A, const u16* __restrict__ B,
    const float* __restrict__ bias, const float* __restrict__ res,
    float* __restrict__ outF, u16* __restrict__ outB,
    int N, int K, int KT, int act)
{
  extern __shared__ u16 smem[];
  int tid = threadIdx.x, lane = tid & 63, w = tid >> 6;
  int wm = w & 3, wn = w >> 2, r15 = lane & 15, kg = lane >> 4;
  int m0 = blockIdx.x*128, n0 = blockIdx.y*128;
  v4f acc[2][4] = {};
  stage128(A, smem + 0,     m0, K, 0);
  stage128(B, smem + 16384, n0, K, 0);
  __syncthreads();
  for (int kt = 0; kt < KT; kt++){
    int b = kt & 1;
    if (kt + 1 < KT){
      int b2 = b ^ 1;
      stage128(A, smem + b2*32768,         m0, K, (kt+1)*128);
      stage128(B, smem + b2*32768 + 16384, n0, K, (kt+1)*128);
    }
    compute128(smem + b*32768, smem + b*32768 + 16384, wm, wn, r15, kg, acc);
    __syncthreads();
  }
  #pragma unroll
  for (int i = 0; i < 2; i++){
    #pragma unroll
    for (int j = 0; j < 4; j++){
      int col = n0 + wn*64 + j*16 + r15;
      float bv = bias ? bias[col] : 0.0f;
      #pragma unroll
      for (int rr = 0; rr < 4; rr++){
        int row = m0 + wm*32 + i*16 + kg*4 + rr;
        float v = acc[i][j][rr] + bv;
        size_t oi = (size_t)row*N + col;
        if (res) v += res[oi];
        if (act == 1) v = 0.5f*v*(1.0f + erff(v*0.70710678118654752f));
        if (outF) outF[oi] = v;
        if (outB) outB[oi] = f2bf(v);
      }
    }
  }
}

// ---------------- fused addpos + Q-projection ----------------
__global__ __launch_bounds__(512) void k_qproj(
    const float* __restrict__ src, const float* __restrict__ peT,
    const float* __restrict__ vo, const u16* __restrict__ B,
    const float* __restrict__ bias, u16* __restrict__ QB)
{
  extern __shared__ u16 smem[];
  u16* sA = smem;
  u16* sB = smem + 16384;
  int tid = threadIdx.x, lane = tid & 63, w = tid >> 6;
  int wm = w & 3, wn = w >> 2, r15 = lane & 15, kg = lane >> 4;
  int m0 = blockIdx.x*128;
  stage128(B, sB, 0, 128, 0);
  int r = tid >> 2, c0 = (tid & 3)*32;
  int q = m0 + r;
  float px = ((float)(q >> 9)       + 0.5f)*0.8f + vo[0];
  float py = ((float)((q >> 3)&63)  + 0.5f)*0.8f + vo[1];
  float pz = ((float)(q & 7)        + 0.5f)*0.8f + vo[2];
  const float4* sp  = (const float4*)(src + (size_t)q*128 + c0);
  const float4* pex = (const float4*)(peT +   0 + c0);
  const float4* pey = (const float4*)(peT + 128 + c0);
  const float4* pez = (const float4*)(peT + 256 + c0);
  char* arow = (char*)sA + r*256;
  int rx = (r & 7) << 4;
  #pragma unroll
  for (int j = 0; j < 8; j++){
    float4 v = sp[j];
    float4 ax = pex[j], ay = pey[j], az = pez[j];
    float o0 = v.x + ax.x*px + ay.x*py + az.x*pz;
    float o1 = v.y + ax.y*px + ay.y*py + az.y*pz;
    float o2 = v.z + ax.z*px + ay.z*py + az.z*pz;
    float o3 = v.w + ax.w*px + ay.w*py + az.w*pz;
    int cbyte = (c0 + j*4)*2;
    *(u32*)(arow + ((cbyte    ) ^ rx)) = (u32)f2bf(o0) | ((u32)f2bf(o1) << 16);
    *(u32*)(arow + ((cbyte + 4) ^ rx)) = (u32)f2bf(o2) | ((u32)f2bf(o3) << 16);
  }
  __syncthreads();
  v4f acc[2][4] = {};
  compute128(sA, sB, wm, wn, r15, kg, acc);
  #pragma unroll
  for (int i = 0; i < 2; i++){
    #pragma unroll
    for (int j = 0; j < 4; j++){
      int col = wn*64 + j*16 + r15;
      float bv = bias[col];
      #pragma unroll
      for (int rr = 0; rr < 4; rr++){
        int row = m0 + wm*32 + i*16 + kg*4 + rr;
        QB[(size_t)row*128 + col] = f2bf(acc[i][j][rr] + bv);
      }
    }
  }
}

// ---------------- GEMM (N=128) + residual + LayerNorm fused ----------------
__global__ __launch_bounds__(512) void k_gemmln(
    const u16* __restrict__ A, const u16* __restrict__ B,
    const float* __restrict__ bias, const float* __restrict__ resSrc,
    const float* __restrict__ peT, const float* __restrict__ vo,
    const float* __restrict__ g, const float* __restrict__ b,
    float* __restrict__ outF, u16* __restrict__ outB,
    const int* __restrict__ fov, const float* __restrict__ qe,
    int K, int KT, int mode)
{
  extern __shared__ u16 smem[];
  int tid = threadIdx.x, lane = tid & 63, w = tid >> 6;
  int wm = w & 3, wn = w >> 2, r15 = lane & 15, kg = lane >> 4;
  int m0 = blockIdx.x*128;
  v4f acc[2][4] = {};
  stage128(A, smem + 0,     m0, K, 0);
  stage128(B, smem + 16384, 0,  K, 0);
  __syncthreads();
  for (int kt = 0; kt < KT; kt++){
    int bb = kt & 1;
    if (kt + 1 < KT){
      int b2 = bb ^ 1;
      stage128(A, smem + b2*32768,         m0, K, (kt+1)*128);
      stage128(B, smem + b2*32768 + 16384, 0,  K, (kt+1)*128);
    }
    compute128(smem + bb*32768, smem + bb*32768 + 16384, wm, wn, r15, kg, acc);
    __syncthreads();
  }
  float* lnbuf = (float*)smem;   // [128][132]
  float vo0 = 0.f, vo1 = 0.f, vo2 = 0.f;
  if (mode == 1){ vo0 = vo[0]; vo1 = vo[1]; vo2 = vo[2]; }
  #pragma unroll
  for (int i = 0; i < 2; i++){
    #pragma unroll
    for (int j = 0; j < 4; j++){
      int col = wn*64 + j*16 + r15;
      float bv = bias[col];
      float p0 = 0, p1 = 0, p2 = 0;
      if (mode == 1){ p0 = peT[col]; p1 = peT[128+col]; p2 = peT[256+col]; }
      #pragma unroll
      for (int rr = 0; rr < 4; rr++){
        int row = wm*32 + i*16 + kg*4 + rr;
        int q = m0 + row;
        size_t oi = (size_t)q*128 + col;
        float x = acc[i][j][rr] + bv;
        if (mode == 1){
          float px = ((float)(q >> 9)      + 0.5f)*0.8f + vo0;
          float py = ((float)((q >> 3)&63) + 0.5f)*0.8f + vo1;
          float pz = ((float)(q & 7)       + 0.5f)*0.8f + vo2;
          x += resSrc[oi] + p0*px + p1*py + p2*pz;
        } else {
          x += resSrc[oi];
        }
        lnbuf[row*132 + col] = x;
      }
    }
  }
  __syncthreads();
  int r = w*16 + (lane >> 2), j4 = lane & 3;
  const float* rowp = lnbuf + r*132;
  float s = 0.f;
  #pragma unroll
  for (int k = 0; k < 32; k++) s += rowp[j4 + 4*k];
  s += __shfl_xor(s, 1, 64); s += __shfl_xor(s, 2, 64);
  float mean = s * (1.0f/128.0f);
  float vv = 0.f;
  #pragma unroll
  for (int k = 0; k < 32; k++){ float d = rowp[j4 + 4*k] - mean; vv += d*d; }
  vv += __shfl_xor(vv, 1, 64); vv += __shfl_xor(vv, 2, 64);
  float rs = rsqrtf(vv*(1.0f/128.0f) + 1e-5f);
  int gq = m0 + r;
  #pragma unroll
  for (int k = 0; k < 32; k++){
    int c = j4 + 4*k;
    float o = (rowp[c] - mean)*rs*g[c] + b[c];
    size_t oi = (size_t)gq*128 + c;
    if (fov){
      outB[oi] = f2bf(fov[gq] ? o : qe[oi]);
    } else {
      if (outF) outF[oi] = o;
      if (outB) outB[oi] = f2bf(o);
    }
  }
}

// ---------------- dilated 3x3x3 conv v4: 8 waves 2m x 2n x 2k, 64x64 tiles ----------------
__global__ __launch_bounds__(512) void k_conv4(
    const u16* __restrict__ X, const u16* __restrict__ W,
    const float* __restrict__ bias, const u16* __restrict__ zp,
    u16* __restrict__ Y, int dil)
{
  extern __shared__ u16 smem[];
  u16* bufA0 = smem;            // 32 KB
  u16* bufA1 = smem + 16384;    // 32 KB
  u16* bufW0 = smem + 32768;
  u16* bufW1 = smem + 49152;
  int tid = threadIdx.x, lane = tid & 63, w = tid >> 6;
  int wk = w & 1, wm = (w >> 1) & 1, wn = (w >> 2) & 1;
  int r15 = lane & 15, kg = lane >> 4;
  int bid = blockIdx.x;
  int lb = (bid & 7)*32 + (bid >> 3);     // XCD-chunked swizzle (256 = 8*32)
  int m0 = lb*128;
  v4f acc[4][4] = {};
  const v8s vzero = {0,0,0,0,0,0,0,0};
  stageConvA4(X, zp, bufA0, m0, -dil, -dil);
  stage128(W, bufW0, 0, 128, 0);
  for (int g = 0; g < 9; g++){
    const u16* As = (g & 1) ? bufA1 : bufA0;
    #pragma unroll
    for (int dzi = 0; dzi < 3; dzi++){
      int t = g*3 + dzi;
      const u16* Ws = (t & 1) ? bufW1 : bufW0;
      if (t + 1 < 27)
        stage128(W + (size_t)(t+1)*16384, ((t+1)&1) ? bufW1 : bufW0, 0, 128, 0);
      if (dzi == 0 && g < 8){
        int gn = g + 1;
        stageConvA4(X, zp, (gn & 1) ? bufA1 : bufA0, m0, (gn/3 - 1)*dil, (gn%3 - 1)*dil);
      }
      if (dzi == 0){
        if (g < 8) asm volatile("s_waitcnt vmcnt(8)" ::: "memory");
        else       asm volatile("s_waitcnt vmcnt(4)" ::: "memory");
      } else {
        if (t < 26) asm volatile("s_waitcnt vmcnt(4)" ::: "memory");
        else        asm volatile("s_waitcnt vmcnt(0)" ::: "memory");
      }
      __builtin_amdgcn_s_barrier();
      asm volatile("" ::: "memory");
      int zofs = (dzi - 1)*dil;
      bool okz = (unsigned)((r15 & 7) + zofs) < 8u;
      #pragma unroll
      for (int k0 = 0; k0 < 2; k0++){
        int cb = wk*128 + k0*64 + kg*16;
        v8s a[4], b[4];
        #pragma unroll
        for (int q = 0; q < 4; q++){
          int ra = wm*64 + q*16 + r15 + zofs;
          int rc = min(max(ra, 0), 127);
          a[q] = okz ? fragld(As, rc, cb) : vzero;
          b[q] = fragld(Ws, wn*64 + q*16 + r15, cb);
        }
        #pragma unroll
        for (int i = 0; i < 4; i++)
          #pragma unroll
          for (int j = 0; j < 4; j++)
            acc[i][j] = __builtin_amdgcn_mfma_f32_16x16x32_bf16(a[i], b[j], acc[i][j], 0, 0, 0);
      }
      asm volatile("" ::: "memory");
      __builtin_amdgcn_s_barrier();
      asm volatile("" ::: "memory");
    }
  }
  // ---- k-split reduction through LDS (reuses A buffers: 64 KB f32 [128][128]) ----
  float* red = (float*)smem;
  if (wk == 0){
    #pragma unroll
    for (int i = 0; i < 4; i++)
      #pragma unroll
      for (int j = 0; j < 4; j++)
        #pragma unroll
        for (int rr = 0; rr < 4; rr++)
          red[(wm*64 + i*16 + kg*4 + rr)*128 + wn*64 + j*16 + r15] = acc[i][j][rr];
  }
  __syncthreads();
  if (wk == 1){
    #pragma unroll
    for (int i = 0; i < 4; i++){
      #pragma unroll
      for (int j = 0; j < 4; j++){
        int col = wn*64 + j*16 + r15;
        float bv = bias[col];
        #pragma unroll
        for (int rr = 0; rr < 4; rr++){
          int row = wm*64 + i*16 + kg*4 + rr;
          int grow = m0 + row;
          float v = acc[i][j][rr] + red[row*128 + col] + bv + bf2f(X[(size_t)grow*128 + col]);
          v = fmaxf(v, 0.0f);
          Y[(size_t)grow*128 + col] = f2bf(v);
        }
      }
    }
  }
}

// ---------------- MFMA cross-attention ----------------
__global__ __launch_bounds__(256) void k_attn2(
    const u16* __restrict__ QB, const u16* __restrict__ KH, const u16* __restrict__ VT,
    const float* __restrict__ biasArr, u16* __restrict__ O)
{
  __shared__ float sb[128];
  __shared__ u16 sp[4][32*128];
  int tid = threadIdx.x, lane = tid & 63, w = tid >> 6;
  if (tid < 128) sb[tid] = biasArr[tid];
  __syncthreads();
  int c = lane & 15, r = lane >> 4;
  int q0 = blockIdx.x * 64;
  const u16* Kh = KH + (size_t)w*128*32;
  const u16* Vh = VT + (size_t)w*32*128;
  char* spw = (char*)&sp[w][0];

  v8s kf[8];
  #pragma unroll
  for (int kt = 0; kt < 8; kt++) kf[kt] = *(const v8s*)(Kh + (kt*16 + c)*32 + r*8);
  v8s vf[4][2];
  #pragma unroll
  for (int ks = 0; ks < 4; ks++)
    #pragma unroll
    for (int dt = 0; dt < 2; dt++)
      vf[ks][dt] = *(const v8s*)(Vh + (dt*16 + c)*128 + ks*32 + r*8);
  float bv[8][4];
  #pragma unroll
  for (int kt = 0; kt < 8; kt++){
    float4 t = *(const float4*)&sb[kt*16 + r*4];
    bv[kt][0] = t.x; bv[kt][1] = t.y; bv[kt][2] = t.z; bv[kt][3] = t.w;
  }

  #pragma unroll
  for (int half = 0; half < 2; half++){
    v4f s[2][8] = {};
    #pragma unroll
    for (int qt2 = 0; qt2 < 2; qt2++){
      int qt = half*2 + qt2;
      v8s qf = *(const v8s*)(QB + (size_t)(q0 + qt*16 + c)*128 + w*32 + r*8);
      #pragma unroll
      for (int kt = 0; kt < 8; kt++)
        s[qt2][kt] = __builtin_amdgcn_mfma_f32_16x16x32_bf16(kf[kt], qf, s[qt2][kt], 0, 0, 0);
    }
    #pragma unroll
    for (int qt2 = 0; qt2 < 2; qt2++){
      float mx = -1e30f;
      #pragma unroll
      for (int kt = 0; kt < 8; kt++)
        #pragma unroll
        for (int rg = 0; rg < 4; rg++){
          s[qt2][kt][rg] += bv[kt][rg];
          mx = fmaxf(mx, s[qt2][kt][rg]);
        }
      mx = fmaxf(mx, __shfl_xor(mx, 16, 64));
      mx = fmaxf(mx, __shfl_xor(mx, 32, 64));
      float sum = 0.f;
      #pragma unroll
      for (int kt = 0; kt < 8; kt++)
        #pragma unroll
        for (int rg = 0; rg < 4; rg++){
          float p = __expf(s[qt2][kt][rg] - mx);
          s[qt2][kt][rg] = p;
          sum += p;
        }
      sum += __shfl_xor(sum, 16, 64);
      sum += __shfl_xor(sum, 32, 64);
      float inv = 1.0f / sum;
      int row = qt2*16 + c;
      int rbyte = row*256;
      int rxx = (row & 7) << 4;
      #pragma unroll
      for (int kt = 0; kt < 8; kt++){
        #pragma unroll
        for (int pr = 0; pr < 2; pr++){
          u32 pk = (u32)f2bf(s[qt2][kt][pr*2]*inv) | ((u32)f2bf(s[qt2][kt][pr*2+1]*inv) << 16);
          int colb = kt*32 + r*8 + pr*4;
          *(u32*)(spw + rbyte + (colb ^ rxx)) = pk;
        }
      }
    }
    v4f o[2][2] = {};
    #pragma unroll
    for (int ks = 0; ks < 4; ks++){
      #pragma unroll
      for (int qt2 = 0; qt2 < 2; qt2++){
        int row = qt2*16 + c;
        int colb = ks*64 + r*16;
        v8s aP = *(const v8s*)(spw + row*256 + (colb ^ ((row & 7) << 4)));
        o[qt2][0] = __builtin_amdgcn_mfma_f32_16x16x32_bf16(aP, vf[ks][0], o[qt2][0], 0, 0, 0);
        o[qt2][1] = __builtin_amdgcn_mfma_f32_16x16x32_bf16(aP, vf[ks][1], o[qt2][1], 0, 0, 0);
      }
    }
    #pragma unroll
    for (int qt2 = 0; qt2 < 2; qt2++){
      #pragma unroll
      for (int dt = 0; dt < 2; dt++){
        #pragma unroll
        for (int rg = 0; rg < 4; rg++){
          int qq = q0 + (half*2 + qt2)*16 + r*4 + rg;
          O[(size_t)qq*128 + w*32 + dt*16 + c] = f2bf(o[qt2][dt][rg]);
        }
      }
    }
  }
}

// ---------------- 1x1x1 head conv -> d_out [20][32768] ----------------
__global__ __launch_bounds__(256) void k_outconv(const u16* __restrict__ X,
    const float* __restrict__ W, const float* __restrict__ B, float* __restrict__ out)
{
  __shared__ float sw[20*128];
  __shared__ float sbb[20];
  int tid = threadIdx.x;
  for (int i = tid; i < 20*128; i += 256) sw[i] = W[i];
  if (tid < 20) sbb[tid] = B[tid];
  __syncthreads();
  int s = blockIdx.x*256 + tid;
  u32 rv[64];
  const u32* xp = (const u32*)(X + (size_t)s*128);
  #pragma unroll
  for (int j = 0; j < 64; j++) rv[j] = xp[j];
  for (int ot = 0; ot < 20; ot++){
    float acc = sbb[ot];
    #pragma unroll
    for (int j = 0; j < 64; j++){
      u32 u = rv[j];
      acc += bf2f((u16)(u & 0xffff))*sw[ot*128 + 2*j] + bf2f((u16)(u >> 16))*sw[ot*128 + 2*j + 1];
    }
    out[(size_t)ot*NQv + s] = acc;
  }
}

extern "C" void kernel_launch(void* const* d_in, const int* in_sizes, int n_in,
                              void* d_out, int out_size, void* d_ws, size_t ws_size,
                              hipStream_t stream)
{
  const float* iq    = (const float*)d_in[0];
  const float* logits= (const float*)d_in[1];
  const float* pmL   = (const float*)d_in[2];
  const float* depth = (const float*)d_in[3];
  const float* Km    = (const float*)d_in[4];
  const float* Em    = (const float*)d_in[5];
  const float* vo    = (const float*)d_in[6];
  const float* qe    = (const float*)d_in[7];
  const float* pe    = (const float*)d_in[8];
  const float* ain_w = (const float*)d_in[9];
  const float* ain_b = (const float*)d_in[10];
  const float* aout_w= (const float*)d_in[11];
  const float* aout_b= (const float*)d_in[12];
  const float* ln1g  = (const float*)d_in[13];
  const float* ln1b  = (const float*)d_in[14];
  const float* w1    = (const float*)d_in[15];
  const float* b1    = (const float*)d_in[16];
  const float* w2    = (const float*)d_in[17];
  const float* b2    = (const float*)d_in[18];
  const float* ln2g  = (const float*)d_in[19];
  const float* ln2b  = (const float*)d_in[20];
  const float* pw    = (const float*)d_in[21];
  const float* pb    = (const float*)d_in[22];
  const float* ow    = (const float*)d_in[23];
  const float* ob    = (const float*)d_in[24];
  const int*   fov   = (const int*)d_in[25];
  float* out = (float*)d_out;

  (void)hipFuncSetAttribute((const void*)k_gemm2,  hipFuncAttributeMaxDynamicSharedMemorySize, 131072);
  (void)hipFuncSetAttribute((const void*)k_gemmln, hipFuncAttributeMaxDynamicSharedMemorySize, 131072);
  (void)hipFuncSetAttribute((const void*)k_conv4,  hipFuncAttributeMaxDynamicSharedMemorySize, 131072);
  (void)hipFuncSetAttribute((const void*)k_qproj,  hipFuncAttributeMaxDynamicSharedMemorySize, 65536);

  char* ws = (char*)d_ws;
  size_t off = 0;
  auto alloc = [&](size_t bytes) -> char* {
    char* p = ws + off;
    off = (off + bytes + 255) & ~(size_t)255;
    return p;
  };
  float* mats    = (float*)alloc(32*4);
  float* scores  = (float*)alloc(128*4);
  int*   keep0   = (int*)  alloc(128*4);
  int*   keep    = (int*)  alloc(128*4);
  float* biasArr = (float*)alloc(128*4);
  float* xyz     = (float*)alloc(512*4);
  u16*   zp      = (u16*)  alloc(256);
  float* peT     = (float*)alloc(384*4);
  int*   mids    = (int*)  alloc((size_t)HWp*4);
  float* kvkb    = (float*)alloc((size_t)NI*128*4);
  u16* khs_bf  = (u16*)alloc((size_t)3*4*128*32*2);
  u16* vt_bf   = (u16*)alloc((size_t)3*4*32*128*2);
  u16* ain_bf  = (u16*)alloc((size_t)3*384*128*2);
  u16* aout_bf = (u16*)alloc((size_t)3*128*128*2);
  u16* w1_bf   = (u16*)alloc((size_t)3*512*128*2);
  u16* w2_bf   = (u16*)alloc((size_t)3*128*512*2);
  u16* wc_bf   = (u16*)alloc((size_t)3*27*128*128*2);
  float* T1 = (float*)alloc((size_t)NQv*128*4);
  float* T2 = (float*)alloc((size_t)NQv*128*4);
  u16*  XB = (u16*) alloc((size_t)NQv*128*2);
  u16*  HB = (u16*) alloc((size_t)NQv*512*2);
  u16* QB  = HB;           // q-projection (HB free until FFN1)
  u16* x3a = XB;           // conv ping
  u16* x3b = HB;           // conv pong
  (void)ws_size; (void)in_sizes; (void)n_in; (void)out_size;

  // ---- prep ----
  k_prep_small<<<1,128,0,stream>>>(Km, Em, logits, mats, scores, keep0);
  {
    int n0 = 3*384*128, n1 = 3*128*128, n2 = 3*512*128, n3 = 3*128*512;
    int zn0 = 3*4*128*32, zn1 = 3*4*32*128, zn2 = 128;
    int total = n0+n1+n2+n3+zn0+zn1+zn2+384;
    k_prep_multi<<<(total+255)/256,256,0,stream>>>(
        ain_w, ain_bf, n0, aout_w, aout_bf, n1, w1, w1_bf, n2, w2, w2_bf, n3,
        khs_bf, zn0, vt_bf, zn1, zp, zn2, pe, peT);
  }
  k_packconv2<<<dim3(128,3),256,0,stream>>>(pw, wc_bf);
  k_mask_argmax2<<<120,256,0,stream>>>(pmL, scores, keep0, mids);
  k_instbp<<<NI,256,0,stream>>>(pmL, mids, keep0, depth, mats, keep, xyz);
  k_kvk<<<(NI*128+255)/256,256,0,stream>>>(iq, pe, xyz, keep, kvkb);
  { dim3 g(3,4); k_khvh2<<<g,512,0,stream>>>(kvkb, iq, ain_w, ain_b, keep, biasArr, khs_bf, vt_bf); }

  // ---- 3 transformer layers ----
  for (int li = 0; li < 3; li++){
    const float* src = (li == 0) ? qe : T2;
    k_qproj<<<256,512,65536,stream>>>(src, peT, vo, ain_bf + (size_t)li*384*128,
                                      ain_b + li*384, QB);
    k_attn2<<<512,256,0,stream>>>(QB, khs_bf + (size_t)li*4*128*32,
                                  vt_bf + (size_t)li*4*32*128, biasArr, XB);
    k_gemmln<<<256,512,69632,stream>>>(XB, aout_bf + (size_t)li*128*128, aout_b + li*128,
                                       src, peT, vo, ln1g + li*128, ln1b + li*128,
                                       T1, XB, nullptr, nullptr, 128, 1, 1);
    k_gemm2<<<dim3(256,4),512,65536,stream>>>(XB, w1_bf + (size_t)li*512*128, b1 + li*512,
                                              nullptr, nullptr, HB, 512, 128, 1, 1);
    if (li < 2){
      k_gemmln<<<256,512,131072,stream>>>(HB, w2_bf + (size_t)li*128*512, b2 + li*128,
                                          T1, nullptr, nullptr, ln2g + li*128, ln2b + li*128,
                                          T2, nullptr, nullptr, nullptr, 512, 4, 0);
    } else {
      k_gemmln<<<256,512,131072,stream>>>(HB, w2_bf + (size_t)li*128*512, b2 + li*128,
                                          T1, nullptr, nullptr, ln2g + li*128, ln2b + li*128,
                                          nullptr, x3a, fov, qe, 512, 4, 0);
    }
  }

  // ---- conv stack ----
  k_conv4<<<256,512,131072,stream>>>(x3a, wc_bf + (size_t)0*27*16384, pb + 0,   zp, x3b, 1);
  k_conv4<<<256,512,131072,stream>>>(x3b, wc_bf + (size_t)1*27*16384, pb + 128, zp, x3a, 2);
  k_conv4<<<256,512,131072,stream>>>(x3a, wc_bf + (size_t)2*27*16384, pb + 256, zp, x3b, 3);
  k_outconv<<<128,256,0,stream>>>(x3b, ow, ob, out);
}

// Round 8
// 361.410 us; speedup vs baseline: 3.9775x; 1.3449x over previous
//
#include <hip/hip_runtime.h>
#include <math.h>

typedef unsigned short u16;
typedef unsigned int   u32;

#define NQv 32768
#define HWp 7680
#define NI  100

typedef short v8s __attribute__((ext_vector_type(8)));
typedef float v4f __attribute__((ext_vector_type(4)));

__device__ inline float bf2f(u16 u){ u32 x = ((u32)u) << 16; return __uint_as_float(x); }
__device__ inline u16 f2bf(float f){
  u32 x = __float_as_uint(f);
  u32 r = (x + 0x7fffu + ((x >> 16) & 1u)) >> 16;
  return (u16)r;
}
__device__ inline float sigf(float x){ return 1.0f / (1.0f + expf(-x)); }

typedef const __attribute__((address_space(1))) void* gas_t;
typedef __attribute__((address_space(3))) void* las_t;

// ---------------- small prep ----------------
__global__ void k_prep_small(const float* __restrict__ Km, const float* __restrict__ Em,
                             const float* __restrict__ logits,
                             float* __restrict__ mats, float* __restrict__ scores,
                             int* __restrict__ keep0)
{
  int tid = threadIdx.x;
  if (tid == 0) {
    double a[9];
    for (int i = 0; i < 9; i++) a[i] = (double)Km[i];
    double det = a[0]*(a[4]*a[8]-a[5]*a[7]) - a[1]*(a[3]*a[8]-a[5]*a[6]) + a[2]*(a[3]*a[7]-a[4]*a[6]);
    double id = 1.0 / det;
    double inv[9];
    inv[0]=(a[4]*a[8]-a[5]*a[7])*id; inv[1]=(a[2]*a[7]-a[1]*a[8])*id; inv[2]=(a[1]*a[5]-a[2]*a[4])*id;
    inv[3]=(a[5]*a[6]-a[3]*a[8])*id; inv[4]=(a[0]*a[8]-a[2]*a[6])*id; inv[5]=(a[2]*a[3]-a[0]*a[5])*id;
    inv[6]=(a[3]*a[7]-a[4]*a[6])*id; inv[7]=(a[1]*a[6]-a[0]*a[7])*id; inv[8]=(a[0]*a[4]-a[1]*a[3])*id;
    for (int i = 0; i < 9; i++) mats[i] = (float)inv[i];
    double m[4][8];
    for (int r = 0; r < 4; r++){
      for (int c = 0; c < 4; c++){ m[r][c] = (double)Em[r*4+c]; m[r][4+c] = (r==c) ? 1.0 : 0.0; }
    }
    for (int col = 0; col < 4; col++){
      int piv = col; double best = fabs(m[col][col]);
      for (int r = col+1; r < 4; r++){ double v = fabs(m[r][col]); if (v > best){ best = v; piv = r; } }
      if (piv != col){ for (int c = 0; c < 8; c++){ double t = m[col][c]; m[col][c] = m[piv][c]; m[piv][c] = t; } }
      double p = m[col][col];
      for (int c = 0; c < 8; c++) m[col][c] /= p;
      for (int r = 0; r < 4; r++) if (r != col){ double f = m[r][col]; for (int c = 0; c < 8; c++) m[r][c] -= f*m[col][c]; }
    }
    for (int r = 0; r < 3; r++) for (int c = 0; c < 4; c++) mats[9 + r*4 + c] = (float)m[r][4+c];
  }
  if (tid < NI) {
    float mx = -1e30f;
    for (int c = 0; c < 21; c++){ float t = sigf(logits[tid*21+c]) / 0.06f; mx = fmaxf(mx, t); }
    float s = 0.f;
    for (int c = 0; c < 21; c++){ float t = sigf(logits[tid*21+c]) / 0.06f; s += expf(t - mx); }
    float sc = 1.0f / s;
    scores[tid] = sc;
    keep0[tid] = (sc > 0.25f) ? 1 : 0;
  }
}

__global__ void k_prep_multi(
    const float* __restrict__ s0, u16* __restrict__ d0, int n0,
    const float* __restrict__ s1, u16* __restrict__ d1, int n1,
    const float* __restrict__ s2, u16* __restrict__ d2, int n2,
    const float* __restrict__ s3, u16* __restrict__ d3, int n3,
    u16* __restrict__ z0, int zn0, u16* __restrict__ z1, int zn1,
    u16* __restrict__ z2, int zn2,
    const float* __restrict__ pe, float* __restrict__ peT)
{
  int i = blockIdx.x*256 + threadIdx.x;
  if (i < n0){ d0[i] = f2bf(s0[i]); return; } i -= n0;
  if (i < n1){ d1[i] = f2bf(s1[i]); return; } i -= n1;
  if (i < n2){ d2[i] = f2bf(s2[i]); return; } i -= n2;
  if (i < n3){ d3[i] = f2bf(s3[i]); return; } i -= n3;
  if (i < zn0){ z0[i] = 0; return; } i -= zn0;
  if (i < zn1){ z1[i] = 0; return; } i -= zn1;
  if (i < zn2){ z2[i] = 0; return; } i -= zn2;
  if (i < 384){ int d = i >> 7, c = i & 127; peT[i] = pe[c*3 + d]; }
}

__global__ __launch_bounds__(256) void k_mask_argmax2(
    const float* __restrict__ pmL, const float* __restrict__ scores,
    const int* __restrict__ keep0, int* __restrict__ mids)
{
  __shared__ float sv[4][64];
  __shared__ int   si[4][64];
  int tid = threadIdx.x, lane = tid & 63, w = tid >> 6;
  int p = blockIdx.x*64 + lane;
  float best = -2e30f; int bid = 0;
  #pragma unroll 5
  for (int jj = 0; jj < 25; jj++){
    int i = w*25 + jj;
    float lg = pmL[i*HWp + p];
    float val = keep0[i] ? scores[i] * sigf(lg) : -1.0f;
    if (val > best){ best = val; bid = i; }
  }
  sv[w][lane] = best; si[w][lane] = bid;
  __syncthreads();
  if (w == 0){
    float b0 = sv[0][lane]; int i0 = si[0][lane];
    #pragma unroll
    for (int g = 1; g < 4; g++){
      float bg = sv[g][lane]; int ig = si[g][lane];
      if (bg > b0 || (bg == b0 && ig < i0)){ b0 = bg; i0 = ig; }
    }
    mids[p] = i0;
  }
}

__global__ __launch_bounds__(256) void k_instbp(
    const float* __restrict__ pmL, const int* __restrict__ mids,
    const int* __restrict__ keep0, const float* __restrict__ depth,
    const float* __restrict__ mats, int* __restrict__ keep, float* __restrict__ xyz)
{
  int i = blockIdx.x, tid = threadIdx.x;
  int k0 = keep0[i];
  int ma = 0, pa = 0, it = 0;
  for (int p = tid; p < HWp; p += 256){
    float lg = pmL[i*HWp + p];
    int pb = (lg >= 0.0f) ? 1 : 0;
    int mi = (mids[p] == i && k0) ? 1 : 0;
    ma += mi; pa += pb; it += (mi & pb);
  }
  __shared__ int sma[256], spa[256], sit[256];
  __shared__ int s_keep;
  sma[tid] = ma; spa[tid] = pa; sit[tid] = it;
  __syncthreads();
  for (int off = 128; off; off >>= 1){
    if (tid < off){ sma[tid]+=sma[tid+off]; spa[tid]+=spa[tid+off]; sit[tid]+=sit[tid+off]; }
    __syncthreads();
  }
  if (tid == 0){
    int kk = (k0 && sit[0] > 0 && ((float)sma[0] >= 0.8f*(float)spa[0])) ? 1 : 0;
    keep[i] = kk; s_keep = kk;
  }
  __syncthreads();
  float sx = 0.f, sy = 0.f, sz = 0.f;
  if (s_keep){
    float ik0=mats[0],ik1=mats[1],ik2=mats[2],ik3=mats[3],ik4=mats[4],ik5=mats[5],ik6=mats[6],ik7=mats[7],ik8=mats[8];
    const float* iE = mats + 9;
    for (int p = tid; p < HWp; p += 256){
      if (mids[p] == i && pmL[i*HWp + p] >= 0.0f){
        int r = p / 160, c = p % 160;
        float xg = (float)((double)c * (1279.0/159.0));
        float yg = (float)((double)r * (383.0/47.0));
        float d = depth[p];
        float g0 = xg*d, g1 = yg*d, g2 = d;
        float c0 = ik0*g0 + ik1*g1 + ik2*g2;
        float c1 = ik3*g0 + ik4*g1 + ik5*g2;
        float c2 = ik6*g0 + ik7*g1 + ik8*g2;
        sx += iE[0]*c0 + iE[1]*c1 + iE[2]*c2 + iE[3];
        sy += iE[4]*c0 + iE[5]*c1 + iE[6]*c2 + iE[7];
        sz += iE[8]*c0 + iE[9]*c1 + iE[10]*c2 + iE[11];
      }
    }
  }
  __shared__ float rx[256], ry[256], rz[256];
  rx[tid]=sx; ry[tid]=sy; rz[tid]=sz;
  __syncthreads();
  for (int off = 128; off; off >>= 1){
    if (tid < off){ rx[tid]+=rx[tid+off]; ry[tid]+=ry[tid+off]; rz[tid]+=rz[tid+off]; }
    __syncthreads();
  }
  if (tid == 0){ xyz[i*3+0]=rx[0]; xyz[i*3+1]=ry[0]; xyz[i*3+2]=rz[0]; }
}

__global__ void k_kvk(const float* __restrict__ iq, const float* __restrict__ pe,
                      const float* __restrict__ xyz, const int* __restrict__ keep,
                      float* __restrict__ kvk)
{
  int tid = threadIdx.x;
  unsigned long long b = __ballot(tid < 100 && keep[tid] != 0);
  __shared__ int s_w[4];
  if ((tid & 63) == 0) s_w[tid >> 6] = (b != 0ULL);
  __syncthreads();
  float u = (s_w[0] | s_w[1]) ? 1.0f : 0.0f;
  int idx = blockIdx.x*256 + tid;
  if (idx >= NI*128) return;
  int i = idx >> 7, c = idx & 127;
  float ip = pe[c*3+0]*xyz[i*3+0] + pe[c*3+1]*xyz[i*3+1] + pe[c*3+2]*xyz[i*3+2];
  kvk[idx] = iq[idx] + u * ip;
}

__global__ __launch_bounds__(512) void k_khvh2(const float* __restrict__ kvk,
    const float* __restrict__ iq, const float* __restrict__ Win,
    const float* __restrict__ bin, const int* __restrict__ keep,
    float* __restrict__ biasArr, u16* __restrict__ khs_bf, u16* __restrict__ vt_bf)
{
  __shared__ u16 s_in[NI][130];
  __shared__ u16 s_w[64][130];
  __shared__ int s_any[8];
  int li = blockIdx.x, c0 = blockIdx.y*64;
  bool isK = (c0 < 128);
  const float* srcIn = isK ? kvk : iq;
  int tid = threadIdx.x;
  unsigned long long bm = __ballot(tid < 100 && keep[tid] != 0);
  if ((tid & 63) == 0) s_any[tid >> 6] = (bm != 0ULL);
  for (int i = tid; i < NI*128; i += 512) s_in[i>>7][i&127] = f2bf(srcIn[i]);
  const float* wbase = Win + ((size_t)li*384 + 128 + c0)*128;
  for (int i = tid; i < 64*128; i += 512) s_w[i>>7][i&127] = f2bf(wbase[i]);
  __syncthreads();
  if (li == 0 && c0 == 0 && tid < 128){
    int any = s_any[0] | s_any[1];
    float bb;
    if (tid < NI) bb = any ? (keep[tid] ? 0.0f : -1e9f) : 0.0f;
    else bb = -1e9f;
    biasArr[tid] = bb;
  }
  for (int o = tid; o < NI*64; o += 512){
    int k = o >> 6, c = o & 63;
    float acc = 0.f;
    #pragma unroll 8
    for (int j = 0; j < 128; j++) acc += bf2f(s_in[k][j]) * bf2f(s_w[c][j]);
    int cc = c0 + c;
    float v = acc + bin[li*384 + 128 + cc];
    int ch = cc & 127;
    if (isK) khs_bf[(((size_t)li*4 + (ch>>5))*128 + k)*32 + (ch&31)] = f2bf(v * 0.17677669529663687f);
    else     vt_bf [(((size_t)li*4 + (ch>>5))*32 + (ch&31))*128 + k] = f2bf(v);
  }
}

__global__ __launch_bounds__(256) void k_packconv2(const float* __restrict__ w, u16* __restrict__ wp)
{
  __shared__ u16 s[3456];
  int o = blockIdx.x, li = blockIdx.y;
  const float* src = w + ((size_t)li*128 + o)*3456;
  for (int t = threadIdx.x; t < 3456; t += 256) s[t] = f2bf(src[t]);
  __syncthreads();
  for (int e = threadIdx.x; e < 3456; e += 256){
    int t = e >> 7, i = e & 127;
    wp[(((size_t)li*27 + t)*128 + o)*128 + i] = s[i*27 + t];
  }
}

// ================= tiled MFMA infrastructure =================
__device__ inline void stage128(const u16* __restrict__ G, u16* lds,
                                int rbase, int pitchK, int kofs)
{
  int lane = threadIdx.x & 63, w = threadIdx.x >> 6;
  #pragma unroll
  for (int s = 0; s < 4; s++){
    int ldsOff = s*8192 + w*1024 + lane*16;   // bytes
    int row = ldsOff >> 8;
    int cb  = ldsOff & 255;
    int scb = cb ^ ((row & 7) << 4);
    const u16* src = G + (size_t)(rbase + row)*pitchK + kofs + (scb >> 1);
    u16* dst = lds + (s*4096 + w*512);
    __builtin_amdgcn_global_load_lds((gas_t)src, (las_t)dst, 16, 0, 0);
  }
}

// linear 32 KB copy (16 B/thread x 4 rounds), 512 threads
__device__ inline void copy32k(const u16* __restrict__ G, u16* lds)
{
  int lane = threadIdx.x & 63, w = threadIdx.x >> 6;
  #pragma unroll
  for (int s = 0; s < 4; s++){
    int off = s*4096 + w*512;   // u16 units, wave base
    const u16* src = G + off + lane*8;
    __builtin_amdgcn_global_load_lds((gas_t)src, (las_t)(lds + off), 16, 0, 0);
  }
}

__device__ inline void stageConvA4(const u16* __restrict__ X, const u16* __restrict__ zp,
                                   u16* lds, int m0, int dx, int dy)
{
  int lane = threadIdx.x & 63, w = threadIdx.x >> 6;
  #pragma unroll
  for (int s = 0; s < 4; s++){
    int ldsOff = s*8192 + w*1024 + lane*16;
    int row = ldsOff >> 8;
    int cb  = ldsOff & 255;
    int scb = cb ^ ((row & 7) << 4);
    int sidx = m0 + row;
    int xs = (sidx >> 9) + dx, ys = ((sidx >> 3) & 63) + dy, zs = sidx & 7;
    bool ok = ((unsigned)xs < 64u) & ((unsigned)ys < 64u);
    const u16* src = ok ? (X + (size_t)((xs*64+ys)*8+zs)*128 + (scb>>1)) : (zp + (scb>>1));
    u16* dst = lds + (s*4096 + w*512);
    __builtin_amdgcn_global_load_lds((gas_t)src, (las_t)dst, 16, 0, 0);
  }
}

__device__ inline v8s fragld(const u16* base, int row, int cb){
  return *(const v8s*)(base + row*128 + (((cb) ^ ((row & 7) << 4)) >> 1));
}

__device__ inline void compute128(const u16* As, const u16* Bs,
                                  int wm, int wn, int r15, int kg, v4f acc[2][4])
{
  #pragma unroll
  for (int k0 = 0; k0 < 4; k0++){
    int cb = k0*64 + kg*16;
    v8s a0 = fragld(As, wm*32 +      r15, cb);
    v8s a1 = fragld(As, wm*32 + 16 + r15, cb);
    v8s b0 = fragld(Bs, wn*64 +      r15, cb);
    v8s b1 = fragld(Bs, wn*64 + 16 + r15, cb);
    v8s b2 = fragld(Bs, wn*64 + 32 + r15, cb);
    v8s b3 = fragld(Bs, wn*64 + 48 + r15, cb);
    acc[0][0] = __builtin_amdgcn_mfma_f32_16x16x32_bf16(a0, b0, acc[0][0], 0, 0, 0);
    acc[0][1] = __builtin_amdgcn_mfma_f32_16x16x32_bf16(a0, b1, acc[0][1], 0, 0, 0);
    acc[0][2] = __builtin_amdgcn_mfma_f32_16x16x32_bf16(a0, b2, acc[0][2], 0, 0, 0);
    acc[0][3] = __builtin_amdgcn_mfma_f32_16x16x32_bf16(a0, b3, acc[0][3], 0, 0, 0);
    acc[1][0] = __builtin_amdgcn_mfma_f32_16x16x32_bf16(a1, b0, acc[1][0], 0, 0, 0);
    acc[1][1] = __builtin_amdgcn_mfma_f32_16x16x32_bf16(a1, b1, acc[1][1], 0, 0, 0);
    acc[1][2] = __builtin_amdgcn_mfma_f32_16x16x32_bf16(a1, b2, acc[1][2], 0, 0, 0);
    acc[1][3] = __builtin_amdgcn_mfma_f32_16x16x32_bf16(a1, b3, acc[1][3], 0, 0, 0);
  }
}

// ================== fused transformer layer ==================
// block = 128 queries, 512 threads, 160 KB LDS.
// LDS: SA[32K] SB[32K] X[32K bf16 swz] R[64K: KV early, f32 LN buf later]
__global__ __launch_bounds__(512) void k_layer(
    const void* __restrict__ srcv, int srcBf,
    const float* __restrict__ peT, const float* __restrict__ vo,
    const u16* __restrict__ ainQ, const float* __restrict__ ainQb,
    const u16* __restrict__ khs, const u16* __restrict__ vt,
    const float* __restrict__ biasArr,
    const u16* __restrict__ aoutw, const float* __restrict__ aoutb,
    const float* __restrict__ g1, const float* __restrict__ b1v,
    const u16* __restrict__ w1p, const float* __restrict__ b1p,
    const u16* __restrict__ w2p, const float* __restrict__ b2p,
    const float* __restrict__ g2, const float* __restrict__ b2v,
    u16* __restrict__ outB, const int* __restrict__ fov, const float* __restrict__ qe)
{
  extern __shared__ u16 smem[];
  u16* SA = smem;              // 16384 u16
  u16* SB = smem + 16384;
  u16* X  = smem + 32768;
  u16* Rh = smem + 49152;      // 32768 u16 = 64 KB
  char* Xc = (char*)X;
  char* Rc = (char*)Rh;
  int tid = threadIdx.x, lane = tid & 63, w = tid >> 6;
  int wm = w & 3, wn = w >> 2, r15 = lane & 15, kg = lane >> 4;
  int m0 = blockIdx.x * 128;

  // ---- P0: stage ainQ -> SA, KV -> R, build x -> X ----
  stage128(ainQ, SA, 0, 128, 0);
  copy32k(khs, Rh);
  copy32k(vt, Rh + 16384);
  {
    int r = tid >> 2, c0 = (tid & 3)*32;
    int q = m0 + r;
    float px = ((float)(q >> 9)       + 0.5f)*0.8f + vo[0];
    float py = ((float)((q >> 3)&63)  + 0.5f)*0.8f + vo[1];
    float pz = ((float)(q & 7)        + 0.5f)*0.8f + vo[2];
    char* arow = Xc + r*256;
    int rx = (r & 7) << 4;
    if (!srcBf){
      const float4* sp  = (const float4*)((const float*)srcv + (size_t)q*128 + c0);
      const float4* pex = (const float4*)(peT +   0 + c0);
      const float4* pey = (const float4*)(peT + 128 + c0);
      const float4* pez = (const float4*)(peT + 256 + c0);
      #pragma unroll
      for (int j = 0; j < 8; j++){
        float4 v = sp[j];
        float4 ax = pex[j], ay = pey[j], az = pez[j];
        float o0 = v.x + ax.x*px + ay.x*py + az.x*pz;
        float o1 = v.y + ax.y*px + ay.y*py + az.y*pz;
        float o2 = v.z + ax.z*px + ay.z*py + az.z*pz;
        float o3 = v.w + ax.w*px + ay.w*py + az.w*pz;
        int cbyte = (c0 + j*4)*2;
        *(u32*)(arow + ((cbyte    ) ^ rx)) = (u32)f2bf(o0) | ((u32)f2bf(o1) << 16);
        *(u32*)(arow + ((cbyte + 4) ^ rx)) = (u32)f2bf(o2) | ((u32)f2bf(o3) << 16);
      }
    } else {
      const u16* sp = (const u16*)srcv + (size_t)q*128 + c0;
      #pragma unroll
      for (int j = 0; j < 4; j++){
        v8s t = *(const v8s*)(sp + j*8);
        #pragma unroll
        for (int pr = 0; pr < 4; pr++){
          int c = c0 + j*8 + pr*2;
          float e0 = bf2f((u16)t[pr*2])   + peT[c]*px   + peT[128+c]*py   + peT[256+c]*pz;
          float e1 = bf2f((u16)t[pr*2+1]) + peT[c+1]*px + peT[128+c+1]*py + peT[256+c+1]*pz;
          *(u32*)(arow + ((c*2) ^ rx)) = (u32)f2bf(e0) | ((u32)f2bf(e1) << 16);
        }
      }
    }
  }
  __syncthreads();

  // ---- P1: Q-GEMM -> SB (bf16 swz) ----
  {
    v4f acc[2][4] = {};
    compute128(X, SA, wm, wn, r15, kg, acc);
    #pragma unroll
    for (int i = 0; i < 2; i++){
      #pragma unroll
      for (int j = 0; j < 4; j++){
        int col = wn*64 + j*16 + r15;
        float bv = ainQb[col];
        #pragma unroll
        for (int rr = 0; rr < 4; rr++){
          int row = wm*32 + i*16 + kg*4 + rr;
          *(u16*)((char*)SB + row*256 + (((col*2)) ^ ((row & 7) << 4))) = f2bf(acc[i][j][rr] + bv);
        }
      }
    }
  }
  __syncthreads();

  // ---- P2: attention: wave = 16 queries, heads sequential; P scratch in SA ----
  {
    int c = lane & 15, r4 = lane >> 4;
    char* pwc = (char*)(SA + w*2048);     // 4 KB wave-private
    int qrow_base = w*16;
    #pragma unroll
    for (int h = 0; h < 4; h++){
      const u16* Kh = Rh + h*4096;
      const u16* Vh = Rh + 16384 + h*4096;
      int qrow = qrow_base + c;
      v8s qf = *(const v8s*)((char*)SB + qrow*256 + ((h*64 + r4*16) ^ ((qrow & 7) << 4)));
      v4f s[8] = {{0,0,0,0},{0,0,0,0},{0,0,0,0},{0,0,0,0},{0,0,0,0},{0,0,0,0},{0,0,0,0},{0,0,0,0}};
      #pragma unroll
      for (int kt = 0; kt < 8; kt++){
        v8s kf = *(const v8s*)(Kh + (kt*16 + c)*32 + r4*8);
        s[kt] = __builtin_amdgcn_mfma_f32_16x16x32_bf16(kf, qf, s[kt], 0, 0, 0);
      }
      float mx = -1e30f;
      #pragma unroll
      for (int kt = 0; kt < 8; kt++){
        float4 bb = *(const float4*)(biasArr + kt*16 + r4*4);
        s[kt][0] += bb.x; s[kt][1] += bb.y; s[kt][2] += bb.z; s[kt][3] += bb.w;
        mx = fmaxf(mx, fmaxf(fmaxf(s[kt][0], s[kt][1]), fmaxf(s[kt][2], s[kt][3])));
      }
      mx = fmaxf(mx, __shfl_xor(mx, 16, 64));
      mx = fmaxf(mx, __shfl_xor(mx, 32, 64));
      float sum = 0.f;
      #pragma unroll
      for (int kt = 0; kt < 8; kt++){
        #pragma unroll
        for (int rg = 0; rg < 4; rg++){
          float p = __expf(s[kt][rg] - mx);
          s[kt][rg] = p; sum += p;
        }
      }
      sum += __shfl_xor(sum, 16, 64);
      sum += __shfl_xor(sum, 32, 64);
      float inv = 1.0f / sum;
      int rxq = (c & 7) << 4;
      #pragma unroll
      for (int kt = 0; kt < 8; kt++){
        #pragma unroll
        for (int pr = 0; pr < 2; pr++){
          u32 pk = (u32)f2bf(s[kt][pr*2]*inv) | ((u32)f2bf(s[kt][pr*2+1]*inv) << 16);
          int colb = kt*32 + r4*8 + pr*4;
          *(u32*)(pwc + c*256 + (colb ^ rxq)) = pk;
        }
      }
      v4f o[2] = {{0,0,0,0},{0,0,0,0}};
      #pragma unroll
      for (int ks = 0; ks < 4; ks++){
        v8s aP = *(const v8s*)(pwc + c*256 + ((ks*64 + r4*16) ^ rxq));
        #pragma unroll
        for (int dt = 0; dt < 2; dt++){
          v8s vf = *(const v8s*)(Vh + (dt*16 + c)*128 + ks*32 + r4*8);
          o[dt] = __builtin_amdgcn_mfma_f32_16x16x32_bf16(aP, vf, o[dt], 0, 0, 0);
        }
      }
      #pragma unroll
      for (int dt = 0; dt < 2; dt++){
        #pragma unroll
        for (int rg = 0; rg < 4; rg++){
          int row = qrow_base + r4*4 + rg;
          int col = h*32 + dt*16 + c;
          *(u16*)((char*)SB + row*256 + ((col*2) ^ ((row & 7) << 4))) = f2bf(o[dt][rg]);
        }
      }
    }
  }
  __syncthreads();

  // ---- P3/P4: stage aout -> SA; out-proj + residual(x) -> R (f32 swz) ----
  stage128(aoutw, SA, 0, 128, 0);
  __syncthreads();
  {
    v4f acc[2][4] = {};
    compute128(SB, SA, wm, wn, r15, kg, acc);
    #pragma unroll
    for (int i = 0; i < 2; i++){
      #pragma unroll
      for (int j = 0; j < 4; j++){
        int col = wn*64 + j*16 + r15;
        float bv = aoutb[col];
        #pragma unroll
        for (int rr = 0; rr < 4; rr++){
          int row = wm*32 + i*16 + kg*4 + rr;
          float xres = bf2f(*(const u16*)(Xc + row*256 + ((col*2) ^ ((row & 7) << 4))));
          float y = acc[i][j][rr] + bv + xres;
          *(float*)(Rc + row*512 + ((col*4) ^ ((row & 7) << 4))) = y;
        }
      }
    }
  }
  __syncthreads();

  // ---- P5: LN1 -> Rf (in place, f32) + X (bf16) ----
  {
    int r = tid >> 2, j4 = tid & 3;
    float vals[32];
    int rx = (r & 7) << 4;
    #pragma unroll
    for (int k = 0; k < 32; k++){
      int c = j4 + 4*k;
      vals[k] = *(const float*)(Rc + r*512 + ((c*4) ^ rx));
    }
    float s = 0.f;
    #pragma unroll
    for (int k = 0; k < 32; k++) s += vals[k];
    s += __shfl_xor(s, 1, 64); s += __shfl_xor(s, 2, 64);
    float mean = s * (1.0f/128.0f);
    float vv = 0.f;
    #pragma unroll
    for (int k = 0; k < 32; k++){ float d = vals[k] - mean; vv += d*d; }
    vv += __shfl_xor(vv, 1, 64); vv += __shfl_xor(vv, 2, 64);
    float rs = rsqrtf(vv*(1.0f/128.0f) + 1e-5f);
    #pragma unroll
    for (int k = 0; k < 32; k++){
      int c = j4 + 4*k;
      float o = (vals[k] - mean)*rs*g1[c] + b1v[c];
      *(float*)(Rc + r*512 + ((c*4) ^ rx)) = o;
      *(u16*)(Xc + r*256 + ((c*2) ^ rx)) = f2bf(o);
    }
  }
  __syncthreads();

  // ---- P6: FFN (4 tiles of 128 hidden), h stays in LDS ----
  v4f acc2[2][4] = {};
  for (int nt = 0; nt < 4; nt++){
    stage128(w1p, SA, nt*128, 128, 0);
    stage128(w2p, SB, 0, 512, nt*128);
    __syncthreads();
    v4f a1[2][4] = {};
    compute128(X, SA, wm, wn, r15, kg, a1);
    __syncthreads();
    #pragma unroll
    for (int i = 0; i < 2; i++){
      #pragma unroll
      for (int j = 0; j < 4; j++){
        int col = wn*64 + j*16 + r15;
        float bv = b1p[nt*128 + col];
        #pragma unroll
        for (int rr = 0; rr < 4; rr++){
          int row = wm*32 + i*16 + kg*4 + rr;
          float hv = a1[i][j][rr] + bv;
          hv = 0.5f*hv*(1.0f + erff(hv*0.70710678118654752f));
          *(u16*)((char*)SA + row*256 + ((col*2) ^ ((row & 7) << 4))) = f2bf(hv);
        }
      }
    }
    __syncthreads();
    compute128(SA, SB, wm, wn, r15, kg, acc2);
    __syncthreads();
  }

  // ---- P7: FFN2 + bias + x1 residual -> Rf (in place) ----
  {
    #pragma unroll
    for (int i = 0; i < 2; i++){
      #pragma unroll
      for (int j = 0; j < 4; j++){
        int col = wn*64 + j*16 + r15;
        float bv = b2p[col];
        #pragma unroll
        for (int rr = 0; rr < 4; rr++){
          int row = wm*32 + i*16 + kg*4 + rr;
          char* p = Rc + row*512 + ((col*4) ^ ((row & 7) << 4));
          float y = acc2[i][j][rr] + bv + *(const float*)p;
          *(float*)p = y;
        }
      }
    }
  }
  __syncthreads();

  // ---- P8: LN2 -> global out (bf16; optional fov select) ----
  {
    int r = tid >> 2, j4 = tid & 3;
    float vals[32];
    int rx = (r & 7) << 4;
    #pragma unroll
    for (int k = 0; k < 32; k++){
      int c = j4 + 4*k;
      vals[k] = *(const float*)(Rc + r*512 + ((c*4) ^ rx));
    }
    float s = 0.f;
    #pragma unroll
    for (int k = 0; k < 32; k++) s += vals[k];
    s += __shfl_xor(s, 1, 64); s += __shfl_xor(s, 2, 64);
    float mean = s * (1.0f/128.0f);
    float vv = 0.f;
    #pragma unroll
    for (int k = 0; k < 32; k++){ float d = vals[k] - mean; vv += d*d; }
    vv += __shfl_xor(vv, 1, 64); vv += __shfl_xor(vv, 2, 64);
    float rs = rsqrtf(vv*(1.0f/128.0f) + 1e-5f);
    int gq = m0 + r;
    #pragma unroll
    for (int k = 0; k < 32; k++){
      int c = j4 + 4*k;
      float o = (vals[k] - mean)*rs*g2[c] + b2v[c];
      if (fov){
        outB[(size_t)gq*128 + c] = f2bf(fov[gq] ? o : qe[(size_t)gq*128 + c]);
      } else {
        outB[(size_t)gq*128 + c] = f2bf(o);
      }
    }
  }
}

// ---------------- dilated 3x3x3 conv v4 ----------------
__global__ __launch_bounds__(512) void k_conv4(
    const u16* __restrict__ X, const u16* __restrict__ W,
    const float* __restrict__ bias, const u16* __restrict__ zp,
    u16* __restrict__ Y, int dil)
{
  extern __shared__ u16 smem[];
  u16* bufA0 = smem;
  u16* bufA1 = smem + 16384;
  u16* bufW0 = smem + 32768;
  u16* bufW1 = smem + 49152;
  int tid = threadIdx.x, lane = tid & 63, w = tid >> 6;
  int wk = w & 1, wm = (w >> 1) & 1, wn = (w >> 2) & 1;
  int r15 = lane & 15, kg = lane >> 4;
  int bid = blockIdx.x;
  int lb = (bid & 7)*32 + (bid >> 3);
  int m0 = lb*128;
  v4f acc[4][4] = {};
  const v8s vzero = {0,0,0,0,0,0,0,0};
  stageConvA4(X, zp, bufA0, m0, -dil, -dil);
  stage128(W, bufW0, 0, 128, 0);
  for (int g = 0; g < 9; g++){
    const u16* As = (g & 1) ? bufA1 : bufA0;
    #pragma unroll
    for (int dzi = 0; dzi < 3; dzi++){
      int t = g*3 + dzi;
      const u16* Ws = (t & 1) ? bufW1 : bufW0;
      if (t + 1 < 27)
        stage128(W + (size_t)(t+1)*16384, ((t+1)&1) ? bufW1 : bufW0, 0, 128, 0);
      if (dzi == 0 && g < 8){
        int gn = g + 1;
        stageConvA4(X, zp, (gn & 1) ? bufA1 : bufA0, m0, (gn/3 - 1)*dil, (gn%3 - 1)*dil);
      }
      if (dzi == 0){
        if (g < 8) asm volatile("s_waitcnt vmcnt(8)" ::: "memory");
        else       asm volatile("s_waitcnt vmcnt(4)" ::: "memory");
      } else {
        if (t < 26) asm volatile("s_waitcnt vmcnt(4)" ::: "memory");
        else        asm volatile("s_waitcnt vmcnt(0)" ::: "memory");
      }
      __builtin_amdgcn_s_barrier();
      asm volatile("" ::: "memory");
      int zofs = (dzi - 1)*dil;
      bool okz = (unsigned)((r15 & 7) + zofs) < 8u;
      #pragma unroll
      for (int k0 = 0; k0 < 2; k0++){
        int cb = wk*128 + k0*64 + kg*16;
        v8s a[4], b[4];
        #pragma unroll
        for (int q = 0; q < 4; q++){
          int ra = wm*64 + q*16 + r15 + zofs;
          int rc = min(max(ra, 0), 127);
          a[q] = okz ? fragld(As, rc, cb) : vzero;
          b[q] = fragld(Ws, wn*64 + q*16 + r15, cb);
        }
        #pragma unroll
        for (int i = 0; i < 4; i++)
          #pragma unroll
          for (int j = 0; j < 4; j++)
            acc[i][j] = __builtin_amdgcn_mfma_f32_16x16x32_bf16(a[i], b[j], acc[i][j], 0, 0, 0);
      }
      asm volatile("" ::: "memory");
      __builtin_amdgcn_s_barrier();
      asm volatile("" ::: "memory");
    }
  }
  float* red = (float*)smem;
  if (wk == 0){
    #pragma unroll
    for (int i = 0; i < 4; i++)
      #pragma unroll
      for (int j = 0; j < 4; j++)
        #pragma unroll
        for (int rr = 0; rr < 4; rr++)
          red[(wm*64 + i*16 + kg*4 + rr)*128 + wn*64 + j*16 + r15] = acc[i][j][rr];
  }
  __syncthreads();
  if (wk == 1){
    #pragma unroll
    for (int i = 0; i < 4; i++){
      #pragma unroll
      for (int j = 0; j < 4; j++){
        int col = wn*64 + j*16 + r15;
        float bv = bias[col];
        #pragma unroll
        for (int rr = 0; rr < 4; rr++){
          int row = wm*64 + i*16 + kg*4 + rr;
          int grow = m0 + row;
          float v = acc[i][j][rr] + red[row*128 + col] + bv + bf2f(X[(size_t)grow*128 + col]);
          v = fmaxf(v, 0.0f);
          Y[(size_t)grow*128 + col] = f2bf(v);
        }
      }
    }
  }
}

// ---------------- 1x1x1 head conv -> d_out [20][32768] ----------------
__global__ __launch_bounds__(256) void k_outconv(const u16* __restrict__ X,
    const float* __restrict__ W, const float* __restrict__ B, float* __restrict__ out)
{
  __shared__ float sw[20*128];
  __shared__ float sbb[20];
  int tid = threadIdx.x;
  for (int i = tid; i < 20*128; i += 256) sw[i] = W[i];
  if (tid < 20) sbb[tid] = B[tid];
  __syncthreads();
  int s = blockIdx.x*256 + tid;
  u32 rv[64];
  const u32* xp = (const u32*)(X + (size_t)s*128);
  #pragma unroll
  for (int j = 0; j < 64; j++) rv[j] = xp[j];
  for (int ot = 0; ot < 20; ot++){
    float acc = sbb[ot];
    #pragma unroll
    for (int j = 0; j < 64; j++){
      u32 u = rv[j];
      acc += bf2f((u16)(u & 0xffff))*sw[ot*128 + 2*j] + bf2f((u16)(u >> 16))*sw[ot*128 + 2*j + 1];
    }
    out[(size_t)ot*NQv + s] = acc;
  }
}

extern "C" void kernel_launch(void* const* d_in, const int* in_sizes, int n_in,
                              void* d_out, int out_size, void* d_ws, size_t ws_size,
                              hipStream_t stream)
{
  const float* iq    = (const float*)d_in[0];
  const float* logits= (const float*)d_in[1];
  const float* pmL   = (const float*)d_in[2];
  const float* depth = (const float*)d_in[3];
  const float* Km    = (const float*)d_in[4];
  const float* Em    = (const float*)d_in[5];
  const float* vo    = (const float*)d_in[6];
  const float* qe    = (const float*)d_in[7];
  const float* pe    = (const float*)d_in[8];
  const float* ain_w = (const float*)d_in[9];
  const float* ain_b = (const float*)d_in[10];
  const float* aout_w= (const float*)d_in[11];
  const float* aout_b= (const float*)d_in[12];
  const float* ln1g  = (const float*)d_in[13];
  const float* ln1b  = (const float*)d_in[14];
  const float* w1    = (const float*)d_in[15];
  const float* b1    = (const float*)d_in[16];
  const float* w2    = (const float*)d_in[17];
  const float* b2    = (const float*)d_in[18];
  const float* ln2g  = (const float*)d_in[19];
  const float* ln2b  = (const float*)d_in[20];
  const float* pw    = (const float*)d_in[21];
  const float* pb    = (const float*)d_in[22];
  const float* ow    = (const float*)d_in[23];
  const float* ob    = (const float*)d_in[24];
  const int*   fov   = (const int*)d_in[25];
  float* out = (float*)d_out;

  (void)hipFuncSetAttribute((const void*)k_layer, hipFuncAttributeMaxDynamicSharedMemorySize, 163840);
  (void)hipFuncSetAttribute((const void*)k_conv4, hipFuncAttributeMaxDynamicSharedMemorySize, 131072);

  char* ws = (char*)d_ws;
  size_t off = 0;
  auto alloc = [&](size_t bytes) -> char* {
    char* p = ws + off;
    off = (off + bytes + 255) & ~(size_t)255;
    return p;
  };
  float* mats    = (float*)alloc(32*4);
  float* scores  = (float*)alloc(128*4);
  int*   keep0   = (int*)  alloc(128*4);
  int*   keep    = (int*)  alloc(128*4);
  float* biasArr = (float*)alloc(128*4);
  float* xyz     = (float*)alloc(512*4);
  u16*   zp      = (u16*)  alloc(256);
  float* peT     = (float*)alloc(384*4);
  int*   mids    = (int*)  alloc((size_t)HWp*4);
  float* kvkb    = (float*)alloc((size_t)NI*128*4);
  u16* khs_bf  = (u16*)alloc((size_t)3*4*128*32*2);
  u16* vt_bf   = (u16*)alloc((size_t)3*4*32*128*2);
  u16* ain_bf  = (u16*)alloc((size_t)3*384*128*2);
  u16* aout_bf = (u16*)alloc((size_t)3*128*128*2);
  u16* w1_bf   = (u16*)alloc((size_t)3*512*128*2);
  u16* w2_bf   = (u16*)alloc((size_t)3*128*512*2);
  u16* wc_bf   = (u16*)alloc((size_t)3*27*128*128*2);
  u16* T2bf = (u16*)alloc((size_t)NQv*128*2);
  u16* x3a  = (u16*)alloc((size_t)NQv*128*2);
  u16* x3b  = (u16*)alloc((size_t)NQv*128*2);
  (void)ws_size; (void)in_sizes; (void)n_in; (void)out_size;

  // ---- prep ----
  k_prep_small<<<1,128,0,stream>>>(Km, Em, logits, mats, scores, keep0);
  {
    int n0 = 3*384*128, n1 = 3*128*128, n2 = 3*512*128, n3 = 3*128*512;
    int zn0 = 3*4*128*32, zn1 = 3*4*32*128, zn2 = 128;
    int total = n0+n1+n2+n3+zn0+zn1+zn2+384;
    k_prep_multi<<<(total+255)/256,256,0,stream>>>(
        ain_w, ain_bf, n0, aout_w, aout_bf, n1, w1, w1_bf, n2, w2, w2_bf, n3,
        khs_bf, zn0, vt_bf, zn1, zp, zn2, pe, peT);
  }
  k_packconv2<<<dim3(128,3),256,0,stream>>>(pw, wc_bf);
  k_mask_argmax2<<<120,256,0,stream>>>(pmL, scores, keep0, mids);
  k_instbp<<<NI,256,0,stream>>>(pmL, mids, keep0, depth, mats, keep, xyz);
  k_kvk<<<(NI*128+255)/256,256,0,stream>>>(iq, pe, xyz, keep, kvkb);
  { dim3 g(3,4); k_khvh2<<<g,512,0,stream>>>(kvkb, iq, ain_w, ain_b, keep, biasArr, khs_bf, vt_bf); }

  // ---- 3 fused transformer layers ----
  for (int li = 0; li < 3; li++){
    const void* src = (li == 0) ? (const void*)qe : (const void*)T2bf;
    u16* outT = (li < 2) ? T2bf : x3a;
    k_layer<<<256,512,163840,stream>>>(
        src, (li == 0) ? 0 : 1, peT, vo,
        ain_bf + (size_t)li*384*128, ain_b + li*384,
        khs_bf + (size_t)li*16384, vt_bf + (size_t)li*16384, biasArr,
        aout_bf + (size_t)li*128*128, aout_b + li*128,
        ln1g + li*128, ln1b + li*128,
        w1_bf + (size_t)li*512*128, b1 + li*512,
        w2_bf + (size_t)li*128*512, b2 + li*128,
        ln2g + li*128, ln2b + li*128,
        outT, (li == 2) ? fov : nullptr, qe);
  }

  // ---- conv stack ----
  k_conv4<<<256,512,131072,stream>>>(x3a, wc_bf + (size_t)0*27*16384, pb + 0,   zp, x3b, 1);
  k_conv4<<<256,512,131072,stream>>>(x3b, wc_bf + (size_t)1*27*16384, pb + 128, zp, x3a, 2);
  k_conv4<<<256,512,131072,stream>>>(x3a, wc_bf + (size_t)2*27*16384, pb + 256, zp, x3b, 3);
  k_outconv<<<128,256,0,stream>>>(x3b, ow, ob, out);
}